// Round 9
// baseline (124.605 us; speedup 1.0000x reference)
//
#include <hip/hip_runtime.h>
#include <math.h>

#define BB 32
#define LC 512
#define LQ 64
#define HH 512

// Kernel 1: per (b, 64-row i-tile):
//   z2 tile (c*cqw)@q^T + fused s0/s1 dots
//   a1[b,i,:]  = rowsoftmax_j(z + s1[j])        (materialized)
//   e2[b,i,k]  = exp(z2[i,k] - m_tile[k])       (per-tile col-max normalized)
//   pcm/pcs[b,tile,k] = per-tile column max / expsum
__global__ __launch_bounds__(512) void s2_fused_kernel(
    const float* __restrict__ c, const float* __restrict__ q,
    const float* __restrict__ cw, const float* __restrict__ qw,
    const float* __restrict__ cqw,
    float* __restrict__ e2, float* __restrict__ a1,
    float* __restrict__ pcm, float* __restrict__ pcs) {
    int b = blockIdx.y, it = blockIdx.x, i0 = it * 64;
    int t = threadIdx.x, tx = t & 15, ty = t >> 4;   // ty 0..31
    __shared__ float cmT[64][65];   // [h][i]
    __shared__ float qT[64][65];    // [h][j]
    __shared__ float s0_s[64], s1_s[64], mt_s[64];
    __shared__ float redm[32][65], redp[32][65];
    float acc[2][4] = {};           // rows i = ty*2+iy, cols j = tx*4+jx
    float ps0[2] = {0.f, 0.f}, ps1[2] = {0.f, 0.f};

    for (int h0 = 0; h0 < HH; h0 += 64) {
        for (int u = 0; u < 2; ++u) {
            int r = u * 32 + ty;
            int h = tx * 4;
            float4 cv = *(const float4*)(c + ((size_t)(b * LC + i0 + r)) * HH + h0 + h);
            float4 wv = *(const float4*)(cqw + h0 + h);
            cmT[h + 0][r] = cv.x * wv.x; cmT[h + 1][r] = cv.y * wv.y;
            cmT[h + 2][r] = cv.z * wv.z; cmT[h + 3][r] = cv.w * wv.w;
            float4 cwv = *(const float4*)(cw + h0 + h);
            ps0[u] += cv.x * cwv.x + cv.y * cwv.y + cv.z * cwv.z + cv.w * cwv.w;
            float4 qv = *(const float4*)(q + ((size_t)(b * LQ + r)) * HH + h0 + h);
            qT[h + 0][r] = qv.x; qT[h + 1][r] = qv.y;
            qT[h + 2][r] = qv.z; qT[h + 3][r] = qv.w;
            float4 qwv = *(const float4*)(qw + h0 + h);
            ps1[u] += qv.x * qwv.x + qv.y * qwv.y + qv.z * qwv.z + qv.w * qwv.w;
        }
        __syncthreads();
        #pragma unroll 8
        for (int hh = 0; hh < 64; ++hh) {
            float2 cv = *(const float2*)(&cmT[hh][ty * 2]);
            float4 qv = *(const float4*)(&qT[hh][tx * 4]);
            acc[0][0] += cv.x * qv.x; acc[0][1] += cv.x * qv.y;
            acc[0][2] += cv.x * qv.z; acc[0][3] += cv.x * qv.w;
            acc[1][0] += cv.y * qv.x; acc[1][1] += cv.y * qv.y;
            acc[1][2] += cv.y * qv.z; acc[1][3] += cv.y * qv.w;
        }
        __syncthreads();
    }

    // s0/s1 partial reduce across the 16 tx lanes
    for (int off = 1; off < 16; off <<= 1) {
        ps0[0] += __shfl_xor(ps0[0], off, 64); ps0[1] += __shfl_xor(ps0[1], off, 64);
        ps1[0] += __shfl_xor(ps1[0], off, 64); ps1[1] += __shfl_xor(ps1[1], off, 64);
    }
    if (tx == 0) {
        s0_s[ty] = ps0[0]; s0_s[32 + ty] = ps0[1];
        s1_s[ty] = ps1[0]; s1_s[32 + ty] = ps1[1];
    }
    __syncthreads();

    // row softmax (over j) -> a1
    float4 s1v = make_float4(s1_s[tx * 4 + 0], s1_s[tx * 4 + 1], s1_s[tx * 4 + 2], s1_s[tx * 4 + 3]);
    for (int iy = 0; iy < 2; ++iy) {
        int gi = b * LC + i0 + ty * 2 + iy;
        float z0 = acc[iy][0] + s1v.x, z1 = acc[iy][1] + s1v.y;
        float z2v = acc[iy][2] + s1v.z, z3 = acc[iy][3] + s1v.w;
        float m = fmaxf(fmaxf(z0, z1), fmaxf(z2v, z3));
        for (int off = 1; off < 16; off <<= 1) m = fmaxf(m, __shfl_xor(m, off, 64));
        float e0 = __expf(z0 - m), e1 = __expf(z1 - m), e2v = __expf(z2v - m), e3 = __expf(z3 - m);
        float s = e0 + e1 + e2v + e3;
        for (int off = 1; off < 16; off <<= 1) s += __shfl_xor(s, off, 64);
        float si = 1.f / s;
        *(float4*)(&a1[(size_t)gi * LQ + tx * 4]) = make_float4(e0 * si, e1 * si, e2v * si, e3 * si);
    }

    // column max partials (z2 = acc + s0[i])
    float s0a = s0_s[ty * 2], s0b = s0_s[ty * 2 + 1];
    for (int jx = 0; jx < 4; ++jx)
        redm[ty][tx * 4 + jx] = fmaxf(acc[0][jx] + s0a, acc[1][jx] + s0b);
    __syncthreads();
    if (t < 64) {
        float M = redm[0][t];
        #pragma unroll
        for (int g = 1; g < 32; ++g) M = fmaxf(M, redm[g][t]);
        mt_s[t] = M;
        pcm[(b * 8 + it) * 64 + t] = M;
    }
    __syncthreads();
    // e2 write + column expsum partials
    {
        float4 mv = make_float4(mt_s[tx * 4 + 0], mt_s[tx * 4 + 1], mt_s[tx * 4 + 2], mt_s[tx * 4 + 3]);
        float ea[4], eb[4];
        for (int jx = 0; jx < 4; ++jx) {
            float mj = (jx == 0) ? mv.x : (jx == 1) ? mv.y : (jx == 2) ? mv.z : mv.w;
            ea[jx] = __expf(acc[0][jx] + s0a - mj);
            eb[jx] = __expf(acc[1][jx] + s0b - mj);
            redp[ty][tx * 4 + jx] = ea[jx] + eb[jx];
        }
        int gi0 = b * LC + i0 + ty * 2;
        *(float4*)(&e2[(size_t)gi0 * LQ + tx * 4]) = make_float4(ea[0], ea[1], ea[2], ea[3]);
        *(float4*)(&e2[(size_t)(gi0 + 1) * LQ + tx * 4]) = make_float4(eb[0], eb[1], eb[2], eb[3]);
    }
    __syncthreads();
    if (t < 64) {
        float S = redp[0][t];
        #pragma unroll
        for (int g = 1; g < 32; ++g) S += redp[g][t];
        pcs[(b * 8 + it) * 64 + t] = S;
    }
}

// Kernel 2: tmat[b,k,h] = sum_i a2[b,i,k] * c[b,i,h], with
// a2 = e2[i,k] * sc[tile(i)][k],  sc = exp(pcm - M)/S  (combined in-block)
__global__ __launch_bounds__(512) void t_kernel(
    const float* __restrict__ c, const float* __restrict__ e2,
    const float* __restrict__ pcm, const float* __restrict__ pcs,
    float* __restrict__ tmat) {
    int b = blockIdx.y, h0 = blockIdx.x * 64;
    int t = threadIdx.x, tx = t & 15, ty = t >> 4;
    __shared__ float c_s[64][65];    // [i][h]
    __shared__ float a2_s[64][65];   // [i][k]
    __shared__ float sc_s[8][64];
    if (t < 64) {
        float pm[8];
        #pragma unroll
        for (int g = 0; g < 8; ++g) pm[g] = pcm[(b * 8 + g) * 64 + t];
        float M = pm[0];
        #pragma unroll
        for (int g = 1; g < 8; ++g) M = fmaxf(M, pm[g]);
        float S = 0.f, ee[8];
        #pragma unroll
        for (int g = 0; g < 8; ++g) {
            ee[g] = __expf(pm[g] - M);
            S += pcs[(b * 8 + g) * 64 + t] * ee[g];
        }
        float si = 1.f / S;
        #pragma unroll
        for (int g = 0; g < 8; ++g) sc_s[g][t] = ee[g] * si;
    }
    __syncthreads();
    float acc[2][4] = {};
    for (int ic = 0; ic < LC; ic += 64) {
        for (int u = 0; u < 2; ++u) {
            int r = u * 32 + ty;
            int gi = b * LC + ic + r;
            *(float4*)(&c_s[r][tx * 4]) = *(const float4*)(c + (size_t)gi * HH + h0 + tx * 4);
            float4 ev = *(const float4*)(e2 + (size_t)gi * LQ + tx * 4);
            float4 scv = *(const float4*)(&sc_s[(ic + r) >> 6][tx * 4]);
            a2_s[r][tx * 4 + 0] = ev.x * scv.x; a2_s[r][tx * 4 + 1] = ev.y * scv.y;
            a2_s[r][tx * 4 + 2] = ev.z * scv.z; a2_s[r][tx * 4 + 3] = ev.w * scv.w;
        }
        __syncthreads();
        #pragma unroll 8
        for (int ii = 0; ii < 64; ++ii) {
            float2 av = *(const float2*)(&a2_s[ii][ty * 2]);
            float4 cv = *(const float4*)(&c_s[ii][tx * 4]);
            acc[0][0] += av.x * cv.x; acc[0][1] += av.x * cv.y;
            acc[0][2] += av.x * cv.z; acc[0][3] += av.x * cv.w;
            acc[1][0] += av.y * cv.x; acc[1][1] += av.y * cv.y;
            acc[1][2] += av.y * cv.z; acc[1][3] += av.y * cv.w;
        }
        __syncthreads();
    }
    for (int ky = 0; ky < 2; ++ky) {
        int k = ty * 2 + ky;
        *(float4*)(&tmat[((size_t)(b * LQ + k)) * HH + h0 + tx * 4]) =
            make_float4(acc[ky][0], acc[ky][1], acc[ky][2], acc[ky][3]);
    }
}

// Kernel 3: per (b, i-tile 128, h-tile 64): a = a1@q, bb = a1@tmat,
// out = [c, a, c*a, c*bb] concat on h
__global__ __launch_bounds__(512) void f_kernel(
    const float* __restrict__ c, const float* __restrict__ q,
    const float* __restrict__ tmat, const float* __restrict__ a1,
    float* __restrict__ out) {
    int b = blockIdx.z;
    int i0 = blockIdx.x * 128;
    int h0 = blockIdx.y * 64;
    int t = threadIdx.x;
    __shared__ float a1_s[128][65];
    __shared__ float q_s[64][64];
    __shared__ float t_s[64][64];
    for (int u = 0; u < 2; ++u) {
        int f = u * 512 + t;
        int r = f >> 4, c4 = (f & 15) * 4;
        *(float4*)(&q_s[r][c4]) = *(const float4*)(q + ((size_t)(b * LQ + r)) * HH + h0 + c4);
        *(float4*)(&t_s[r][c4]) = *(const float4*)(tmat + ((size_t)(b * LQ + r)) * HH + h0 + c4);
    }
    for (int u = 0; u < 4; ++u) {
        int f = u * 512 + t;
        int r = f >> 4, c4 = (f & 15) * 4;
        *(float4*)(&a1_s[r][c4]) = *(const float4*)(a1 + ((size_t)(b * LC + i0 + r)) * LQ + c4);
    }
    __syncthreads();
    int tx = t & 15, ty = t >> 4;   // tx: h-group, ty 0..31: 4-row i-group
    float acc_a[4][4] = {}, acc_b[4][4] = {};
    for (int k = 0; k < LQ; ++k) {
        float4 qv = *(const float4*)(&q_s[k][tx * 4]);
        float4 tv = *(const float4*)(&t_s[k][tx * 4]);
        for (int r = 0; r < 4; ++r) {
            float a1v = a1_s[ty * 4 + r][k];
            acc_a[r][0] += a1v * qv.x; acc_a[r][1] += a1v * qv.y;
            acc_a[r][2] += a1v * qv.z; acc_a[r][3] += a1v * qv.w;
            acc_b[r][0] += a1v * tv.x; acc_b[r][1] += a1v * tv.y;
            acc_b[r][2] += a1v * tv.z; acc_b[r][3] += a1v * tv.w;
        }
    }
    for (int r = 0; r < 4; ++r) {
        int i = i0 + ty * 4 + r;
        size_t crow = ((size_t)(b * LC + i)) * HH + h0 + tx * 4;
        float4 cv = *(const float4*)(c + crow);
        size_t orow = ((size_t)(b * LC + i)) * 2048;
        float4 av = make_float4(acc_a[r][0], acc_a[r][1], acc_a[r][2], acc_a[r][3]);
        float4 bv = make_float4(acc_b[r][0], acc_b[r][1], acc_b[r][2], acc_b[r][3]);
        float4 cav = make_float4(cv.x * av.x, cv.y * av.y, cv.z * av.z, cv.w * av.w);
        float4 cbv = make_float4(cv.x * bv.x, cv.y * bv.y, cv.z * bv.z, cv.w * bv.w);
        *(float4*)(&out[orow + h0 + tx * 4]) = cv;
        *(float4*)(&out[orow + 512 + h0 + tx * 4]) = av;
        *(float4*)(&out[orow + 1024 + h0 + tx * 4]) = cav;
        *(float4*)(&out[orow + 1536 + h0 + tx * 4]) = cbv;
    }
}

extern "C" void kernel_launch(void* const* d_in, const int* in_sizes, int n_in,
                              void* d_out, int out_size, void* d_ws, size_t ws_size,
                              hipStream_t stream) {
    const float* c   = (const float*)d_in[0];
    const float* q   = (const float*)d_in[1];
    const float* cw  = (const float*)d_in[4];
    const float* qw  = (const float*)d_in[5];
    const float* cqw = (const float*)d_in[6];
    float* out = (float*)d_out;

    float* ws   = (float*)d_ws;
    float* e2   = ws;                            // 1048576
    float* a1   = e2 + (size_t)BB * LC * LQ;     // 1048576
    float* tmat = a1 + (size_t)BB * LC * LQ;     // 1048576
    float* pcm  = tmat + (size_t)BB * LQ * HH;   // 16384
    float* pcs  = pcm + BB * (LC / 64) * LQ;     // 16384

    s2_fused_kernel<<<dim3(LC / 64, BB), 512, 0, stream>>>(c, q, cw, qw, cqw, e2, a1, pcm, pcs);
    t_kernel<<<dim3(HH / 64, BB), 512, 0, stream>>>(c, e2, pcm, pcs, tmat);
    f_kernel<<<dim3(LC / 128, HH / 64, BB), 512, 0, stream>>>(c, q, tmat, a1, out);
}

// Round 10
// 101.103 us; speedup vs baseline: 1.2325x; 1.2325x over previous
//
#include <hip/hip_runtime.h>
#include <math.h>

#define BB 32
#define LC 512
#define LQ 64
#define HH 512

// Kernel 1: per (b, 64-row i-tile):
//   z2 = (c*cqw)@q^T tile + fused s0/s1 dots
//   a1[b,i,:]  = rowsoftmax_j(z2 + s1[j])       (materialized)
//   e2[b,i,k]  = exp(z2[i,k] - m_tile[k])       (per-tile col-max normalized)
//   pcm/pcs[b,tile,k] = per-tile column max / expsum
// 256 threads, 4x4 register tile (LDS-BW-optimal: 2 B/FMA).
__global__ __launch_bounds__(256) void s2_fused_kernel(
    const float* __restrict__ c, const float* __restrict__ q,
    const float* __restrict__ cw, const float* __restrict__ qw,
    const float* __restrict__ cqw,
    float* __restrict__ e2, float* __restrict__ a1,
    float* __restrict__ pcm, float* __restrict__ pcs) {
    int b = blockIdx.y, it = blockIdx.x, i0 = it * 64;
    int t = threadIdx.x, tx = t & 15, ty = t >> 4;   // 16x16
    __shared__ float cmT[64][65];   // [h][i]
    __shared__ float qT[64][65];    // [h][j]
    __shared__ float s0_s[64], s1_s[64], mt_s[64];
    __shared__ float redm[16][65], redp[16][65];
    float acc[4][4] = {};           // rows i = ty*4+iy, cols j = tx*4+jx
    float ps0[4] = {0.f, 0.f, 0.f, 0.f}, ps1[4] = {0.f, 0.f, 0.f, 0.f};

    for (int h0 = 0; h0 < HH; h0 += 64) {
        for (int u = 0; u < 4; ++u) {
            int r = u * 16 + ty;
            int h = tx * 4;
            float4 cv = *(const float4*)(c + ((size_t)(b * LC + i0 + r)) * HH + h0 + h);
            float4 wv = *(const float4*)(cqw + h0 + h);
            cmT[h + 0][r] = cv.x * wv.x; cmT[h + 1][r] = cv.y * wv.y;
            cmT[h + 2][r] = cv.z * wv.z; cmT[h + 3][r] = cv.w * wv.w;
            float4 cwv = *(const float4*)(cw + h0 + h);
            ps0[u] += cv.x * cwv.x + cv.y * cwv.y + cv.z * cwv.z + cv.w * cwv.w;
            float4 qv = *(const float4*)(q + ((size_t)(b * LQ + r)) * HH + h0 + h);
            qT[h + 0][r] = qv.x; qT[h + 1][r] = qv.y;
            qT[h + 2][r] = qv.z; qT[h + 3][r] = qv.w;
            float4 qwv = *(const float4*)(qw + h0 + h);
            ps1[u] += qv.x * qwv.x + qv.y * qwv.y + qv.z * qwv.z + qv.w * qwv.w;
        }
        __syncthreads();
        #pragma unroll 4
        for (int hh = 0; hh < 64; ++hh) {
            float4 cv = *(const float4*)(&cmT[hh][ty * 4]);
            float4 qv = *(const float4*)(&qT[hh][tx * 4]);
            acc[0][0] += cv.x * qv.x; acc[0][1] += cv.x * qv.y; acc[0][2] += cv.x * qv.z; acc[0][3] += cv.x * qv.w;
            acc[1][0] += cv.y * qv.x; acc[1][1] += cv.y * qv.y; acc[1][2] += cv.y * qv.z; acc[1][3] += cv.y * qv.w;
            acc[2][0] += cv.z * qv.x; acc[2][1] += cv.z * qv.y; acc[2][2] += cv.z * qv.z; acc[2][3] += cv.z * qv.w;
            acc[3][0] += cv.w * qv.x; acc[3][1] += cv.w * qv.y; acc[3][2] += cv.w * qv.z; acc[3][3] += cv.w * qv.w;
        }
        __syncthreads();
    }

    // s0/s1 partial reduce across the 16 tx lanes (within same-ty 16-lane groups)
    for (int off = 1; off < 16; off <<= 1) {
        #pragma unroll
        for (int u = 0; u < 4; ++u) {
            ps0[u] += __shfl_xor(ps0[u], off, 64);
            ps1[u] += __shfl_xor(ps1[u], off, 64);
        }
    }
    if (tx == 0) {
        #pragma unroll
        for (int u = 0; u < 4; ++u) {
            s0_s[u * 16 + ty] = ps0[u];
            s1_s[u * 16 + ty] = ps1[u];
        }
    }
    __syncthreads();

    // row softmax (over j) -> a1; rows ty*4+iy
    float4 s1v = make_float4(s1_s[tx * 4 + 0], s1_s[tx * 4 + 1], s1_s[tx * 4 + 2], s1_s[tx * 4 + 3]);
    #pragma unroll
    for (int iy = 0; iy < 4; ++iy) {
        int gi = b * LC + i0 + ty * 4 + iy;
        float z0 = acc[iy][0] + s1v.x, z1 = acc[iy][1] + s1v.y;
        float z2v = acc[iy][2] + s1v.z, z3 = acc[iy][3] + s1v.w;
        float m = fmaxf(fmaxf(z0, z1), fmaxf(z2v, z3));
        for (int off = 1; off < 16; off <<= 1) m = fmaxf(m, __shfl_xor(m, off, 64));
        float e0 = __expf(z0 - m), e1 = __expf(z1 - m), e2v = __expf(z2v - m), e3 = __expf(z3 - m);
        float s = e0 + e1 + e2v + e3;
        for (int off = 1; off < 16; off <<= 1) s += __shfl_xor(s, off, 64);
        float si = 1.f / s;
        *(float4*)(&a1[(size_t)gi * LQ + tx * 4]) = make_float4(e0 * si, e1 * si, e2v * si, e3 * si);
    }

    // column max partials (z2 = acc + s0[i])
    float s0r[4] = {s0_s[ty * 4 + 0], s0_s[ty * 4 + 1], s0_s[ty * 4 + 2], s0_s[ty * 4 + 3]};
    #pragma unroll
    for (int jx = 0; jx < 4; ++jx) {
        float m = acc[0][jx] + s0r[0];
        m = fmaxf(m, acc[1][jx] + s0r[1]);
        m = fmaxf(m, acc[2][jx] + s0r[2]);
        m = fmaxf(m, acc[3][jx] + s0r[3]);
        redm[ty][tx * 4 + jx] = m;
    }
    __syncthreads();
    if (t < 64) {
        float M = redm[0][t];
        #pragma unroll
        for (int g = 1; g < 16; ++g) M = fmaxf(M, redm[g][t]);
        mt_s[t] = M;
        pcm[(b * 8 + it) * 64 + t] = M;
    }
    __syncthreads();
    // e2 write + column expsum partials
    {
        float mj[4] = {mt_s[tx * 4 + 0], mt_s[tx * 4 + 1], mt_s[tx * 4 + 2], mt_s[tx * 4 + 3]};
        float colsum[4] = {0.f, 0.f, 0.f, 0.f};
        #pragma unroll
        for (int iy = 0; iy < 4; ++iy) {
            float e0 = __expf(acc[iy][0] + s0r[iy] - mj[0]);
            float e1 = __expf(acc[iy][1] + s0r[iy] - mj[1]);
            float e2v = __expf(acc[iy][2] + s0r[iy] - mj[2]);
            float e3 = __expf(acc[iy][3] + s0r[iy] - mj[3]);
            colsum[0] += e0; colsum[1] += e1; colsum[2] += e2v; colsum[3] += e3;
            int gi = b * LC + i0 + ty * 4 + iy;
            *(float4*)(&e2[(size_t)gi * LQ + tx * 4]) = make_float4(e0, e1, e2v, e3);
        }
        #pragma unroll
        for (int jx = 0; jx < 4; ++jx) redp[ty][tx * 4 + jx] = colsum[jx];
    }
    __syncthreads();
    if (t < 64) {
        float S = redp[0][t];
        #pragma unroll
        for (int g = 1; g < 16; ++g) S += redp[g][t];
        pcs[(b * 8 + it) * 64 + t] = S;
    }
}

// Kernel 2: tmat[b,k,h] = sum_i a2[b,i,k] * c[b,i,h], with
// a2 = e2[i,k] * sc[tile(i)][k],  sc = exp(pcm - M)/S  (combined in-block)
// 256 threads, 4x4 register tile.
__global__ __launch_bounds__(256) void t_kernel(
    const float* __restrict__ c, const float* __restrict__ e2,
    const float* __restrict__ pcm, const float* __restrict__ pcs,
    float* __restrict__ tmat) {
    int b = blockIdx.y, h0 = blockIdx.x * 64;
    int t = threadIdx.x, tx = t & 15, ty = t >> 4;
    __shared__ float c_s[64][65];    // [i][h]
    __shared__ float a2_s[64][65];   // [i][k]
    __shared__ float sc_s[8][64];
    if (t < 64) {
        float pm[8];
        #pragma unroll
        for (int g = 0; g < 8; ++g) pm[g] = pcm[(b * 8 + g) * 64 + t];
        float M = pm[0];
        #pragma unroll
        for (int g = 1; g < 8; ++g) M = fmaxf(M, pm[g]);
        float S = 0.f, ee[8];
        #pragma unroll
        for (int g = 0; g < 8; ++g) {
            ee[g] = __expf(pm[g] - M);
            S += pcs[(b * 8 + g) * 64 + t] * ee[g];
        }
        float si = 1.f / S;
        #pragma unroll
        for (int g = 0; g < 8; ++g) sc_s[g][t] = ee[g] * si;
    }
    __syncthreads();
    float acc[4][4] = {};   // [ky][hx]
    for (int ic = 0; ic < LC; ic += 64) {
        for (int u = 0; u < 4; ++u) {
            int r = u * 16 + ty;
            int gi = b * LC + ic + r;
            *(float4*)(&c_s[r][tx * 4]) = *(const float4*)(c + (size_t)gi * HH + h0 + tx * 4);
            float4 ev = *(const float4*)(e2 + (size_t)gi * LQ + tx * 4);
            float4 scv = *(const float4*)(&sc_s[(ic + r) >> 6][tx * 4]);
            a2_s[r][tx * 4 + 0] = ev.x * scv.x; a2_s[r][tx * 4 + 1] = ev.y * scv.y;
            a2_s[r][tx * 4 + 2] = ev.z * scv.z; a2_s[r][tx * 4 + 3] = ev.w * scv.w;
        }
        __syncthreads();
        #pragma unroll 4
        for (int ii = 0; ii < 64; ++ii) {
            float4 av = *(const float4*)(&a2_s[ii][ty * 4]);
            float4 cv = *(const float4*)(&c_s[ii][tx * 4]);
            acc[0][0] += av.x * cv.x; acc[0][1] += av.x * cv.y; acc[0][2] += av.x * cv.z; acc[0][3] += av.x * cv.w;
            acc[1][0] += av.y * cv.x; acc[1][1] += av.y * cv.y; acc[1][2] += av.y * cv.z; acc[1][3] += av.y * cv.w;
            acc[2][0] += av.z * cv.x; acc[2][1] += av.z * cv.y; acc[2][2] += av.z * cv.z; acc[2][3] += av.z * cv.w;
            acc[3][0] += av.w * cv.x; acc[3][1] += av.w * cv.y; acc[3][2] += av.w * cv.z; acc[3][3] += av.w * cv.w;
        }
        __syncthreads();
    }
    #pragma unroll
    for (int ky = 0; ky < 4; ++ky) {
        int k = ty * 4 + ky;
        *(float4*)(&tmat[((size_t)(b * LQ + k)) * HH + h0 + tx * 4]) =
            make_float4(acc[ky][0], acc[ky][1], acc[ky][2], acc[ky][3]);
    }
}

// Kernel 3: per (b, i-tile 128, h-tile 64): a = a1@q, bb = a1@tmat,
// out = [c, a, c*a, c*bb] concat on h
__global__ __launch_bounds__(512) void f_kernel(
    const float* __restrict__ c, const float* __restrict__ q,
    const float* __restrict__ tmat, const float* __restrict__ a1,
    float* __restrict__ out) {
    int b = blockIdx.z;
    int i0 = blockIdx.x * 128;
    int h0 = blockIdx.y * 64;
    int t = threadIdx.x;
    __shared__ float a1_s[128][65];
    __shared__ float q_s[64][64];
    __shared__ float t_s[64][64];
    for (int u = 0; u < 2; ++u) {
        int f = u * 512 + t;
        int r = f >> 4, c4 = (f & 15) * 4;
        *(float4*)(&q_s[r][c4]) = *(const float4*)(q + ((size_t)(b * LQ + r)) * HH + h0 + c4);
        *(float4*)(&t_s[r][c4]) = *(const float4*)(tmat + ((size_t)(b * LQ + r)) * HH + h0 + c4);
    }
    for (int u = 0; u < 4; ++u) {
        int f = u * 512 + t;
        int r = f >> 4, c4 = (f & 15) * 4;
        *(float4*)(&a1_s[r][c4]) = *(const float4*)(a1 + ((size_t)(b * LC + i0 + r)) * LQ + c4);
    }
    __syncthreads();
    int tx = t & 15, ty = t >> 4;   // tx: h-group, ty 0..31: 4-row i-group
    float acc_a[4][4] = {}, acc_b[4][4] = {};
    for (int k = 0; k < LQ; ++k) {
        float4 qv = *(const float4*)(&q_s[k][tx * 4]);
        float4 tv = *(const float4*)(&t_s[k][tx * 4]);
        for (int r = 0; r < 4; ++r) {
            float a1v = a1_s[ty * 4 + r][k];
            acc_a[r][0] += a1v * qv.x; acc_a[r][1] += a1v * qv.y;
            acc_a[r][2] += a1v * qv.z; acc_a[r][3] += a1v * qv.w;
            acc_b[r][0] += a1v * tv.x; acc_b[r][1] += a1v * tv.y;
            acc_b[r][2] += a1v * tv.z; acc_b[r][3] += a1v * tv.w;
        }
    }
    for (int r = 0; r < 4; ++r) {
        int i = i0 + ty * 4 + r;
        size_t crow = ((size_t)(b * LC + i)) * HH + h0 + tx * 4;
        float4 cv = *(const float4*)(c + crow);
        size_t orow = ((size_t)(b * LC + i)) * 2048;
        float4 av = make_float4(acc_a[r][0], acc_a[r][1], acc_a[r][2], acc_a[r][3]);
        float4 bv = make_float4(acc_b[r][0], acc_b[r][1], acc_b[r][2], acc_b[r][3]);
        float4 cav = make_float4(cv.x * av.x, cv.y * av.y, cv.z * av.z, cv.w * av.w);
        float4 cbv = make_float4(cv.x * bv.x, cv.y * bv.y, cv.z * bv.z, cv.w * bv.w);
        *(float4*)(&out[orow + h0 + tx * 4]) = cv;
        *(float4*)(&out[orow + 512 + h0 + tx * 4]) = av;
        *(float4*)(&out[orow + 1024 + h0 + tx * 4]) = cav;
        *(float4*)(&out[orow + 1536 + h0 + tx * 4]) = cbv;
    }
}

extern "C" void kernel_launch(void* const* d_in, const int* in_sizes, int n_in,
                              void* d_out, int out_size, void* d_ws, size_t ws_size,
                              hipStream_t stream) {
    const float* c   = (const float*)d_in[0];
    const float* q   = (const float*)d_in[1];
    const float* cw  = (const float*)d_in[4];
    const float* qw  = (const float*)d_in[5];
    const float* cqw = (const float*)d_in[6];
    float* out = (float*)d_out;

    float* ws   = (float*)d_ws;
    float* e2   = ws;                            // 1048576
    float* a1   = e2 + (size_t)BB * LC * LQ;     // 1048576
    float* tmat = a1 + (size_t)BB * LC * LQ;     // 1048576
    float* pcm  = tmat + (size_t)BB * LQ * HH;   // 16384
    float* pcs  = pcm + BB * (LC / 64) * LQ;     // 16384

    s2_fused_kernel<<<dim3(LC / 64, BB), 256, 0, stream>>>(c, q, cw, qw, cqw, e2, a1, pcm, pcs);
    t_kernel<<<dim3(HH / 64, BB), 256, 0, stream>>>(c, e2, pcm, pcs, tmat);
    f_kernel<<<dim3(LC / 128, HH / 64, BB), 512, 0, stream>>>(c, q, tmat, a1, out);
}

// Round 12
// 98.616 us; speedup vs baseline: 1.2635x; 1.0252x over previous
//
#include <hip/hip_runtime.h>
#include <math.h>

#define BB 32
#define LC 512
#define LQ 64
#define HH 512

typedef __attribute__((ext_vector_type(8))) short short8;
typedef __attribute__((ext_vector_type(4))) float f32x4;

__device__ __forceinline__ unsigned short f2bf(float x) {
    unsigned int u = __float_as_uint(x);
    return (unsigned short)((u + 0x7fffu + ((u >> 16) & 1u)) >> 16);
}

// Kernel 1 (fp32, proven in round 10): per (b, 64-row i-tile):
//   z2 = (c*cqw)@q^T tile + fused s0/s1 dots
//   a1 = rowsoftmax; e2 = exp(z2 + s0 - m_tile); pcm/pcs column partials
__global__ __launch_bounds__(256) void s2_fused_kernel(
    const float* __restrict__ c, const float* __restrict__ q,
    const float* __restrict__ cw, const float* __restrict__ qw,
    const float* __restrict__ cqw,
    float* __restrict__ e2, float* __restrict__ a1,
    float* __restrict__ pcm, float* __restrict__ pcs) {
    int b = blockIdx.y, it = blockIdx.x, i0 = it * 64;
    int t = threadIdx.x, tx = t & 15, ty = t >> 4;   // 16x16
    __shared__ float cmT[64][65];   // [h][i]
    __shared__ float qT[64][65];    // [h][j]
    __shared__ float s0_s[64], s1_s[64], mt_s[64];
    __shared__ float redm[16][65], redp[16][65];
    float acc[4][4] = {};           // rows i = ty*4+iy, cols j = tx*4+jx
    float ps0[4] = {0.f, 0.f, 0.f, 0.f}, ps1[4] = {0.f, 0.f, 0.f, 0.f};

    for (int h0 = 0; h0 < HH; h0 += 64) {
        for (int u = 0; u < 4; ++u) {
            int r = u * 16 + ty;
            int h = tx * 4;
            float4 cv = *(const float4*)(c + ((size_t)(b * LC + i0 + r)) * HH + h0 + h);
            float4 wv = *(const float4*)(cqw + h0 + h);
            cmT[h + 0][r] = cv.x * wv.x; cmT[h + 1][r] = cv.y * wv.y;
            cmT[h + 2][r] = cv.z * wv.z; cmT[h + 3][r] = cv.w * wv.w;
            float4 cwv = *(const float4*)(cw + h0 + h);
            ps0[u] += cv.x * cwv.x + cv.y * cwv.y + cv.z * cwv.z + cv.w * cwv.w;
            float4 qv = *(const float4*)(q + ((size_t)(b * LQ + r)) * HH + h0 + h);
            qT[h + 0][r] = qv.x; qT[h + 1][r] = qv.y;
            qT[h + 2][r] = qv.z; qT[h + 3][r] = qv.w;
            float4 qwv = *(const float4*)(qw + h0 + h);
            ps1[u] += qv.x * qwv.x + qv.y * qwv.y + qv.z * qwv.z + qv.w * qwv.w;
        }
        __syncthreads();
        #pragma unroll 4
        for (int hh = 0; hh < 64; ++hh) {
            float4 cv = *(const float4*)(&cmT[hh][ty * 4]);
            float4 qv = *(const float4*)(&qT[hh][tx * 4]);
            acc[0][0] += cv.x * qv.x; acc[0][1] += cv.x * qv.y; acc[0][2] += cv.x * qv.z; acc[0][3] += cv.x * qv.w;
            acc[1][0] += cv.y * qv.x; acc[1][1] += cv.y * qv.y; acc[1][2] += cv.y * qv.z; acc[1][3] += cv.y * qv.w;
            acc[2][0] += cv.z * qv.x; acc[2][1] += cv.z * qv.y; acc[2][2] += cv.z * qv.z; acc[2][3] += cv.z * qv.w;
            acc[3][0] += cv.w * qv.x; acc[3][1] += cv.w * qv.y; acc[3][2] += cv.w * qv.z; acc[3][3] += cv.w * qv.w;
        }
        __syncthreads();
    }

    for (int off = 1; off < 16; off <<= 1) {
        #pragma unroll
        for (int u = 0; u < 4; ++u) {
            ps0[u] += __shfl_xor(ps0[u], off, 64);
            ps1[u] += __shfl_xor(ps1[u], off, 64);
        }
    }
    if (tx == 0) {
        #pragma unroll
        for (int u = 0; u < 4; ++u) {
            s0_s[u * 16 + ty] = ps0[u];
            s1_s[u * 16 + ty] = ps1[u];
        }
    }
    __syncthreads();

    float4 s1v = make_float4(s1_s[tx * 4 + 0], s1_s[tx * 4 + 1], s1_s[tx * 4 + 2], s1_s[tx * 4 + 3]);
    #pragma unroll
    for (int iy = 0; iy < 4; ++iy) {
        int gi = b * LC + i0 + ty * 4 + iy;
        float z0 = acc[iy][0] + s1v.x, z1 = acc[iy][1] + s1v.y;
        float z2v = acc[iy][2] + s1v.z, z3 = acc[iy][3] + s1v.w;
        float m = fmaxf(fmaxf(z0, z1), fmaxf(z2v, z3));
        for (int off = 1; off < 16; off <<= 1) m = fmaxf(m, __shfl_xor(m, off, 64));
        float e0 = __expf(z0 - m), e1 = __expf(z1 - m), e2v = __expf(z2v - m), e3 = __expf(z3 - m);
        float s = e0 + e1 + e2v + e3;
        for (int off = 1; off < 16; off <<= 1) s += __shfl_xor(s, off, 64);
        float si = 1.f / s;
        *(float4*)(&a1[(size_t)gi * LQ + tx * 4]) = make_float4(e0 * si, e1 * si, e2v * si, e3 * si);
    }

    float s0r[4] = {s0_s[ty * 4 + 0], s0_s[ty * 4 + 1], s0_s[ty * 4 + 2], s0_s[ty * 4 + 3]};
    #pragma unroll
    for (int jx = 0; jx < 4; ++jx) {
        float m = acc[0][jx] + s0r[0];
        m = fmaxf(m, acc[1][jx] + s0r[1]);
        m = fmaxf(m, acc[2][jx] + s0r[2]);
        m = fmaxf(m, acc[3][jx] + s0r[3]);
        redm[ty][tx * 4 + jx] = m;
    }
    __syncthreads();
    if (t < 64) {
        float M = redm[0][t];
        #pragma unroll
        for (int g = 1; g < 16; ++g) M = fmaxf(M, redm[g][t]);
        mt_s[t] = M;
        pcm[(b * 8 + it) * 64 + t] = M;
    }
    __syncthreads();
    {
        float mj[4] = {mt_s[tx * 4 + 0], mt_s[tx * 4 + 1], mt_s[tx * 4 + 2], mt_s[tx * 4 + 3]};
        float colsum[4] = {0.f, 0.f, 0.f, 0.f};
        #pragma unroll
        for (int iy = 0; iy < 4; ++iy) {
            float e0 = __expf(acc[iy][0] + s0r[iy] - mj[0]);
            float e1 = __expf(acc[iy][1] + s0r[iy] - mj[1]);
            float e2v = __expf(acc[iy][2] + s0r[iy] - mj[2]);
            float e3 = __expf(acc[iy][3] + s0r[iy] - mj[3]);
            colsum[0] += e0; colsum[1] += e1; colsum[2] += e2v; colsum[3] += e3;
            int gi = b * LC + i0 + ty * 4 + iy;
            *(float4*)(&e2[(size_t)gi * LQ + tx * 4]) = make_float4(e0, e1, e2v, e3);
        }
        #pragma unroll
        for (int jx = 0; jx < 4; ++jx) redp[ty][tx * 4 + jx] = colsum[jx];
    }
    __syncthreads();
    if (t < 64) {
        float S = redp[0][t];
        #pragma unroll
        for (int g = 1; g < 16; ++g) S += redp[g][t];
        pcs[(b * 8 + it) * 64 + t] = S;
    }
}

// Kernel 2 (fp32, proven in round 10): tmat[b,k,h] = sum_i a2[b,i,k]*c[b,i,h]
__global__ __launch_bounds__(256) void t_kernel(
    const float* __restrict__ c, const float* __restrict__ e2,
    const float* __restrict__ pcm, const float* __restrict__ pcs,
    float* __restrict__ tmat) {
    int b = blockIdx.y, h0 = blockIdx.x * 64;
    int t = threadIdx.x, tx = t & 15, ty = t >> 4;
    __shared__ float c_s[64][65];    // [i][h]
    __shared__ float a2_s[64][65];   // [i][k]
    __shared__ float sc_s[8][64];
    if (t < 64) {
        float pm[8];
        #pragma unroll
        for (int g = 0; g < 8; ++g) pm[g] = pcm[(b * 8 + g) * 64 + t];
        float M = pm[0];
        #pragma unroll
        for (int g = 1; g < 8; ++g) M = fmaxf(M, pm[g]);
        float S = 0.f, ee[8];
        #pragma unroll
        for (int g = 0; g < 8; ++g) {
            ee[g] = __expf(pm[g] - M);
            S += pcs[(b * 8 + g) * 64 + t] * ee[g];
        }
        float si = 1.f / S;
        #pragma unroll
        for (int g = 0; g < 8; ++g) sc_s[g][t] = ee[g] * si;
    }
    __syncthreads();
    float acc[4][4] = {};   // [ky][hx]
    for (int ic = 0; ic < LC; ic += 64) {
        for (int u = 0; u < 4; ++u) {
            int r = u * 16 + ty;
            int gi = b * LC + ic + r;
            *(float4*)(&c_s[r][tx * 4]) = *(const float4*)(c + (size_t)gi * HH + h0 + tx * 4);
            float4 ev = *(const float4*)(e2 + (size_t)gi * LQ + tx * 4);
            float4 scv = *(const float4*)(&sc_s[(ic + r) >> 6][tx * 4]);
            a2_s[r][tx * 4 + 0] = ev.x * scv.x; a2_s[r][tx * 4 + 1] = ev.y * scv.y;
            a2_s[r][tx * 4 + 2] = ev.z * scv.z; a2_s[r][tx * 4 + 3] = ev.w * scv.w;
        }
        __syncthreads();
        #pragma unroll 4
        for (int ii = 0; ii < 64; ++ii) {
            float4 av = *(const float4*)(&a2_s[ii][ty * 4]);
            float4 cv = *(const float4*)(&c_s[ii][tx * 4]);
            acc[0][0] += av.x * cv.x; acc[0][1] += av.x * cv.y; acc[0][2] += av.x * cv.z; acc[0][3] += av.x * cv.w;
            acc[1][0] += av.y * cv.x; acc[1][1] += av.y * cv.y; acc[1][2] += av.y * cv.z; acc[1][3] += av.y * cv.w;
            acc[2][0] += av.z * cv.x; acc[2][1] += av.z * cv.y; acc[2][2] += av.z * cv.z; acc[2][3] += av.z * cv.w;
            acc[3][0] += av.w * cv.x; acc[3][1] += av.w * cv.y; acc[3][2] += av.w * cv.z; acc[3][3] += av.w * cv.w;
        }
        __syncthreads();
    }
    #pragma unroll
    for (int ky = 0; ky < 4; ++ky) {
        int k = ty * 4 + ky;
        *(float4*)(&tmat[((size_t)(b * LQ + k)) * HH + h0 + tx * 4]) =
            make_float4(acc[ky][0], acc[ky][1], acc[ky][2], acc[ky][3]);
    }
}

// Kernel 3 (NEW, MFMA): per (b, i-tile 128, h-tile 64):
//   a = a1@q, bb = a1@tmat via mfma_f32_16x16x32_bf16; out = [c, a, c*a, c*bb]
// 512 thr = 8 waves; wave w owns i-rows 16w..16w+16; trivial epilogue (no reductions).
__global__ __launch_bounds__(512) void f_mfma_kernel(
    const float* __restrict__ c, const float* __restrict__ q,
    const float* __restrict__ tmat, const float* __restrict__ a1,
    float* __restrict__ out) {
    int b = blockIdx.z;
    int i0 = blockIdx.x * 128;
    int h0 = blockIdx.y * 64;
    int t = threadIdx.x;
    int lane = t & 63, w = t >> 6;
    int lo = lane & 15, hi = lane >> 4;
    __shared__ __align__(16) unsigned short a1b[128][72];  // [i_loc][k] bf16
    __shared__ __align__(16) unsigned short qTb[64][72];   // [h_loc][k] bf16
    __shared__ __align__(16) unsigned short tTb[64][72];   // [h_loc][k] bf16
    #pragma unroll
    for (int u = 0; u < 4; ++u) {
        int idx = u * 512 + t;
        int r = idx >> 4, c4 = (idx & 15) * 4;
        float4 v = *(const float4*)(a1 + ((size_t)(b * LC + i0 + r)) * LQ + c4);
        a1b[r][c4 + 0] = f2bf(v.x); a1b[r][c4 + 1] = f2bf(v.y);
        a1b[r][c4 + 2] = f2bf(v.z); a1b[r][c4 + 3] = f2bf(v.w);
    }
    #pragma unroll
    for (int u = 0; u < 2; ++u) {
        int idx = u * 512 + t;
        int k = idx >> 4, h4 = (idx & 15) * 4;
        float4 qv = *(const float4*)(q + ((size_t)(b * LQ + k)) * HH + h0 + h4);
        qTb[h4 + 0][k] = f2bf(qv.x); qTb[h4 + 1][k] = f2bf(qv.y);
        qTb[h4 + 2][k] = f2bf(qv.z); qTb[h4 + 3][k] = f2bf(qv.w);
        float4 tv = *(const float4*)(tmat + ((size_t)(b * LQ + k)) * HH + h0 + h4);
        tTb[h4 + 0][k] = f2bf(tv.x); tTb[h4 + 1][k] = f2bf(tv.y);
        tTb[h4 + 2][k] = f2bf(tv.z); tTb[h4 + 3][k] = f2bf(tv.w);
    }
    __syncthreads();
    f32x4 acc_a[4] = {{0.f,0.f,0.f,0.f},{0.f,0.f,0.f,0.f},{0.f,0.f,0.f,0.f},{0.f,0.f,0.f,0.f}};
    f32x4 acc_b[4] = {{0.f,0.f,0.f,0.f},{0.f,0.f,0.f,0.f},{0.f,0.f,0.f,0.f},{0.f,0.f,0.f,0.f}};
    #pragma unroll
    for (int kk = 0; kk < 64; kk += 32) {
        short8 af = *(const short8*)(&a1b[16 * w + lo][kk + hi * 8]);
        #pragma unroll
        for (int jt = 0; jt < 4; ++jt) {
            short8 bq = *(const short8*)(&qTb[16 * jt + lo][kk + hi * 8]);
            acc_a[jt] = __builtin_amdgcn_mfma_f32_16x16x32_bf16(af, bq, acc_a[jt], 0, 0, 0);
            short8 bt = *(const short8*)(&tTb[16 * jt + lo][kk + hi * 8]);
            acc_b[jt] = __builtin_amdgcn_mfma_f32_16x16x32_bf16(af, bt, acc_b[jt], 0, 0, 0);
        }
    }
    // epilogue: D row=(lane>>4)*4+reg -> i; col=lane&15 -> h within 16-block jt
    #pragma unroll
    for (int e = 0; e < 4; ++e) {
        int i = i0 + 16 * w + hi * 4 + e;
        const float* crow = c + ((size_t)(b * LC + i)) * HH + h0;
        float* orow = out + ((size_t)(b * LC + i)) * 2048 + h0;
        #pragma unroll
        for (int jt = 0; jt < 4; ++jt) {
            int h = 16 * jt + lo;
            float cv = crow[h];
            float av = acc_a[jt][e];
            float bv = acc_b[jt][e];
            orow[h] = cv;
            orow[512 + h] = av;
            orow[1024 + h] = cv * av;
            orow[1536 + h] = cv * bv;
        }
    }
}

extern "C" void kernel_launch(void* const* d_in, const int* in_sizes, int n_in,
                              void* d_out, int out_size, void* d_ws, size_t ws_size,
                              hipStream_t stream) {
    const float* c   = (const float*)d_in[0];
    const float* q   = (const float*)d_in[1];
    const float* cw  = (const float*)d_in[4];
    const float* qw  = (const float*)d_in[5];
    const float* cqw = (const float*)d_in[6];
    float* out = (float*)d_out;

    float* ws   = (float*)d_ws;
    float* e2   = ws;                            // 1048576
    float* a1   = e2 + (size_t)BB * LC * LQ;     // 1048576
    float* tmat = a1 + (size_t)BB * LC * LQ;     // 1048576
    float* pcm  = tmat + (size_t)BB * LQ * HH;   // 16384
    float* pcs  = pcm + BB * (LC / 64) * LQ;     // 16384

    s2_fused_kernel<<<dim3(LC / 64, BB), 256, 0, stream>>>(c, q, cw, qw, cqw, e2, a1, pcm, pcs);
    t_kernel<<<dim3(HH / 64, BB), 256, 0, stream>>>(c, e2, pcm, pcs, tmat);
    f_mfma_kernel<<<dim3(LC / 128, HH / 64, BB), 512, 0, stream>>>(c, q, tmat, a1, out);
}

// Round 13
// 69.892 us; speedup vs baseline: 1.7828x; 1.4110x over previous
//
#include <hip/hip_runtime.h>
#include <math.h>

#define BB 32
#define LC 512
#define LQ 64
#define HH 512

typedef __attribute__((ext_vector_type(8))) short short8;
typedef __attribute__((ext_vector_type(4))) float f32x4;

__device__ __forceinline__ unsigned short f2bf(float x) {
    unsigned int u = __float_as_uint(x);
    return (unsigned short)((u + 0x7fffu + ((u >> 16) & 1u)) >> 16);
}

// Kernel 1 (MFMA core + proven fp32 epilogue): per (b, 64-row i-tile):
//   z2 = (c*cqw)@q^T via bf16 MFMA -> LDS fp32 tile (validated D mapping)
//   then round-10 epilogue verbatim: a1 rowsoftmax, e2, pcm/pcs column partials.
__global__ __launch_bounds__(256) void s2_mfma_kernel(
    const float* __restrict__ c, const float* __restrict__ q,
    const float* __restrict__ cw, const float* __restrict__ qw,
    const float* __restrict__ cqw,
    float* __restrict__ e2, float* __restrict__ a1,
    float* __restrict__ pcm, float* __restrict__ pcs) {
    int b = blockIdx.y, it = blockIdx.x, i0 = it * 64;
    int t = threadIdx.x, tx = t & 15, ty = t >> 4;
    int lane = t & 63, w = t >> 6, lo = lane & 15, hi = lane >> 4;
    __shared__ __align__(16) unsigned short cmb[64][72];  // [i][k] bf16
    __shared__ __align__(16) unsigned short qb[64][72];   // [j][k] bf16
    __shared__ float z2s[64][65];                         // fp32 z2 tile
    __shared__ float s0_s[64], s1_s[64], mt_s[64];
    __shared__ float redm[16][65], redp[16][65];
    f32x4 acc[4] = {{0.f,0.f,0.f,0.f},{0.f,0.f,0.f,0.f},{0.f,0.f,0.f,0.f},{0.f,0.f,0.f,0.f}};
    float ps0[4] = {0.f,0.f,0.f,0.f}, ps1[4] = {0.f,0.f,0.f,0.f};

    for (int h0 = 0; h0 < HH; h0 += 64) {
        #pragma unroll
        for (int u = 0; u < 4; ++u) {
            int r = u * 16 + ty;
            int h = tx * 4;
            float4 cv = *(const float4*)(c + ((size_t)(b * LC + i0 + r)) * HH + h0 + h);
            float4 wv = *(const float4*)(cqw + h0 + h);
            cmb[r][h + 0] = f2bf(cv.x * wv.x);
            cmb[r][h + 1] = f2bf(cv.y * wv.y);
            cmb[r][h + 2] = f2bf(cv.z * wv.z);
            cmb[r][h + 3] = f2bf(cv.w * wv.w);
            float4 cwv = *(const float4*)(cw + h0 + h);
            ps0[u] += cv.x * cwv.x + cv.y * cwv.y + cv.z * cwv.z + cv.w * cwv.w;
            float4 qv = *(const float4*)(q + ((size_t)(b * LQ + r)) * HH + h0 + h);
            qb[r][h + 0] = f2bf(qv.x);
            qb[r][h + 1] = f2bf(qv.y);
            qb[r][h + 2] = f2bf(qv.z);
            qb[r][h + 3] = f2bf(qv.w);
            float4 qwv = *(const float4*)(qw + h0 + h);
            ps1[u] += qv.x * qwv.x + qv.y * qwv.y + qv.z * qwv.z + qv.w * qwv.w;
        }
        __syncthreads();
        #pragma unroll
        for (int kk = 0; kk < 64; kk += 32) {
            short8 af = *(const short8*)(&cmb[16 * w + lo][kk + hi * 8]);
            #pragma unroll
            for (int jt = 0; jt < 4; ++jt) {
                short8 bf = *(const short8*)(&qb[16 * jt + lo][kk + hi * 8]);
                acc[jt] = __builtin_amdgcn_mfma_f32_16x16x32_bf16(af, bf, acc[jt], 0, 0, 0);
            }
        }
        __syncthreads();
    }

    // spill MFMA D to LDS with the f-validated mapping: row=16w+hi*4+e, col=16jt+lo
    #pragma unroll
    for (int jt = 0; jt < 4; ++jt)
        #pragma unroll
        for (int e = 0; e < 4; ++e)
            z2s[16 * w + hi * 4 + e][16 * jt + lo] = acc[jt][e];

    // s0/s1 reduce (proven round-10 logic)
    for (int off = 1; off < 16; off <<= 1) {
        #pragma unroll
        for (int u = 0; u < 4; ++u) {
            ps0[u] += __shfl_xor(ps0[u], off, 64);
            ps1[u] += __shfl_xor(ps1[u], off, 64);
        }
    }
    if (tx == 0) {
        #pragma unroll
        for (int u = 0; u < 4; ++u) {
            s0_s[u * 16 + ty] = ps0[u];
            s1_s[u * 16 + ty] = ps1[u];
        }
    }
    __syncthreads();

    // ---- round-10 epilogue verbatim, with acc[iy][jx] := z2s[ty*4+iy][tx*4+jx] ----
    float4 zacc[4];
    #pragma unroll
    for (int iy = 0; iy < 4; ++iy) zacc[iy] = *(const float4*)(&z2s[ty * 4 + iy][tx * 4]);

    float4 s1v = make_float4(s1_s[tx * 4 + 0], s1_s[tx * 4 + 1], s1_s[tx * 4 + 2], s1_s[tx * 4 + 3]);
    #pragma unroll
    for (int iy = 0; iy < 4; ++iy) {
        int gi = b * LC + i0 + ty * 4 + iy;
        float z0 = zacc[iy].x + s1v.x, z1 = zacc[iy].y + s1v.y;
        float z2v = zacc[iy].z + s1v.z, z3 = zacc[iy].w + s1v.w;
        float m = fmaxf(fmaxf(z0, z1), fmaxf(z2v, z3));
        for (int off = 1; off < 16; off <<= 1) m = fmaxf(m, __shfl_xor(m, off, 64));
        float e0 = __expf(z0 - m), e1 = __expf(z1 - m), e2v = __expf(z2v - m), e3 = __expf(z3 - m);
        float s = e0 + e1 + e2v + e3;
        for (int off = 1; off < 16; off <<= 1) s += __shfl_xor(s, off, 64);
        float si = 1.f / s;
        *(float4*)(&a1[(size_t)gi * LQ + tx * 4]) = make_float4(e0 * si, e1 * si, e2v * si, e3 * si);
    }

    float s0r[4] = {s0_s[ty * 4 + 0], s0_s[ty * 4 + 1], s0_s[ty * 4 + 2], s0_s[ty * 4 + 3]};
    #pragma unroll
    for (int jx = 0; jx < 4; ++jx) {
        float zc[4] = {(&zacc[0].x)[jx], (&zacc[1].x)[jx], (&zacc[2].x)[jx], (&zacc[3].x)[jx]};
        float m = zc[0] + s0r[0];
        m = fmaxf(m, zc[1] + s0r[1]);
        m = fmaxf(m, zc[2] + s0r[2]);
        m = fmaxf(m, zc[3] + s0r[3]);
        redm[ty][tx * 4 + jx] = m;
    }
    __syncthreads();
    if (t < 64) {
        float M = redm[0][t];
        #pragma unroll
        for (int g = 1; g < 16; ++g) M = fmaxf(M, redm[g][t]);
        mt_s[t] = M;
        pcm[(b * 8 + it) * 64 + t] = M;
    }
    __syncthreads();
    {
        float mj[4] = {mt_s[tx * 4 + 0], mt_s[tx * 4 + 1], mt_s[tx * 4 + 2], mt_s[tx * 4 + 3]};
        float colsum[4] = {0.f, 0.f, 0.f, 0.f};
        #pragma unroll
        for (int iy = 0; iy < 4; ++iy) {
            float e0 = __expf(zacc[iy].x + s0r[iy] - mj[0]);
            float e1 = __expf(zacc[iy].y + s0r[iy] - mj[1]);
            float e2v = __expf(zacc[iy].z + s0r[iy] - mj[2]);
            float e3 = __expf(zacc[iy].w + s0r[iy] - mj[3]);
            colsum[0] += e0; colsum[1] += e1; colsum[2] += e2v; colsum[3] += e3;
            int gi = b * LC + i0 + ty * 4 + iy;
            *(float4*)(&e2[(size_t)gi * LQ + tx * 4]) = make_float4(e0, e1, e2v, e3);
        }
        #pragma unroll
        for (int jx = 0; jx < 4; ++jx) redp[ty][tx * 4 + jx] = colsum[jx];
    }
    __syncthreads();
    if (t < 64) {
        float S = redp[0][t];
        #pragma unroll
        for (int g = 1; g < 16; ++g) S += redp[g][t];
        pcs[(b * 8 + it) * 64 + t] = S;
    }
}

// Kernel 2 (MFMA, all sub-patterns f-validated): tmat[b,k,h] = sum_i a2[b,i,k]*c[b,i,h]
// M=k, N=h, K=i; a2 = e2*sc during transposed bf16 staging; direct D writes.
__global__ __launch_bounds__(256) void t_mfma_kernel(
    const float* __restrict__ c, const float* __restrict__ e2,
    const float* __restrict__ pcm, const float* __restrict__ pcs,
    float* __restrict__ tmat) {
    int b = blockIdx.y, h0 = blockIdx.x * 64;
    int t = threadIdx.x, tx = t & 15, ty = t >> 4;
    int lane = t & 63, w = t >> 6, lo = lane & 15, hi = lane >> 4;
    __shared__ __align__(16) unsigned short a2b[64][72];  // [k][i_local] bf16
    __shared__ __align__(16) unsigned short cb[64][72];   // [h_local][i_local] bf16
    __shared__ float sc_s[8][64];
    if (t < 64) {
        float pm[8];
        #pragma unroll
        for (int g = 0; g < 8; ++g) pm[g] = pcm[(b * 8 + g) * 64 + t];
        float M = pm[0];
        #pragma unroll
        for (int g = 1; g < 8; ++g) M = fmaxf(M, pm[g]);
        float S = 0.f, ee[8];
        #pragma unroll
        for (int g = 0; g < 8; ++g) {
            ee[g] = __expf(pm[g] - M);
            S += pcs[(b * 8 + g) * 64 + t] * ee[g];
        }
        float si = 1.f / S;
        #pragma unroll
        for (int g = 0; g < 8; ++g) sc_s[g][t] = ee[g] * si;
    }
    __syncthreads();
    f32x4 acc[4] = {{0.f,0.f,0.f,0.f},{0.f,0.f,0.f,0.f},{0.f,0.f,0.f,0.f},{0.f,0.f,0.f,0.f}};
    for (int ic = 0; ic < LC; ic += 64) {
        #pragma unroll
        for (int u = 0; u < 4; ++u) {
            int r = u * 16 + ty;
            int gi = b * LC + ic + r;
            float4 cv = *(const float4*)(c + (size_t)gi * HH + h0 + tx * 4);
            cb[tx * 4 + 0][r] = f2bf(cv.x);
            cb[tx * 4 + 1][r] = f2bf(cv.y);
            cb[tx * 4 + 2][r] = f2bf(cv.z);
            cb[tx * 4 + 3][r] = f2bf(cv.w);
            float4 ev = *(const float4*)(e2 + (size_t)gi * LQ + tx * 4);
            float4 scv = *(const float4*)(&sc_s[(ic + r) >> 6][tx * 4]);
            a2b[tx * 4 + 0][r] = f2bf(ev.x * scv.x);
            a2b[tx * 4 + 1][r] = f2bf(ev.y * scv.y);
            a2b[tx * 4 + 2][r] = f2bf(ev.z * scv.z);
            a2b[tx * 4 + 3][r] = f2bf(ev.w * scv.w);
        }
        __syncthreads();
        #pragma unroll
        for (int kk = 0; kk < 64; kk += 32) {
            short8 af = *(const short8*)(&a2b[16 * w + lo][kk + hi * 8]);
            #pragma unroll
            for (int jt = 0; jt < 4; ++jt) {
                short8 bf = *(const short8*)(&cb[16 * jt + lo][kk + hi * 8]);
                acc[jt] = __builtin_amdgcn_mfma_f32_16x16x32_bf16(af, bf, acc[jt], 0, 0, 0);
            }
        }
        __syncthreads();
    }
    #pragma unroll
    for (int e = 0; e < 4; ++e) {
        int k = 16 * w + hi * 4 + e;
        #pragma unroll
        for (int jt = 0; jt < 4; ++jt)
            tmat[((size_t)(b * LQ + k)) * HH + h0 + 16 * jt + lo] = acc[jt][e];
    }
}

// Kernel 3 (MFMA, validated round 12): per (b, i-tile 128, h-tile 64):
//   a = a1@q, bb = a1@tmat; out = [c, a, c*a, c*bb]
__global__ __launch_bounds__(512) void f_mfma_kernel(
    const float* __restrict__ c, const float* __restrict__ q,
    const float* __restrict__ tmat, const float* __restrict__ a1,
    float* __restrict__ out) {
    int b = blockIdx.z;
    int i0 = blockIdx.x * 128;
    int h0 = blockIdx.y * 64;
    int t = threadIdx.x;
    int lane = t & 63, w = t >> 6;
    int lo = lane & 15, hi = lane >> 4;
    __shared__ __align__(16) unsigned short a1b[128][72];  // [i_loc][k] bf16
    __shared__ __align__(16) unsigned short qTb[64][72];   // [h_loc][k] bf16
    __shared__ __align__(16) unsigned short tTb[64][72];   // [h_loc][k] bf16
    #pragma unroll
    for (int u = 0; u < 4; ++u) {
        int idx = u * 512 + t;
        int r = idx >> 4, c4 = (idx & 15) * 4;
        float4 v = *(const float4*)(a1 + ((size_t)(b * LC + i0 + r)) * LQ + c4);
        a1b[r][c4 + 0] = f2bf(v.x); a1b[r][c4 + 1] = f2bf(v.y);
        a1b[r][c4 + 2] = f2bf(v.z); a1b[r][c4 + 3] = f2bf(v.w);
    }
    #pragma unroll
    for (int u = 0; u < 2; ++u) {
        int idx = u * 512 + t;
        int k = idx >> 4, h4 = (idx & 15) * 4;
        float4 qv = *(const float4*)(q + ((size_t)(b * LQ + k)) * HH + h0 + h4);
        qTb[h4 + 0][k] = f2bf(qv.x); qTb[h4 + 1][k] = f2bf(qv.y);
        qTb[h4 + 2][k] = f2bf(qv.z); qTb[h4 + 3][k] = f2bf(qv.w);
        float4 tv = *(const float4*)(tmat + ((size_t)(b * LQ + k)) * HH + h0 + h4);
        tTb[h4 + 0][k] = f2bf(tv.x); tTb[h4 + 1][k] = f2bf(tv.y);
        tTb[h4 + 2][k] = f2bf(tv.z); tTb[h4 + 3][k] = f2bf(tv.w);
    }
    __syncthreads();
    f32x4 acc_a[4] = {{0.f,0.f,0.f,0.f},{0.f,0.f,0.f,0.f},{0.f,0.f,0.f,0.f},{0.f,0.f,0.f,0.f}};
    f32x4 acc_b[4] = {{0.f,0.f,0.f,0.f},{0.f,0.f,0.f,0.f},{0.f,0.f,0.f,0.f},{0.f,0.f,0.f,0.f}};
    #pragma unroll
    for (int kk = 0; kk < 64; kk += 32) {
        short8 af = *(const short8*)(&a1b[16 * w + lo][kk + hi * 8]);
        #pragma unroll
        for (int jt = 0; jt < 4; ++jt) {
            short8 bq = *(const short8*)(&qTb[16 * jt + lo][kk + hi * 8]);
            acc_a[jt] = __builtin_amdgcn_mfma_f32_16x16x32_bf16(af, bq, acc_a[jt], 0, 0, 0);
            short8 bt = *(const short8*)(&tTb[16 * jt + lo][kk + hi * 8]);
            acc_b[jt] = __builtin_amdgcn_mfma_f32_16x16x32_bf16(af, bt, acc_b[jt], 0, 0, 0);
        }
    }
    #pragma unroll
    for (int e = 0; e < 4; ++e) {
        int i = i0 + 16 * w + hi * 4 + e;
        const float* crow = c + ((size_t)(b * LC + i)) * HH + h0;
        float* orow = out + ((size_t)(b * LC + i)) * 2048 + h0;
        #pragma unroll
        for (int jt = 0; jt < 4; ++jt) {
            int h = 16 * jt + lo;
            float cv = crow[h];
            float av = acc_a[jt][e];
            float bv = acc_b[jt][e];
            orow[h] = cv;
            orow[512 + h] = av;
            orow[1024 + h] = cv * av;
            orow[1536 + h] = cv * bv;
        }
    }
}

extern "C" void kernel_launch(void* const* d_in, const int* in_sizes, int n_in,
                              void* d_out, int out_size, void* d_ws, size_t ws_size,
                              hipStream_t stream) {
    const float* c   = (const float*)d_in[0];
    const float* q   = (const float*)d_in[1];
    const float* cw  = (const float*)d_in[4];
    const float* qw  = (const float*)d_in[5];
    const float* cqw = (const float*)d_in[6];
    float* out = (float*)d_out;

    float* ws   = (float*)d_ws;
    float* e2   = ws;                            // 1048576
    float* a1   = e2 + (size_t)BB * LC * LQ;     // 1048576
    float* tmat = a1 + (size_t)BB * LC * LQ;     // 1048576
    float* pcm  = tmat + (size_t)BB * LQ * HH;   // 16384
    float* pcs  = pcm + BB * (LC / 64) * LQ;     // 16384

    s2_mfma_kernel<<<dim3(LC / 64, BB), 256, 0, stream>>>(c, q, cw, qw, cqw, e2, a1, pcm, pcs);
    t_mfma_kernel<<<dim3(HH / 64, BB), 256, 0, stream>>>(c, e2, pcm, pcs, tmat);
    f_mfma_kernel<<<dim3(LC / 128, HH / 64, BB), 512, 0, stream>>>(c, q, tmat, a1, out);
}

// Round 15
// 68.805 us; speedup vs baseline: 1.8110x; 1.0158x over previous
//
#include <hip/hip_runtime.h>
#include <math.h>

#define BB 32
#define LC 512
#define LQ 64
#define HH 512

typedef __attribute__((ext_vector_type(8))) short short8;
typedef __attribute__((ext_vector_type(4))) float f32x4;

__device__ __forceinline__ unsigned short f2bf(float x) {
    unsigned int u = __float_as_uint(x);
    return (unsigned short)((u + 0x7fffu + ((u >> 16) & 1u)) >> 16);
}

__device__ __forceinline__ void nts(float* p, float x, float y, float z, float w) {
    f32x4 v = {x, y, z, w};
    __builtin_nontemporal_store(v, (f32x4*)p);
}

// Kernel 1 (MFMA core + proven fp32 epilogue) — unchanged from round 13.
__global__ __launch_bounds__(256) void s2_mfma_kernel(
    const float* __restrict__ c, const float* __restrict__ q,
    const float* __restrict__ cw, const float* __restrict__ qw,
    const float* __restrict__ cqw,
    float* __restrict__ e2, float* __restrict__ a1,
    float* __restrict__ pcm, float* __restrict__ pcs) {
    int b = blockIdx.y, it = blockIdx.x, i0 = it * 64;
    int t = threadIdx.x, tx = t & 15, ty = t >> 4;
    int lane = t & 63, w = t >> 6, lo = lane & 15, hi = lane >> 4;
    __shared__ __align__(16) unsigned short cmb[64][72];  // [i][k] bf16
    __shared__ __align__(16) unsigned short qb[64][72];   // [j][k] bf16
    __shared__ float z2s[64][65];                         // fp32 z2 tile
    __shared__ float s0_s[64], s1_s[64], mt_s[64];
    __shared__ float redm[16][65], redp[16][65];
    f32x4 acc[4] = {{0.f,0.f,0.f,0.f},{0.f,0.f,0.f,0.f},{0.f,0.f,0.f,0.f},{0.f,0.f,0.f,0.f}};
    float ps0[4] = {0.f,0.f,0.f,0.f}, ps1[4] = {0.f,0.f,0.f,0.f};

    for (int h0 = 0; h0 < HH; h0 += 64) {
        #pragma unroll
        for (int u = 0; u < 4; ++u) {
            int r = u * 16 + ty;
            int h = tx * 4;
            float4 cv = *(const float4*)(c + ((size_t)(b * LC + i0 + r)) * HH + h0 + h);
            float4 wv = *(const float4*)(cqw + h0 + h);
            cmb[r][h + 0] = f2bf(cv.x * wv.x);
            cmb[r][h + 1] = f2bf(cv.y * wv.y);
            cmb[r][h + 2] = f2bf(cv.z * wv.z);
            cmb[r][h + 3] = f2bf(cv.w * wv.w);
            float4 cwv = *(const float4*)(cw + h0 + h);
            ps0[u] += cv.x * cwv.x + cv.y * cwv.y + cv.z * cwv.z + cv.w * cwv.w;
            float4 qv = *(const float4*)(q + ((size_t)(b * LQ + r)) * HH + h0 + h);
            qb[r][h + 0] = f2bf(qv.x);
            qb[r][h + 1] = f2bf(qv.y);
            qb[r][h + 2] = f2bf(qv.z);
            qb[r][h + 3] = f2bf(qv.w);
            float4 qwv = *(const float4*)(qw + h0 + h);
            ps1[u] += qv.x * qwv.x + qv.y * qwv.y + qv.z * qwv.z + qv.w * qwv.w;
        }
        __syncthreads();
        #pragma unroll
        for (int kk = 0; kk < 64; kk += 32) {
            short8 af = *(const short8*)(&cmb[16 * w + lo][kk + hi * 8]);
            #pragma unroll
            for (int jt = 0; jt < 4; ++jt) {
                short8 bf = *(const short8*)(&qb[16 * jt + lo][kk + hi * 8]);
                acc[jt] = __builtin_amdgcn_mfma_f32_16x16x32_bf16(af, bf, acc[jt], 0, 0, 0);
            }
        }
        __syncthreads();
    }

    #pragma unroll
    for (int jt = 0; jt < 4; ++jt)
        #pragma unroll
        for (int e = 0; e < 4; ++e)
            z2s[16 * w + hi * 4 + e][16 * jt + lo] = acc[jt][e];

    for (int off = 1; off < 16; off <<= 1) {
        #pragma unroll
        for (int u = 0; u < 4; ++u) {
            ps0[u] += __shfl_xor(ps0[u], off, 64);
            ps1[u] += __shfl_xor(ps1[u], off, 64);
        }
    }
    if (tx == 0) {
        #pragma unroll
        for (int u = 0; u < 4; ++u) {
            s0_s[u * 16 + ty] = ps0[u];
            s1_s[u * 16 + ty] = ps1[u];
        }
    }
    __syncthreads();

    float4 zacc[4];
    #pragma unroll
    for (int iy = 0; iy < 4; ++iy) zacc[iy] = *(const float4*)(&z2s[ty * 4 + iy][tx * 4]);

    float4 s1v = make_float4(s1_s[tx * 4 + 0], s1_s[tx * 4 + 1], s1_s[tx * 4 + 2], s1_s[tx * 4 + 3]);
    #pragma unroll
    for (int iy = 0; iy < 4; ++iy) {
        int gi = b * LC + i0 + ty * 4 + iy;
        float z0 = zacc[iy].x + s1v.x, z1 = zacc[iy].y + s1v.y;
        float z2v = zacc[iy].z + s1v.z, z3 = zacc[iy].w + s1v.w;
        float m = fmaxf(fmaxf(z0, z1), fmaxf(z2v, z3));
        for (int off = 1; off < 16; off <<= 1) m = fmaxf(m, __shfl_xor(m, off, 64));
        float e0 = __expf(z0 - m), e1 = __expf(z1 - m), e2v = __expf(z2v - m), e3 = __expf(z3 - m);
        float s = e0 + e1 + e2v + e3;
        for (int off = 1; off < 16; off <<= 1) s += __shfl_xor(s, off, 64);
        float si = 1.f / s;
        *(float4*)(&a1[(size_t)gi * LQ + tx * 4]) = make_float4(e0 * si, e1 * si, e2v * si, e3 * si);
    }

    float s0r[4] = {s0_s[ty * 4 + 0], s0_s[ty * 4 + 1], s0_s[ty * 4 + 2], s0_s[ty * 4 + 3]};
    #pragma unroll
    for (int jx = 0; jx < 4; ++jx) {
        float zc[4] = {(&zacc[0].x)[jx], (&zacc[1].x)[jx], (&zacc[2].x)[jx], (&zacc[3].x)[jx]};
        float m = zc[0] + s0r[0];
        m = fmaxf(m, zc[1] + s0r[1]);
        m = fmaxf(m, zc[2] + s0r[2]);
        m = fmaxf(m, zc[3] + s0r[3]);
        redm[ty][tx * 4 + jx] = m;
    }
    __syncthreads();
    if (t < 64) {
        float M = redm[0][t];
        #pragma unroll
        for (int g = 1; g < 16; ++g) M = fmaxf(M, redm[g][t]);
        mt_s[t] = M;
        pcm[(b * 8 + it) * 64 + t] = M;
    }
    __syncthreads();
    {
        float mj[4] = {mt_s[tx * 4 + 0], mt_s[tx * 4 + 1], mt_s[tx * 4 + 2], mt_s[tx * 4 + 3]};
        float colsum[4] = {0.f, 0.f, 0.f, 0.f};
        #pragma unroll
        for (int iy = 0; iy < 4; ++iy) {
            float e0 = __expf(zacc[iy].x + s0r[iy] - mj[0]);
            float e1 = __expf(zacc[iy].y + s0r[iy] - mj[1]);
            float e2v = __expf(zacc[iy].z + s0r[iy] - mj[2]);
            float e3 = __expf(zacc[iy].w + s0r[iy] - mj[3]);
            colsum[0] += e0; colsum[1] += e1; colsum[2] += e2v; colsum[3] += e3;
            int gi = b * LC + i0 + ty * 4 + iy;
            *(float4*)(&e2[(size_t)gi * LQ + tx * 4]) = make_float4(e0, e1, e2v, e3);
        }
        #pragma unroll
        for (int jx = 0; jx < 4; ++jx) redp[ty][tx * 4 + jx] = colsum[jx];
    }
    __syncthreads();
    if (t < 64) {
        float S = redp[0][t];
        #pragma unroll
        for (int g = 1; g < 16; ++g) S += redp[g][t];
        pcs[(b * 8 + it) * 64 + t] = S;
    }
}

// Kernel 2 (MFMA) — unchanged from round 13.
__global__ __launch_bounds__(256) void t_mfma_kernel(
    const float* __restrict__ c, const float* __restrict__ e2,
    const float* __restrict__ pcm, const float* __restrict__ pcs,
    float* __restrict__ tmat) {
    int b = blockIdx.y, h0 = blockIdx.x * 64;
    int t = threadIdx.x, tx = t & 15, ty = t >> 4;
    int lane = t & 63, w = t >> 6, lo = lane & 15, hi = lane >> 4;
    __shared__ __align__(16) unsigned short a2b[64][72];  // [k][i_local] bf16
    __shared__ __align__(16) unsigned short cb[64][72];   // [h_local][i_local] bf16
    __shared__ float sc_s[8][64];
    if (t < 64) {
        float pm[8];
        #pragma unroll
        for (int g = 0; g < 8; ++g) pm[g] = pcm[(b * 8 + g) * 64 + t];
        float M = pm[0];
        #pragma unroll
        for (int g = 1; g < 8; ++g) M = fmaxf(M, pm[g]);
        float S = 0.f, ee[8];
        #pragma unroll
        for (int g = 0; g < 8; ++g) {
            ee[g] = __expf(pm[g] - M);
            S += pcs[(b * 8 + g) * 64 + t] * ee[g];
        }
        float si = 1.f / S;
        #pragma unroll
        for (int g = 0; g < 8; ++g) sc_s[g][t] = ee[g] * si;
    }
    __syncthreads();
    f32x4 acc[4] = {{0.f,0.f,0.f,0.f},{0.f,0.f,0.f,0.f},{0.f,0.f,0.f,0.f},{0.f,0.f,0.f,0.f}};
    for (int ic = 0; ic < LC; ic += 64) {
        #pragma unroll
        for (int u = 0; u < 4; ++u) {
            int r = u * 16 + ty;
            int gi = b * LC + ic + r;
            float4 cv = *(const float4*)(c + (size_t)gi * HH + h0 + tx * 4);
            cb[tx * 4 + 0][r] = f2bf(cv.x);
            cb[tx * 4 + 1][r] = f2bf(cv.y);
            cb[tx * 4 + 2][r] = f2bf(cv.z);
            cb[tx * 4 + 3][r] = f2bf(cv.w);
            float4 ev = *(const float4*)(e2 + (size_t)gi * LQ + tx * 4);
            float4 scv = *(const float4*)(&sc_s[(ic + r) >> 6][tx * 4]);
            a2b[tx * 4 + 0][r] = f2bf(ev.x * scv.x);
            a2b[tx * 4 + 1][r] = f2bf(ev.y * scv.y);
            a2b[tx * 4 + 2][r] = f2bf(ev.z * scv.z);
            a2b[tx * 4 + 3][r] = f2bf(ev.w * scv.w);
        }
        __syncthreads();
        #pragma unroll
        for (int kk = 0; kk < 64; kk += 32) {
            short8 af = *(const short8*)(&a2b[16 * w + lo][kk + hi * 8]);
            #pragma unroll
            for (int jt = 0; jt < 4; ++jt) {
                short8 bf = *(const short8*)(&cb[16 * jt + lo][kk + hi * 8]);
                acc[jt] = __builtin_amdgcn_mfma_f32_16x16x32_bf16(af, bf, acc[jt], 0, 0, 0);
            }
        }
        __syncthreads();
    }
    #pragma unroll
    for (int e = 0; e < 4; ++e) {
        int k = 16 * w + hi * 4 + e;
        #pragma unroll
        for (int jt = 0; jt < 4; ++jt)
            tmat[((size_t)(b * LQ + k)) * HH + h0 + 16 * jt + lo] = acc[jt][e];
    }
}

// Kernel 3 (MFMA + vectorized nt epilogue): per (b, i-tile 128, h-tile 64):
//   a = a1@q, bb = a1@tmat; out = [c, a, c*a, c*bb] via LDS re-tile -> float4 nt stores.
struct FStage {
    unsigned short a1b[128][72];
    unsigned short qTb[64][72];
    unsigned short tTb[64][72];
};
union FSMem {
    FStage st;
    float spill[128][68];
};

__global__ __launch_bounds__(512) void f_mfma_kernel(
    const float* __restrict__ c, const float* __restrict__ q,
    const float* __restrict__ tmat, const float* __restrict__ a1,
    float* __restrict__ out) {
    int b = blockIdx.z;
    int i0 = blockIdx.x * 128;
    int h0 = blockIdx.y * 64;
    int t = threadIdx.x;
    int lane = t & 63, w = t >> 6;
    int lo = lane & 15, hi = lane >> 4;
    __shared__ __align__(16) FSMem sm;
    #pragma unroll
    for (int u = 0; u < 4; ++u) {
        int idx = u * 512 + t;
        int r = idx >> 4, c4 = (idx & 15) * 4;
        float4 v = *(const float4*)(a1 + ((size_t)(b * LC + i0 + r)) * LQ + c4);
        sm.st.a1b[r][c4 + 0] = f2bf(v.x); sm.st.a1b[r][c4 + 1] = f2bf(v.y);
        sm.st.a1b[r][c4 + 2] = f2bf(v.z); sm.st.a1b[r][c4 + 3] = f2bf(v.w);
    }
    #pragma unroll
    for (int u = 0; u < 2; ++u) {
        int idx = u * 512 + t;
        int k = idx >> 4, h4 = (idx & 15) * 4;
        float4 qv = *(const float4*)(q + ((size_t)(b * LQ + k)) * HH + h0 + h4);
        sm.st.qTb[h4 + 0][k] = f2bf(qv.x); sm.st.qTb[h4 + 1][k] = f2bf(qv.y);
        sm.st.qTb[h4 + 2][k] = f2bf(qv.z); sm.st.qTb[h4 + 3][k] = f2bf(qv.w);
        float4 tv = *(const float4*)(tmat + ((size_t)(b * LQ + k)) * HH + h0 + h4);
        sm.st.tTb[h4 + 0][k] = f2bf(tv.x); sm.st.tTb[h4 + 1][k] = f2bf(tv.y);
        sm.st.tTb[h4 + 2][k] = f2bf(tv.z); sm.st.tTb[h4 + 3][k] = f2bf(tv.w);
    }
    __syncthreads();
    f32x4 acc_a[4] = {{0.f,0.f,0.f,0.f},{0.f,0.f,0.f,0.f},{0.f,0.f,0.f,0.f},{0.f,0.f,0.f,0.f}};
    f32x4 acc_b[4] = {{0.f,0.f,0.f,0.f},{0.f,0.f,0.f,0.f},{0.f,0.f,0.f,0.f},{0.f,0.f,0.f,0.f}};
    #pragma unroll
    for (int kk = 0; kk < 64; kk += 32) {
        short8 af = *(const short8*)(&sm.st.a1b[16 * w + lo][kk + hi * 8]);
        #pragma unroll
        for (int jt = 0; jt < 4; ++jt) {
            short8 bq = *(const short8*)(&sm.st.qTb[16 * jt + lo][kk + hi * 8]);
            acc_a[jt] = __builtin_amdgcn_mfma_f32_16x16x32_bf16(af, bq, acc_a[jt], 0, 0, 0);
            short8 bt = *(const short8*)(&sm.st.tTb[16 * jt + lo][kk + hi * 8]);
            acc_b[jt] = __builtin_amdgcn_mfma_f32_16x16x32_bf16(af, bt, acc_b[jt], 0, 0, 0);
        }
    }
    __syncthreads();   // all waves done reading staged bf16 before spill overwrites

    // Phase A: spill acc_a, write c / a / c*a sections as float4 nt stores
    #pragma unroll
    for (int jt = 0; jt < 4; ++jt)
        #pragma unroll
        for (int e = 0; e < 4; ++e)
            sm.spill[16 * w + hi * 4 + e][16 * jt + lo] = acc_a[jt][e];
    __syncthreads();
    #pragma unroll
    for (int u = 0; u < 4; ++u) {
        int idx = u * 512 + t;
        int r = idx >> 4, c4 = (idx & 15) * 4;
        int i = i0 + r;
        const float* crow = c + ((size_t)(b * LC + i)) * HH + h0;
        float* orow = out + ((size_t)(b * LC + i)) * 2048 + h0;
        float4 av = *(const float4*)(&sm.spill[r][c4]);
        float4 cv = *(const float4*)(crow + c4);
        nts(orow + c4, cv.x, cv.y, cv.z, cv.w);
        nts(orow + 512 + c4, av.x, av.y, av.z, av.w);
        nts(orow + 1024 + c4, cv.x * av.x, cv.y * av.y, cv.z * av.z, cv.w * av.w);
    }
    __syncthreads();

    // Phase B: spill acc_b, write c*bb section
    #pragma unroll
    for (int jt = 0; jt < 4; ++jt)
        #pragma unroll
        for (int e = 0; e < 4; ++e)
            sm.spill[16 * w + hi * 4 + e][16 * jt + lo] = acc_b[jt][e];
    __syncthreads();
    #pragma unroll
    for (int u = 0; u < 4; ++u) {
        int idx = u * 512 + t;
        int r = idx >> 4, c4 = (idx & 15) * 4;
        int i = i0 + r;
        const float* crow = c + ((size_t)(b * LC + i)) * HH + h0;
        float* orow = out + ((size_t)(b * LC + i)) * 2048 + h0;
        float4 bv = *(const float4*)(&sm.spill[r][c4]);
        float4 cv = *(const float4*)(crow + c4);
        nts(orow + 1536 + c4, cv.x * bv.x, cv.y * bv.y, cv.z * bv.z, cv.w * bv.w);
    }
}

extern "C" void kernel_launch(void* const* d_in, const int* in_sizes, int n_in,
                              void* d_out, int out_size, void* d_ws, size_t ws_size,
                              hipStream_t stream) {
    const float* c   = (const float*)d_in[0];
    const float* q   = (const float*)d_in[1];
    const float* cw  = (const float*)d_in[4];
    const float* qw  = (const float*)d_in[5];
    const float* cqw = (const float*)d_in[6];
    float* out = (float*)d_out;

    float* ws   = (float*)d_ws;
    float* e2   = ws;                            // 1048576
    float* a1   = e2 + (size_t)BB * LC * LQ;     // 1048576
    float* tmat = a1 + (size_t)BB * LC * LQ;     // 1048576
    float* pcm  = tmat + (size_t)BB * LQ * HH;   // 16384
    float* pcs  = pcm + BB * (LC / 64) * LQ;     // 16384

    s2_mfma_kernel<<<dim3(LC / 64, BB), 256, 0, stream>>>(c, q, cw, qw, cqw, e2, a1, pcm, pcs);
    t_mfma_kernel<<<dim3(HH / 64, BB), 256, 0, stream>>>(c, e2, pcm, pcs, tmat);
    f_mfma_kernel<<<dim3(LC / 128, HH / 64, BB), 512, 0, stream>>>(c, q, tmat, a1, out);
}

// Round 16
// 64.194 us; speedup vs baseline: 1.9411x; 1.0718x over previous
//
#include <hip/hip_runtime.h>
#include <math.h>

#define BB 32
#define LC 512
#define LQ 64
#define HH 512

typedef __attribute__((ext_vector_type(8))) short short8;
typedef __attribute__((ext_vector_type(4))) float f32x4;

__device__ __forceinline__ unsigned short f2bf(float x) {
    unsigned int u = __float_as_uint(x);
    return (unsigned short)((u + 0x7fffu + ((u >> 16) & 1u)) >> 16);
}
__device__ __forceinline__ float bf2f(unsigned short v) {
    return __uint_as_float(((unsigned int)v) << 16);
}
__device__ __forceinline__ void nts(float* p, float x, float y, float z, float w) {
    f32x4 v = {x, y, z, w};
    __builtin_nontemporal_store(v, (f32x4*)p);
}

// Kernel 1 (MFMA core + proven fp32 epilogue; a1/e2 now stored bf16).
__global__ __launch_bounds__(256) void s2_mfma_kernel(
    const float* __restrict__ c, const float* __restrict__ q,
    const float* __restrict__ cw, const float* __restrict__ qw,
    const float* __restrict__ cqw,
    unsigned short* __restrict__ e2, unsigned short* __restrict__ a1,
    float* __restrict__ pcm, float* __restrict__ pcs) {
    int b = blockIdx.y, it = blockIdx.x, i0 = it * 64;
    int t = threadIdx.x, tx = t & 15, ty = t >> 4;
    int lane = t & 63, w = t >> 6, lo = lane & 15, hi = lane >> 4;
    __shared__ __align__(16) unsigned short cmb[64][72];  // [i][k] bf16
    __shared__ __align__(16) unsigned short qb[64][72];   // [j][k] bf16
    __shared__ float z2s[64][65];                         // fp32 z2 tile
    __shared__ float s0_s[64], s1_s[64], mt_s[64];
    __shared__ float redm[16][65], redp[16][65];
    f32x4 acc[4] = {{0.f,0.f,0.f,0.f},{0.f,0.f,0.f,0.f},{0.f,0.f,0.f,0.f},{0.f,0.f,0.f,0.f}};
    float ps0[4] = {0.f,0.f,0.f,0.f}, ps1[4] = {0.f,0.f,0.f,0.f};

    for (int h0 = 0; h0 < HH; h0 += 64) {
        #pragma unroll
        for (int u = 0; u < 4; ++u) {
            int r = u * 16 + ty;
            int h = tx * 4;
            float4 cv = *(const float4*)(c + ((size_t)(b * LC + i0 + r)) * HH + h0 + h);
            float4 wv = *(const float4*)(cqw + h0 + h);
            cmb[r][h + 0] = f2bf(cv.x * wv.x);
            cmb[r][h + 1] = f2bf(cv.y * wv.y);
            cmb[r][h + 2] = f2bf(cv.z * wv.z);
            cmb[r][h + 3] = f2bf(cv.w * wv.w);
            float4 cwv = *(const float4*)(cw + h0 + h);
            ps0[u] += cv.x * cwv.x + cv.y * cwv.y + cv.z * cwv.z + cv.w * cwv.w;
            float4 qv = *(const float4*)(q + ((size_t)(b * LQ + r)) * HH + h0 + h);
            qb[r][h + 0] = f2bf(qv.x);
            qb[r][h + 1] = f2bf(qv.y);
            qb[r][h + 2] = f2bf(qv.z);
            qb[r][h + 3] = f2bf(qv.w);
            float4 qwv = *(const float4*)(qw + h0 + h);
            ps1[u] += qv.x * qwv.x + qv.y * qwv.y + qv.z * qwv.z + qv.w * qwv.w;
        }
        __syncthreads();
        #pragma unroll
        for (int kk = 0; kk < 64; kk += 32) {
            short8 af = *(const short8*)(&cmb[16 * w + lo][kk + hi * 8]);
            #pragma unroll
            for (int jt = 0; jt < 4; ++jt) {
                short8 bf = *(const short8*)(&qb[16 * jt + lo][kk + hi * 8]);
                acc[jt] = __builtin_amdgcn_mfma_f32_16x16x32_bf16(af, bf, acc[jt], 0, 0, 0);
            }
        }
        __syncthreads();
    }

    #pragma unroll
    for (int jt = 0; jt < 4; ++jt)
        #pragma unroll
        for (int e = 0; e < 4; ++e)
            z2s[16 * w + hi * 4 + e][16 * jt + lo] = acc[jt][e];

    for (int off = 1; off < 16; off <<= 1) {
        #pragma unroll
        for (int u = 0; u < 4; ++u) {
            ps0[u] += __shfl_xor(ps0[u], off, 64);
            ps1[u] += __shfl_xor(ps1[u], off, 64);
        }
    }
    if (tx == 0) {
        #pragma unroll
        for (int u = 0; u < 4; ++u) {
            s0_s[u * 16 + ty] = ps0[u];
            s1_s[u * 16 + ty] = ps1[u];
        }
    }
    __syncthreads();

    float4 zacc[4];
    #pragma unroll
    for (int iy = 0; iy < 4; ++iy) zacc[iy] = *(const float4*)(&z2s[ty * 4 + iy][tx * 4]);

    float4 s1v = make_float4(s1_s[tx * 4 + 0], s1_s[tx * 4 + 1], s1_s[tx * 4 + 2], s1_s[tx * 4 + 3]);
    #pragma unroll
    for (int iy = 0; iy < 4; ++iy) {
        int gi = b * LC + i0 + ty * 4 + iy;
        float z0 = zacc[iy].x + s1v.x, z1 = zacc[iy].y + s1v.y;
        float z2v = zacc[iy].z + s1v.z, z3 = zacc[iy].w + s1v.w;
        float m = fmaxf(fmaxf(z0, z1), fmaxf(z2v, z3));
        for (int off = 1; off < 16; off <<= 1) m = fmaxf(m, __shfl_xor(m, off, 64));
        float e0 = __expf(z0 - m), e1 = __expf(z1 - m), e2v = __expf(z2v - m), e3 = __expf(z3 - m);
        float s = e0 + e1 + e2v + e3;
        for (int off = 1; off < 16; off <<= 1) s += __shfl_xor(s, off, 64);
        float si = 1.f / s;
        ushort4 av;
        av.x = f2bf(e0 * si); av.y = f2bf(e1 * si);
        av.z = f2bf(e2v * si); av.w = f2bf(e3 * si);
        *(ushort4*)(&a1[(size_t)gi * LQ + tx * 4]) = av;
    }

    float s0r[4] = {s0_s[ty * 4 + 0], s0_s[ty * 4 + 1], s0_s[ty * 4 + 2], s0_s[ty * 4 + 3]};
    #pragma unroll
    for (int jx = 0; jx < 4; ++jx) {
        float zc[4] = {(&zacc[0].x)[jx], (&zacc[1].x)[jx], (&zacc[2].x)[jx], (&zacc[3].x)[jx]};
        float m = zc[0] + s0r[0];
        m = fmaxf(m, zc[1] + s0r[1]);
        m = fmaxf(m, zc[2] + s0r[2]);
        m = fmaxf(m, zc[3] + s0r[3]);
        redm[ty][tx * 4 + jx] = m;
    }
    __syncthreads();
    if (t < 64) {
        float M = redm[0][t];
        #pragma unroll
        for (int g = 1; g < 16; ++g) M = fmaxf(M, redm[g][t]);
        mt_s[t] = M;
        pcm[(b * 8 + it) * 64 + t] = M;
    }
    __syncthreads();
    {
        float mj[4] = {mt_s[tx * 4 + 0], mt_s[tx * 4 + 1], mt_s[tx * 4 + 2], mt_s[tx * 4 + 3]};
        float colsum[4] = {0.f, 0.f, 0.f, 0.f};
        #pragma unroll
        for (int iy = 0; iy < 4; ++iy) {
            float e0 = __expf(zacc[iy].x + s0r[iy] - mj[0]);
            float e1 = __expf(zacc[iy].y + s0r[iy] - mj[1]);
            float e2v = __expf(zacc[iy].z + s0r[iy] - mj[2]);
            float e3 = __expf(zacc[iy].w + s0r[iy] - mj[3]);
            colsum[0] += e0; colsum[1] += e1; colsum[2] += e2v; colsum[3] += e3;
            int gi = b * LC + i0 + ty * 4 + iy;
            ushort4 evv;
            evv.x = f2bf(e0); evv.y = f2bf(e1); evv.z = f2bf(e2v); evv.w = f2bf(e3);
            *(ushort4*)(&e2[(size_t)gi * LQ + tx * 4]) = evv;
        }
        #pragma unroll
        for (int jx = 0; jx < 4; ++jx) redp[ty][tx * 4 + jx] = colsum[jx];
    }
    __syncthreads();
    if (t < 64) {
        float S = redp[0][t];
        #pragma unroll
        for (int g = 1; g < 16; ++g) S += redp[g][t];
        pcs[(b * 8 + it) * 64 + t] = S;
    }
}

// Kernel 2 (fused t+f): per (b, h-tile 64):
//   t-phase: tTb[h][k] = bf16( sum_i a2[b,i,k] * c[b,i,h] )  (tmat slice, LDS only)
//   f-phase: for each 64-row i-chunk: a = a1@q, bb = a1@tTb;
//            out = [c, a, c*a, c*bb] via spill -> float4 nt stores.
struct TFP1 { unsigned short a2b[64][72]; unsigned short cb[64][72]; };
struct TFP2 { unsigned short a1b[64][72]; float spill[64][68]; };
union TFU { TFP1 p1; TFP2 p2; };

__global__ __launch_bounds__(256) void tf_kernel(
    const float* __restrict__ c, const float* __restrict__ q,
    const unsigned short* __restrict__ e2,
    const float* __restrict__ pcm, const float* __restrict__ pcs,
    const unsigned short* __restrict__ a1, float* __restrict__ out) {
    int b = blockIdx.y, h0 = blockIdx.x * 64;
    int t = threadIdx.x, tx = t & 15, ty = t >> 4;
    int lane = t & 63, w = t >> 6, lo = lane & 15, hi = lane >> 4;
    __shared__ __align__(16) TFU u_;
    __shared__ __align__(16) unsigned short qTb[64][72];  // [h][k] bf16
    __shared__ __align__(16) unsigned short tTb[64][72];  // [h][k] bf16 (tmat slice)
    __shared__ float sc_s[8][64];

    if (t < 64) {
        float pm[8];
        #pragma unroll
        for (int g = 0; g < 8; ++g) pm[g] = pcm[(b * 8 + g) * 64 + t];
        float M = pm[0];
        #pragma unroll
        for (int g = 1; g < 8; ++g) M = fmaxf(M, pm[g]);
        float S = 0.f, ee[8];
        #pragma unroll
        for (int g = 0; g < 8; ++g) {
            ee[g] = __expf(pm[g] - M);
            S += pcs[(b * 8 + g) * 64 + t] * ee[g];
        }
        float si = 1.f / S;
        #pragma unroll
        for (int g = 0; g < 8; ++g) sc_s[g][t] = ee[g] * si;
    }
    __syncthreads();

    // ---- t-phase: M=k, N=h, K=i (identical structure to validated t_mfma) ----
    f32x4 acc[4] = {{0.f,0.f,0.f,0.f},{0.f,0.f,0.f,0.f},{0.f,0.f,0.f,0.f},{0.f,0.f,0.f,0.f}};
    for (int ic = 0; ic < LC; ic += 64) {
        #pragma unroll
        for (int u = 0; u < 4; ++u) {
            int r = u * 16 + ty;
            int gi = b * LC + ic + r;
            float4 cv = *(const float4*)(c + (size_t)gi * HH + h0 + tx * 4);
            u_.p1.cb[tx * 4 + 0][r] = f2bf(cv.x);
            u_.p1.cb[tx * 4 + 1][r] = f2bf(cv.y);
            u_.p1.cb[tx * 4 + 2][r] = f2bf(cv.z);
            u_.p1.cb[tx * 4 + 3][r] = f2bf(cv.w);
            ushort4 ev = *(const ushort4*)(e2 + (size_t)gi * LQ + tx * 4);
            float4 scv = *(const float4*)(&sc_s[ic >> 6][tx * 4]);
            u_.p1.a2b[tx * 4 + 0][r] = f2bf(bf2f(ev.x) * scv.x);
            u_.p1.a2b[tx * 4 + 1][r] = f2bf(bf2f(ev.y) * scv.y);
            u_.p1.a2b[tx * 4 + 2][r] = f2bf(bf2f(ev.z) * scv.z);
            u_.p1.a2b[tx * 4 + 3][r] = f2bf(bf2f(ev.w) * scv.w);
        }
        __syncthreads();
        #pragma unroll
        for (int kk = 0; kk < 64; kk += 32) {
            short8 af = *(const short8*)(&u_.p1.a2b[16 * w + lo][kk + hi * 8]);
            #pragma unroll
            for (int jt = 0; jt < 4; ++jt) {
                short8 bf = *(const short8*)(&u_.p1.cb[16 * jt + lo][kk + hi * 8]);
                acc[jt] = __builtin_amdgcn_mfma_f32_16x16x32_bf16(af, bf, acc[jt], 0, 0, 0);
            }
        }
        __syncthreads();
    }
    // spill tmat slice to LDS bf16: D (k=16w+hi*4+e, h=16jt+lo) -> tTb[h][k]
    #pragma unroll
    for (int jt = 0; jt < 4; ++jt)
        #pragma unroll
        for (int e = 0; e < 4; ++e)
            tTb[16 * jt + lo][16 * w + hi * 4 + e] = f2bf(acc[jt][e]);
    // stage q slice -> qTb[h][k]
    #pragma unroll
    for (int u = 0; u < 4; ++u) {
        int idx = u * 256 + t;
        int k = idx >> 4, h4 = (idx & 15) * 4;
        float4 qv = *(const float4*)(q + ((size_t)(b * LQ + k)) * HH + h0 + h4);
        qTb[h4 + 0][k] = f2bf(qv.x); qTb[h4 + 1][k] = f2bf(qv.y);
        qTb[h4 + 2][k] = f2bf(qv.z); qTb[h4 + 3][k] = f2bf(qv.w);
    }
    __syncthreads();

    // ---- f-phase: 8 i-chunks of 64 rows ----
    for (int it = 0; it < 8; ++it) {
        int i0 = it * 64;
        // stage a1 chunk (raw bf16 copy, 16B per thread-task)
        #pragma unroll
        for (int u = 0; u < 2; ++u) {
            int idx = u * 256 + t;
            int r = idx >> 3, seg = idx & 7;
            *(short8*)(&u_.p2.a1b[r][seg * 8]) =
                *(const short8*)(a1 + (size_t)(b * LC + i0 + r) * LQ + seg * 8);
        }
        __syncthreads();
        f32x4 fa[4] = {{0.f,0.f,0.f,0.f},{0.f,0.f,0.f,0.f},{0.f,0.f,0.f,0.f},{0.f,0.f,0.f,0.f}};
        f32x4 fb[4] = {{0.f,0.f,0.f,0.f},{0.f,0.f,0.f,0.f},{0.f,0.f,0.f,0.f},{0.f,0.f,0.f,0.f}};
        #pragma unroll
        for (int kk = 0; kk < 64; kk += 32) {
            short8 af = *(const short8*)(&u_.p2.a1b[16 * w + lo][kk + hi * 8]);
            #pragma unroll
            for (int jt = 0; jt < 4; ++jt) {
                short8 bq = *(const short8*)(&qTb[16 * jt + lo][kk + hi * 8]);
                fa[jt] = __builtin_amdgcn_mfma_f32_16x16x32_bf16(af, bq, fa[jt], 0, 0, 0);
                short8 bt = *(const short8*)(&tTb[16 * jt + lo][kk + hi * 8]);
                fb[jt] = __builtin_amdgcn_mfma_f32_16x16x32_bf16(af, bt, fb[jt], 0, 0, 0);
            }
        }
        // Phase A: spill fa, write c / a / c*a
        #pragma unroll
        for (int jt = 0; jt < 4; ++jt)
            #pragma unroll
            for (int e = 0; e < 4; ++e)
                u_.p2.spill[16 * w + hi * 4 + e][16 * jt + lo] = fa[jt][e];
        __syncthreads();
        #pragma unroll
        for (int u = 0; u < 4; ++u) {
            int idx = u * 256 + t;
            int r = idx >> 4, c4 = (idx & 15) * 4;
            size_t gi = (size_t)(b * LC + i0 + r);
            float4 av = *(const float4*)(&u_.p2.spill[r][c4]);
            float4 cv = *(const float4*)(c + gi * HH + h0 + c4);
            float* orow = out + gi * 2048 + h0;
            nts(orow + c4, cv.x, cv.y, cv.z, cv.w);
            nts(orow + 512 + c4, av.x, av.y, av.z, av.w);
            nts(orow + 1024 + c4, cv.x * av.x, cv.y * av.y, cv.z * av.z, cv.w * av.w);
        }
        __syncthreads();
        // Phase B: spill fb, write c*bb
        #pragma unroll
        for (int jt = 0; jt < 4; ++jt)
            #pragma unroll
            for (int e = 0; e < 4; ++e)
                u_.p2.spill[16 * w + hi * 4 + e][16 * jt + lo] = fb[jt][e];
        __syncthreads();
        #pragma unroll
        for (int u = 0; u < 4; ++u) {
            int idx = u * 256 + t;
            int r = idx >> 4, c4 = (idx & 15) * 4;
            size_t gi = (size_t)(b * LC + i0 + r);
            float4 bv = *(const float4*)(&u_.p2.spill[r][c4]);
            float4 cv = *(const float4*)(c + gi * HH + h0 + c4);
            float* orow = out + gi * 2048 + h0;
            nts(orow + 1536 + c4, cv.x * bv.x, cv.y * bv.y, cv.z * bv.z, cv.w * bv.w);
        }
        __syncthreads();   // spill reused next chunk
    }
}

extern "C" void kernel_launch(void* const* d_in, const int* in_sizes, int n_in,
                              void* d_out, int out_size, void* d_ws, size_t ws_size,
                              hipStream_t stream) {
    const float* c   = (const float*)d_in[0];
    const float* q   = (const float*)d_in[1];
    const float* cw  = (const float*)d_in[4];
    const float* qw  = (const float*)d_in[5];
    const float* cqw = (const float*)d_in[6];
    float* out = (float*)d_out;

    unsigned short* e2 = (unsigned short*)d_ws;              // 1M bf16
    unsigned short* a1 = e2 + (size_t)BB * LC * LQ;          // 1M bf16
    float* pcm = (float*)(a1 + (size_t)BB * LC * LQ);        // 16384 f32
    float* pcs = pcm + BB * (LC / 64) * LQ;                  // 16384 f32

    s2_mfma_kernel<<<dim3(LC / 64, BB), 256, 0, stream>>>(c, q, cw, qw, cqw, e2, a1, pcm, pcs);
    tf_kernel<<<dim3(HH / 64, BB), 256, 0, stream>>>(c, q, e2, pcm, pcs, a1, out);
}

// Round 17
// 62.121 us; speedup vs baseline: 2.0058x; 1.0334x over previous
//
#include <hip/hip_runtime.h>
#include <math.h>

#define BB 32
#define LC 512
#define LQ 64
#define HH 512

typedef __attribute__((ext_vector_type(8))) short short8;
typedef __attribute__((ext_vector_type(4))) float f32x4;

__device__ __forceinline__ unsigned short f2bf(float x) {
    unsigned int u = __float_as_uint(x);
    return (unsigned short)((u + 0x7fffu + ((u >> 16) & 1u)) >> 16);
}
__device__ __forceinline__ float bf2f(unsigned short v) {
    return __uint_as_float(((unsigned int)v) << 16);
}
__device__ __forceinline__ void nts(float* p, float x, float y, float z, float w) {
    f32x4 v = {x, y, z, w};
    __builtin_nontemporal_store(v, (f32x4*)p);
}

// Kernel 1 (MFMA core + proven fp32 epilogue; a1/e2 stored bf16) — unchanged.
__global__ __launch_bounds__(256) void s2_mfma_kernel(
    const float* __restrict__ c, const float* __restrict__ q,
    const float* __restrict__ cw, const float* __restrict__ qw,
    const float* __restrict__ cqw,
    unsigned short* __restrict__ e2, unsigned short* __restrict__ a1,
    float* __restrict__ pcm, float* __restrict__ pcs) {
    int b = blockIdx.y, it = blockIdx.x, i0 = it * 64;
    int t = threadIdx.x, tx = t & 15, ty = t >> 4;
    int lane = t & 63, w = t >> 6, lo = lane & 15, hi = lane >> 4;
    __shared__ __align__(16) unsigned short cmb[64][72];  // [i][k] bf16
    __shared__ __align__(16) unsigned short qb[64][72];   // [j][k] bf16
    __shared__ float z2s[64][65];                         // fp32 z2 tile
    __shared__ float s0_s[64], s1_s[64], mt_s[64];
    __shared__ float redm[16][65], redp[16][65];
    f32x4 acc[4] = {{0.f,0.f,0.f,0.f},{0.f,0.f,0.f,0.f},{0.f,0.f,0.f,0.f},{0.f,0.f,0.f,0.f}};
    float ps0[4] = {0.f,0.f,0.f,0.f}, ps1[4] = {0.f,0.f,0.f,0.f};

    for (int h0 = 0; h0 < HH; h0 += 64) {
        #pragma unroll
        for (int u = 0; u < 4; ++u) {
            int r = u * 16 + ty;
            int h = tx * 4;
            float4 cv = *(const float4*)(c + ((size_t)(b * LC + i0 + r)) * HH + h0 + h);
            float4 wv = *(const float4*)(cqw + h0 + h);
            cmb[r][h + 0] = f2bf(cv.x * wv.x);
            cmb[r][h + 1] = f2bf(cv.y * wv.y);
            cmb[r][h + 2] = f2bf(cv.z * wv.z);
            cmb[r][h + 3] = f2bf(cv.w * wv.w);
            float4 cwv = *(const float4*)(cw + h0 + h);
            ps0[u] += cv.x * cwv.x + cv.y * cwv.y + cv.z * cwv.z + cv.w * cwv.w;
            float4 qv = *(const float4*)(q + ((size_t)(b * LQ + r)) * HH + h0 + h);
            qb[r][h + 0] = f2bf(qv.x);
            qb[r][h + 1] = f2bf(qv.y);
            qb[r][h + 2] = f2bf(qv.z);
            qb[r][h + 3] = f2bf(qv.w);
            float4 qwv = *(const float4*)(qw + h0 + h);
            ps1[u] += qv.x * qwv.x + qv.y * qwv.y + qv.z * qwv.z + qv.w * qwv.w;
        }
        __syncthreads();
        #pragma unroll
        for (int kk = 0; kk < 64; kk += 32) {
            short8 af = *(const short8*)(&cmb[16 * w + lo][kk + hi * 8]);
            #pragma unroll
            for (int jt = 0; jt < 4; ++jt) {
                short8 bf = *(const short8*)(&qb[16 * jt + lo][kk + hi * 8]);
                acc[jt] = __builtin_amdgcn_mfma_f32_16x16x32_bf16(af, bf, acc[jt], 0, 0, 0);
            }
        }
        __syncthreads();
    }

    #pragma unroll
    for (int jt = 0; jt < 4; ++jt)
        #pragma unroll
        for (int e = 0; e < 4; ++e)
            z2s[16 * w + hi * 4 + e][16 * jt + lo] = acc[jt][e];

    for (int off = 1; off < 16; off <<= 1) {
        #pragma unroll
        for (int u = 0; u < 4; ++u) {
            ps0[u] += __shfl_xor(ps0[u], off, 64);
            ps1[u] += __shfl_xor(ps1[u], off, 64);
        }
    }
    if (tx == 0) {
        #pragma unroll
        for (int u = 0; u < 4; ++u) {
            s0_s[u * 16 + ty] = ps0[u];
            s1_s[u * 16 + ty] = ps1[u];
        }
    }
    __syncthreads();

    float4 zacc[4];
    #pragma unroll
    for (int iy = 0; iy < 4; ++iy) zacc[iy] = *(const float4*)(&z2s[ty * 4 + iy][tx * 4]);

    float4 s1v = make_float4(s1_s[tx * 4 + 0], s1_s[tx * 4 + 1], s1_s[tx * 4 + 2], s1_s[tx * 4 + 3]);
    #pragma unroll
    for (int iy = 0; iy < 4; ++iy) {
        int gi = b * LC + i0 + ty * 4 + iy;
        float z0 = zacc[iy].x + s1v.x, z1 = zacc[iy].y + s1v.y;
        float z2v = zacc[iy].z + s1v.z, z3 = zacc[iy].w + s1v.w;
        float m = fmaxf(fmaxf(z0, z1), fmaxf(z2v, z3));
        for (int off = 1; off < 16; off <<= 1) m = fmaxf(m, __shfl_xor(m, off, 64));
        float e0 = __expf(z0 - m), e1 = __expf(z1 - m), e2v = __expf(z2v - m), e3 = __expf(z3 - m);
        float s = e0 + e1 + e2v + e3;
        for (int off = 1; off < 16; off <<= 1) s += __shfl_xor(s, off, 64);
        float si = 1.f / s;
        ushort4 av;
        av.x = f2bf(e0 * si); av.y = f2bf(e1 * si);
        av.z = f2bf(e2v * si); av.w = f2bf(e3 * si);
        *(ushort4*)(&a1[(size_t)gi * LQ + tx * 4]) = av;
    }

    float s0r[4] = {s0_s[ty * 4 + 0], s0_s[ty * 4 + 1], s0_s[ty * 4 + 2], s0_s[ty * 4 + 3]};
    #pragma unroll
    for (int jx = 0; jx < 4; ++jx) {
        float zc[4] = {(&zacc[0].x)[jx], (&zacc[1].x)[jx], (&zacc[2].x)[jx], (&zacc[3].x)[jx]};
        float m = zc[0] + s0r[0];
        m = fmaxf(m, zc[1] + s0r[1]);
        m = fmaxf(m, zc[2] + s0r[2]);
        m = fmaxf(m, zc[3] + s0r[3]);
        redm[ty][tx * 4 + jx] = m;
    }
    __syncthreads();
    if (t < 64) {
        float M = redm[0][t];
        #pragma unroll
        for (int g = 1; g < 16; ++g) M = fmaxf(M, redm[g][t]);
        mt_s[t] = M;
        pcm[(b * 8 + it) * 64 + t] = M;
    }
    __syncthreads();
    {
        float mj[4] = {mt_s[tx * 4 + 0], mt_s[tx * 4 + 1], mt_s[tx * 4 + 2], mt_s[tx * 4 + 3]};
        float colsum[4] = {0.f, 0.f, 0.f, 0.f};
        #pragma unroll
        for (int iy = 0; iy < 4; ++iy) {
            float e0 = __expf(zacc[iy].x + s0r[iy] - mj[0]);
            float e1 = __expf(zacc[iy].y + s0r[iy] - mj[1]);
            float e2v = __expf(zacc[iy].z + s0r[iy] - mj[2]);
            float e3 = __expf(zacc[iy].w + s0r[iy] - mj[3]);
            colsum[0] += e0; colsum[1] += e1; colsum[2] += e2v; colsum[3] += e3;
            int gi = b * LC + i0 + ty * 4 + iy;
            ushort4 evv;
            evv.x = f2bf(e0); evv.y = f2bf(e1); evv.z = f2bf(e2v); evv.w = f2bf(e3);
            *(ushort4*)(&e2[(size_t)gi * LQ + tx * 4]) = evv;
        }
        #pragma unroll
        for (int jx = 0; jx < 4; ++jx) redp[ty][tx * 4 + jx] = colsum[jx];
    }
    __syncthreads();
    if (t < 64) {
        float S = redp[0][t];
        #pragma unroll
        for (int g = 1; g < 16; ++g) S += redp[g][t];
        pcs[(b * 8 + it) * 64 + t] = S;
    }
}

// Kernel 2 (fused t+f, h-tile 32 -> 512 blocks, 2 resident/CU):
//   t-phase: tTb[h][k] = bf16( sum_i a2[b,i,k] * c[b,i,h] ), h-slice 32, LDS only
//   f-phase: per 64-row i-chunk: a = a1@q, bb = a1@tTb; out = [c, a, c*a, c*bb]
struct TFP1 { unsigned short a2b[64][72]; unsigned short cb[32][72]; };
struct TFP2 { unsigned short a1b[64][72]; float spill[64][36]; };
union TFU { TFP1 p1; TFP2 p2; };

__global__ __launch_bounds__(256) void tf_kernel(
    const float* __restrict__ c, const float* __restrict__ q,
    const unsigned short* __restrict__ e2,
    const float* __restrict__ pcm, const float* __restrict__ pcs,
    const unsigned short* __restrict__ a1, float* __restrict__ out) {
    int b = blockIdx.y, h0 = blockIdx.x * 32;
    int t = threadIdx.x;
    int lane = t & 63, w = t >> 6, lo = lane & 15, hi = lane >> 4;
    __shared__ __align__(16) TFU u_;
    __shared__ __align__(16) unsigned short qTb[32][72];  // [h][k] bf16
    __shared__ __align__(16) unsigned short tTb[32][72];  // [h][k] bf16 (tmat slice)
    __shared__ float sc_s[8][64];

    if (t < 64) {
        float pm[8];
        #pragma unroll
        for (int g = 0; g < 8; ++g) pm[g] = pcm[(b * 8 + g) * 64 + t];
        float M = pm[0];
        #pragma unroll
        for (int g = 1; g < 8; ++g) M = fmaxf(M, pm[g]);
        float S = 0.f, ee[8];
        #pragma unroll
        for (int g = 0; g < 8; ++g) {
            ee[g] = __expf(pm[g] - M);
            S += pcs[(b * 8 + g) * 64 + t] * ee[g];
        }
        float si = 1.f / S;
        #pragma unroll
        for (int g = 0; g < 8; ++g) sc_s[g][t] = ee[g] * si;
    }
    __syncthreads();

    // ---- t-phase: M=64 k, N=32 h, K=i ----
    f32x4 acc[2] = {{0.f,0.f,0.f,0.f},{0.f,0.f,0.f,0.f}};
    for (int ic = 0; ic < LC; ic += 64) {
        // stage c slice: 64 rows x 32 h -> cb[h][r]
        #pragma unroll
        for (int u = 0; u < 2; ++u) {
            int idx = u * 256 + t;
            int r = idx >> 3, h4 = (idx & 7) * 4;
            float4 cv = *(const float4*)(c + (size_t)(b * LC + ic + r) * HH + h0 + h4);
            u_.p1.cb[h4 + 0][r] = f2bf(cv.x);
            u_.p1.cb[h4 + 1][r] = f2bf(cv.y);
            u_.p1.cb[h4 + 2][r] = f2bf(cv.z);
            u_.p1.cb[h4 + 3][r] = f2bf(cv.w);
        }
        // stage a2 slice: 64 rows x 64 k -> a2b[k][r]
        #pragma unroll
        for (int u = 0; u < 4; ++u) {
            int idx = u * 256 + t;
            int r = idx >> 4, k4 = (idx & 15) * 4;
            ushort4 ev = *(const ushort4*)(e2 + (size_t)(b * LC + ic + r) * LQ + k4);
            float4 scv = *(const float4*)(&sc_s[ic >> 6][k4]);
            u_.p1.a2b[k4 + 0][r] = f2bf(bf2f(ev.x) * scv.x);
            u_.p1.a2b[k4 + 1][r] = f2bf(bf2f(ev.y) * scv.y);
            u_.p1.a2b[k4 + 2][r] = f2bf(bf2f(ev.z) * scv.z);
            u_.p1.a2b[k4 + 3][r] = f2bf(bf2f(ev.w) * scv.w);
        }
        __syncthreads();
        #pragma unroll
        for (int kk = 0; kk < 64; kk += 32) {
            short8 af = *(const short8*)(&u_.p1.a2b[16 * w + lo][kk + hi * 8]);
            #pragma unroll
            for (int jt = 0; jt < 2; ++jt) {
                short8 bf = *(const short8*)(&u_.p1.cb[16 * jt + lo][kk + hi * 8]);
                acc[jt] = __builtin_amdgcn_mfma_f32_16x16x32_bf16(af, bf, acc[jt], 0, 0, 0);
            }
        }
        __syncthreads();
    }
    // spill tmat slice: D (k=16w+hi*4+e, h=16jt+lo) -> tTb[h][k]
    #pragma unroll
    for (int jt = 0; jt < 2; ++jt)
        #pragma unroll
        for (int e = 0; e < 4; ++e)
            tTb[16 * jt + lo][16 * w + hi * 4 + e] = f2bf(acc[jt][e]);
    // stage q slice: 64 k x 32 h -> qTb[h][k]
    #pragma unroll
    for (int u = 0; u < 2; ++u) {
        int idx = u * 256 + t;
        int k = idx >> 3, h4 = (idx & 7) * 4;
        float4 qv = *(const float4*)(q + ((size_t)(b * LQ + k)) * HH + h0 + h4);
        qTb[h4 + 0][k] = f2bf(qv.x); qTb[h4 + 1][k] = f2bf(qv.y);
        qTb[h4 + 2][k] = f2bf(qv.z); qTb[h4 + 3][k] = f2bf(qv.w);
    }
    __syncthreads();

    // ---- f-phase: 8 i-chunks of 64 rows ----
    for (int it = 0; it < 8; ++it) {
        int i0 = it * 64;
        #pragma unroll
        for (int u = 0; u < 2; ++u) {
            int idx = u * 256 + t;
            int r = idx >> 3, seg = idx & 7;
            *(short8*)(&u_.p2.a1b[r][seg * 8]) =
                *(const short8*)(a1 + (size_t)(b * LC + i0 + r) * LQ + seg * 8);
        }
        __syncthreads();
        f32x4 fa[2] = {{0.f,0.f,0.f,0.f},{0.f,0.f,0.f,0.f}};
        f32x4 fb[2] = {{0.f,0.f,0.f,0.f},{0.f,0.f,0.f,0.f}};
        #pragma unroll
        for (int kk = 0; kk < 64; kk += 32) {
            short8 af = *(const short8*)(&u_.p2.a1b[16 * w + lo][kk + hi * 8]);
            #pragma unroll
            for (int jt = 0; jt < 2; ++jt) {
                short8 bq = *(const short8*)(&qTb[16 * jt + lo][kk + hi * 8]);
                fa[jt] = __builtin_amdgcn_mfma_f32_16x16x32_bf16(af, bq, fa[jt], 0, 0, 0);
                short8 bt = *(const short8*)(&tTb[16 * jt + lo][kk + hi * 8]);
                fb[jt] = __builtin_amdgcn_mfma_f32_16x16x32_bf16(af, bt, fb[jt], 0, 0, 0);
            }
        }
        // Phase A: spill fa, write c / a / c*a
        #pragma unroll
        for (int jt = 0; jt < 2; ++jt)
            #pragma unroll
            for (int e = 0; e < 4; ++e)
                u_.p2.spill[16 * w + hi * 4 + e][16 * jt + lo] = fa[jt][e];
        __syncthreads();
        #pragma unroll
        for (int u = 0; u < 2; ++u) {
            int idx = u * 256 + t;
            int r = idx >> 3, c4 = (idx & 7) * 4;
            size_t gi = (size_t)(b * LC + i0 + r);
            float4 av = *(const float4*)(&u_.p2.spill[r][c4]);
            float4 cv = *(const float4*)(c + gi * HH + h0 + c4);
            float* orow = out + gi * 2048 + h0;
            nts(orow + c4, cv.x, cv.y, cv.z, cv.w);
            nts(orow + 512 + c4, av.x, av.y, av.z, av.w);
            nts(orow + 1024 + c4, cv.x * av.x, cv.y * av.y, cv.z * av.z, cv.w * av.w);
        }
        __syncthreads();
        // Phase B: spill fb, write c*bb
        #pragma unroll
        for (int jt = 0; jt < 2; ++jt)
            #pragma unroll
            for (int e = 0; e < 4; ++e)
                u_.p2.spill[16 * w + hi * 4 + e][16 * jt + lo] = fb[jt][e];
        __syncthreads();
        #pragma unroll
        for (int u = 0; u < 2; ++u) {
            int idx = u * 256 + t;
            int r = idx >> 3, c4 = (idx & 7) * 4;
            size_t gi = (size_t)(b * LC + i0 + r);
            float4 bv = *(const float4*)(&u_.p2.spill[r][c4]);
            float4 cv = *(const float4*)(c + gi * HH + h0 + c4);
            float* orow = out + gi * 2048 + h0;
            nts(orow + 1536 + c4, cv.x * bv.x, cv.y * bv.y, cv.z * bv.z, cv.w * bv.w);
        }
        __syncthreads();   // spill reused next chunk
    }
}

extern "C" void kernel_launch(void* const* d_in, const int* in_sizes, int n_in,
                              void* d_out, int out_size, void* d_ws, size_t ws_size,
                              hipStream_t stream) {
    const float* c   = (const float*)d_in[0];
    const float* q   = (const float*)d_in[1];
    const float* cw  = (const float*)d_in[4];
    const float* qw  = (const float*)d_in[5];
    const float* cqw = (const float*)d_in[6];
    float* out = (float*)d_out;

    unsigned short* e2 = (unsigned short*)d_ws;              // 1M bf16
    unsigned short* a1 = e2 + (size_t)BB * LC * LQ;          // 1M bf16
    float* pcm = (float*)(a1 + (size_t)BB * LC * LQ);        // 16384 f32
    float* pcs = pcm + BB * (LC / 64) * LQ;                  // 16384 f32

    s2_mfma_kernel<<<dim3(LC / 64, BB), 256, 0, stream>>>(c, q, cw, qw, cqw, e2, a1, pcm, pcs);
    tf_kernel<<<dim3(HH / 32, BB), 256, 0, stream>>>(c, q, e2, pcm, pcs, a1, out);
}

// Round 18
// 61.857 us; speedup vs baseline: 2.0144x; 1.0043x over previous
//
#include <hip/hip_runtime.h>
#include <math.h>

#define BB 32
#define LC 512
#define LQ 64
#define HH 512

typedef __attribute__((ext_vector_type(8))) short short8;
typedef __attribute__((ext_vector_type(4))) float f32x4;

__device__ __forceinline__ unsigned short f2bf(float x) {
    unsigned int u = __float_as_uint(x);
    return (unsigned short)((u + 0x7fffu + ((u >> 16) & 1u)) >> 16);
}
__device__ __forceinline__ float bf2f(unsigned short v) {
    return __uint_as_float(((unsigned int)v) << 16);
}
__device__ __forceinline__ void nts(float* p, float x, float y, float z, float w) {
    f32x4 v = {x, y, z, w};
    __builtin_nontemporal_store(v, (f32x4*)p);
}

// Kernel 1 (MFMA core + proven fp32 epilogue; a1/e2 stored bf16) — unchanged.
__global__ __launch_bounds__(256) void s2_mfma_kernel(
    const float* __restrict__ c, const float* __restrict__ q,
    const float* __restrict__ cw, const float* __restrict__ qw,
    const float* __restrict__ cqw,
    unsigned short* __restrict__ e2, unsigned short* __restrict__ a1,
    float* __restrict__ pcm, float* __restrict__ pcs) {
    int b = blockIdx.y, it = blockIdx.x, i0 = it * 64;
    int t = threadIdx.x, tx = t & 15, ty = t >> 4;
    int lane = t & 63, w = t >> 6, lo = lane & 15, hi = lane >> 4;
    __shared__ __align__(16) unsigned short cmb[64][72];  // [i][k] bf16
    __shared__ __align__(16) unsigned short qb[64][72];   // [j][k] bf16
    __shared__ float z2s[64][65];                         // fp32 z2 tile
    __shared__ float s0_s[64], s1_s[64], mt_s[64];
    __shared__ float redm[16][65], redp[16][65];
    f32x4 acc[4] = {{0.f,0.f,0.f,0.f},{0.f,0.f,0.f,0.f},{0.f,0.f,0.f,0.f},{0.f,0.f,0.f,0.f}};
    float ps0[4] = {0.f,0.f,0.f,0.f}, ps1[4] = {0.f,0.f,0.f,0.f};

    for (int h0 = 0; h0 < HH; h0 += 64) {
        #pragma unroll
        for (int u = 0; u < 4; ++u) {
            int r = u * 16 + ty;
            int h = tx * 4;
            float4 cv = *(const float4*)(c + ((size_t)(b * LC + i0 + r)) * HH + h0 + h);
            float4 wv = *(const float4*)(cqw + h0 + h);
            cmb[r][h + 0] = f2bf(cv.x * wv.x);
            cmb[r][h + 1] = f2bf(cv.y * wv.y);
            cmb[r][h + 2] = f2bf(cv.z * wv.z);
            cmb[r][h + 3] = f2bf(cv.w * wv.w);
            float4 cwv = *(const float4*)(cw + h0 + h);
            ps0[u] += cv.x * cwv.x + cv.y * cwv.y + cv.z * cwv.z + cv.w * cwv.w;
            float4 qv = *(const float4*)(q + ((size_t)(b * LQ + r)) * HH + h0 + h);
            qb[r][h + 0] = f2bf(qv.x);
            qb[r][h + 1] = f2bf(qv.y);
            qb[r][h + 2] = f2bf(qv.z);
            qb[r][h + 3] = f2bf(qv.w);
            float4 qwv = *(const float4*)(qw + h0 + h);
            ps1[u] += qv.x * qwv.x + qv.y * qwv.y + qv.z * qwv.z + qv.w * qwv.w;
        }
        __syncthreads();
        #pragma unroll
        for (int kk = 0; kk < 64; kk += 32) {
            short8 af = *(const short8*)(&cmb[16 * w + lo][kk + hi * 8]);
            #pragma unroll
            for (int jt = 0; jt < 4; ++jt) {
                short8 bf = *(const short8*)(&qb[16 * jt + lo][kk + hi * 8]);
                acc[jt] = __builtin_amdgcn_mfma_f32_16x16x32_bf16(af, bf, acc[jt], 0, 0, 0);
            }
        }
        __syncthreads();
    }

    #pragma unroll
    for (int jt = 0; jt < 4; ++jt)
        #pragma unroll
        for (int e = 0; e < 4; ++e)
            z2s[16 * w + hi * 4 + e][16 * jt + lo] = acc[jt][e];

    for (int off = 1; off < 16; off <<= 1) {
        #pragma unroll
        for (int u = 0; u < 4; ++u) {
            ps0[u] += __shfl_xor(ps0[u], off, 64);
            ps1[u] += __shfl_xor(ps1[u], off, 64);
        }
    }
    if (tx == 0) {
        #pragma unroll
        for (int u = 0; u < 4; ++u) {
            s0_s[u * 16 + ty] = ps0[u];
            s1_s[u * 16 + ty] = ps1[u];
        }
    }
    __syncthreads();

    float4 zacc[4];
    #pragma unroll
    for (int iy = 0; iy < 4; ++iy) zacc[iy] = *(const float4*)(&z2s[ty * 4 + iy][tx * 4]);

    float4 s1v = make_float4(s1_s[tx * 4 + 0], s1_s[tx * 4 + 1], s1_s[tx * 4 + 2], s1_s[tx * 4 + 3]);
    #pragma unroll
    for (int iy = 0; iy < 4; ++iy) {
        int gi = b * LC + i0 + ty * 4 + iy;
        float z0 = zacc[iy].x + s1v.x, z1 = zacc[iy].y + s1v.y;
        float z2v = zacc[iy].z + s1v.z, z3 = zacc[iy].w + s1v.w;
        float m = fmaxf(fmaxf(z0, z1), fmaxf(z2v, z3));
        for (int off = 1; off < 16; off <<= 1) m = fmaxf(m, __shfl_xor(m, off, 64));
        float e0 = __expf(z0 - m), e1 = __expf(z1 - m), e2v = __expf(z2v - m), e3 = __expf(z3 - m);
        float s = e0 + e1 + e2v + e3;
        for (int off = 1; off < 16; off <<= 1) s += __shfl_xor(s, off, 64);
        float si = 1.f / s;
        ushort4 av;
        av.x = f2bf(e0 * si); av.y = f2bf(e1 * si);
        av.z = f2bf(e2v * si); av.w = f2bf(e3 * si);
        *(ushort4*)(&a1[(size_t)gi * LQ + tx * 4]) = av;
    }

    float s0r[4] = {s0_s[ty * 4 + 0], s0_s[ty * 4 + 1], s0_s[ty * 4 + 2], s0_s[ty * 4 + 3]};
    #pragma unroll
    for (int jx = 0; jx < 4; ++jx) {
        float zc[4] = {(&zacc[0].x)[jx], (&zacc[1].x)[jx], (&zacc[2].x)[jx], (&zacc[3].x)[jx]};
        float m = zc[0] + s0r[0];
        m = fmaxf(m, zc[1] + s0r[1]);
        m = fmaxf(m, zc[2] + s0r[2]);
        m = fmaxf(m, zc[3] + s0r[3]);
        redm[ty][tx * 4 + jx] = m;
    }
    __syncthreads();
    if (t < 64) {
        float M = redm[0][t];
        #pragma unroll
        for (int g = 1; g < 16; ++g) M = fmaxf(M, redm[g][t]);
        mt_s[t] = M;
        pcm[(b * 8 + it) * 64 + t] = M;
    }
    __syncthreads();
    {
        float mj[4] = {mt_s[tx * 4 + 0], mt_s[tx * 4 + 1], mt_s[tx * 4 + 2], mt_s[tx * 4 + 3]};
        float colsum[4] = {0.f, 0.f, 0.f, 0.f};
        #pragma unroll
        for (int iy = 0; iy < 4; ++iy) {
            float e0 = __expf(zacc[iy].x + s0r[iy] - mj[0]);
            float e1 = __expf(zacc[iy].y + s0r[iy] - mj[1]);
            float e2v = __expf(zacc[iy].z + s0r[iy] - mj[2]);
            float e3 = __expf(zacc[iy].w + s0r[iy] - mj[3]);
            colsum[0] += e0; colsum[1] += e1; colsum[2] += e2v; colsum[3] += e3;
            int gi = b * LC + i0 + ty * 4 + iy;
            ushort4 evv;
            evv.x = f2bf(e0); evv.y = f2bf(e1); evv.z = f2bf(e2v); evv.w = f2bf(e3);
            *(ushort4*)(&e2[(size_t)gi * LQ + tx * 4]) = evv;
        }
        #pragma unroll
        for (int jx = 0; jx < 4; ++jx) redp[ty][tx * 4 + jx] = colsum[jx];
    }
    __syncthreads();
    if (t < 64) {
        float S = redp[0][t];
        #pragma unroll
        for (int g = 1; g < 16; ++g) S += redp[g][t];
        pcs[(b * 8 + it) * 64 + t] = S;
    }
}

// Kernel 2 (fused t+f, h-tile 32, 512 blocks, 2/CU):
//   t-phase unchanged; f-phase: double-buffered a1 staging, single fa+fb spill,
//   2 barriers/chunk (was 4), all 4 out sections in one store pass.
struct TFP1 { unsigned short a2b[64][72]; unsigned short cb[32][72]; };
struct TFP2 { unsigned short a1b[2][64][72]; float spill[64][72]; };
union TFU { TFP1 p1; TFP2 p2; };

__global__ __launch_bounds__(256) void tf_kernel(
    const float* __restrict__ c, const float* __restrict__ q,
    const unsigned short* __restrict__ e2,
    const float* __restrict__ pcm, const float* __restrict__ pcs,
    const unsigned short* __restrict__ a1, float* __restrict__ out) {
    int b = blockIdx.y, h0 = blockIdx.x * 32;
    int t = threadIdx.x;
    int lane = t & 63, w = t >> 6, lo = lane & 15, hi = lane >> 4;
    __shared__ __align__(16) TFU u_;
    __shared__ __align__(16) unsigned short qTb[32][72];  // [h][k] bf16
    __shared__ __align__(16) unsigned short tTb[32][72];  // [h][k] bf16 (tmat slice)
    __shared__ float sc_s[8][64];

    if (t < 64) {
        float pm[8];
        #pragma unroll
        for (int g = 0; g < 8; ++g) pm[g] = pcm[(b * 8 + g) * 64 + t];
        float M = pm[0];
        #pragma unroll
        for (int g = 1; g < 8; ++g) M = fmaxf(M, pm[g]);
        float S = 0.f, ee[8];
        #pragma unroll
        for (int g = 0; g < 8; ++g) {
            ee[g] = __expf(pm[g] - M);
            S += pcs[(b * 8 + g) * 64 + t] * ee[g];
        }
        float si = 1.f / S;
        #pragma unroll
        for (int g = 0; g < 8; ++g) sc_s[g][t] = ee[g] * si;
    }
    __syncthreads();

    // ---- t-phase: M=64 k, N=32 h, K=i ----
    f32x4 acc[2] = {{0.f,0.f,0.f,0.f},{0.f,0.f,0.f,0.f}};
    for (int ic = 0; ic < LC; ic += 64) {
        #pragma unroll
        for (int u = 0; u < 2; ++u) {
            int idx = u * 256 + t;
            int r = idx >> 3, h4 = (idx & 7) * 4;
            float4 cv = *(const float4*)(c + (size_t)(b * LC + ic + r) * HH + h0 + h4);
            u_.p1.cb[h4 + 0][r] = f2bf(cv.x);
            u_.p1.cb[h4 + 1][r] = f2bf(cv.y);
            u_.p1.cb[h4 + 2][r] = f2bf(cv.z);
            u_.p1.cb[h4 + 3][r] = f2bf(cv.w);
        }
        #pragma unroll
        for (int u = 0; u < 4; ++u) {
            int idx = u * 256 + t;
            int r = idx >> 4, k4 = (idx & 15) * 4;
            ushort4 ev = *(const ushort4*)(e2 + (size_t)(b * LC + ic + r) * LQ + k4);
            float4 scv = *(const float4*)(&sc_s[ic >> 6][k4]);
            u_.p1.a2b[k4 + 0][r] = f2bf(bf2f(ev.x) * scv.x);
            u_.p1.a2b[k4 + 1][r] = f2bf(bf2f(ev.y) * scv.y);
            u_.p1.a2b[k4 + 2][r] = f2bf(bf2f(ev.z) * scv.z);
            u_.p1.a2b[k4 + 3][r] = f2bf(bf2f(ev.w) * scv.w);
        }
        __syncthreads();
        #pragma unroll
        for (int kk = 0; kk < 64; kk += 32) {
            short8 af = *(const short8*)(&u_.p1.a2b[16 * w + lo][kk + hi * 8]);
            #pragma unroll
            for (int jt = 0; jt < 2; ++jt) {
                short8 bf = *(const short8*)(&u_.p1.cb[16 * jt + lo][kk + hi * 8]);
                acc[jt] = __builtin_amdgcn_mfma_f32_16x16x32_bf16(af, bf, acc[jt], 0, 0, 0);
            }
        }
        __syncthreads();
    }
    // spill tmat slice: D (k=16w+hi*4+e, h=16jt+lo) -> tTb[h][k]
    #pragma unroll
    for (int jt = 0; jt < 2; ++jt)
        #pragma unroll
        for (int e = 0; e < 4; ++e)
            tTb[16 * jt + lo][16 * w + hi * 4 + e] = f2bf(acc[jt][e]);
    // stage q slice -> qTb[h][k]
    #pragma unroll
    for (int u = 0; u < 2; ++u) {
        int idx = u * 256 + t;
        int k = idx >> 3, h4 = (idx & 7) * 4;
        float4 qv = *(const float4*)(q + ((size_t)(b * LQ + k)) * HH + h0 + h4);
        qTb[h4 + 0][k] = f2bf(qv.x); qTb[h4 + 1][k] = f2bf(qv.y);
        qTb[h4 + 2][k] = f2bf(qv.z); qTb[h4 + 3][k] = f2bf(qv.w);
    }
    // prologue: stage a1 chunk 0 into buffer 0
    #pragma unroll
    for (int u = 0; u < 2; ++u) {
        int idx = u * 256 + t;
        int r = idx >> 3, seg = idx & 7;
        *(short8*)(&u_.p2.a1b[0][r][seg * 8]) =
            *(const short8*)(a1 + (size_t)(b * LC + r) * LQ + seg * 8);
    }
    __syncthreads();

    // ---- f-phase: 8 i-chunks, double-buffered a1, 2 barriers/chunk ----
    for (int it = 0; it < 8; ++it) {
        int cur = it & 1, nxt = cur ^ 1;
        int i0 = it * 64;
        if (it < 7) {
            #pragma unroll
            for (int u = 0; u < 2; ++u) {
                int idx = u * 256 + t;
                int r = idx >> 3, seg = idx & 7;
                *(short8*)(&u_.p2.a1b[nxt][r][seg * 8]) =
                    *(const short8*)(a1 + (size_t)(b * LC + i0 + 64 + r) * LQ + seg * 8);
            }
        }
        f32x4 fa[2] = {{0.f,0.f,0.f,0.f},{0.f,0.f,0.f,0.f}};
        f32x4 fb[2] = {{0.f,0.f,0.f,0.f},{0.f,0.f,0.f,0.f}};
        #pragma unroll
        for (int kk = 0; kk < 64; kk += 32) {
            short8 af = *(const short8*)(&u_.p2.a1b[cur][16 * w + lo][kk + hi * 8]);
            #pragma unroll
            for (int jt = 0; jt < 2; ++jt) {
                short8 bq = *(const short8*)(&qTb[16 * jt + lo][kk + hi * 8]);
                fa[jt] = __builtin_amdgcn_mfma_f32_16x16x32_bf16(af, bq, fa[jt], 0, 0, 0);
                short8 bt = *(const short8*)(&tTb[16 * jt + lo][kk + hi * 8]);
                fb[jt] = __builtin_amdgcn_mfma_f32_16x16x32_bf16(af, bt, fb[jt], 0, 0, 0);
            }
        }
        // single spill: fa -> cols 0..31, fb -> cols 32..63
        #pragma unroll
        for (int jt = 0; jt < 2; ++jt)
            #pragma unroll
            for (int e = 0; e < 4; ++e) {
                u_.p2.spill[16 * w + hi * 4 + e][16 * jt + lo] = fa[jt][e];
                u_.p2.spill[16 * w + hi * 4 + e][32 + 16 * jt + lo] = fb[jt][e];
            }
        __syncthreads();
        // one store pass: all 4 sections
        #pragma unroll
        for (int u = 0; u < 2; ++u) {
            int idx = u * 256 + t;
            int r = idx >> 3, c4 = (idx & 7) * 4;
            size_t gi = (size_t)(b * LC + i0 + r);
            float4 av = *(const float4*)(&u_.p2.spill[r][c4]);
            float4 bv = *(const float4*)(&u_.p2.spill[r][32 + c4]);
            float4 cv = *(const float4*)(c + gi * HH + h0 + c4);
            float* orow = out + gi * 2048 + h0;
            nts(orow + c4, cv.x, cv.y, cv.z, cv.w);
            nts(orow + 512 + c4, av.x, av.y, av.z, av.w);
            nts(orow + 1024 + c4, cv.x * av.x, cv.y * av.y, cv.z * av.z, cv.w * av.w);
            nts(orow + 1536 + c4, cv.x * bv.x, cv.y * bv.y, cv.z * bv.z, cv.w * bv.w);
        }
        __syncthreads();   // spill + a1b[cur] safe to overwrite next iter
    }
}

extern "C" void kernel_launch(void* const* d_in, const int* in_sizes, int n_in,
                              void* d_out, int out_size, void* d_ws, size_t ws_size,
                              hipStream_t stream) {
    const float* c   = (const float*)d_in[0];
    const float* q   = (const float*)d_in[1];
    const float* cw  = (const float*)d_in[4];
    const float* qw  = (const float*)d_in[5];
    const float* cqw = (const float*)d_in[6];
    float* out = (float*)d_out;

    unsigned short* e2 = (unsigned short*)d_ws;              // 1M bf16
    unsigned short* a1 = e2 + (size_t)BB * LC * LQ;          // 1M bf16
    float* pcm = (float*)(a1 + (size_t)BB * LC * LQ);        // 16384 f32
    float* pcs = pcm + BB * (LC / 64) * LQ;                  // 16384 f32

    s2_mfma_kernel<<<dim3(LC / 64, BB), 256, 0, stream>>>(c, q, cw, qw, cqw, e2, a1, pcm, pcs);
    tf_kernel<<<dim3(HH / 32, BB), 256, 0, stream>>>(c, q, e2, pcm, pcs, a1, out);
}

// Round 19
// 58.426 us; speedup vs baseline: 2.1327x; 1.0587x over previous
//
#include <hip/hip_runtime.h>
#include <math.h>

#define BB 32
#define LC 512
#define LQ 64
#define HH 512

typedef __attribute__((ext_vector_type(8))) short short8;
typedef __attribute__((ext_vector_type(4))) float f32x4;

__device__ __forceinline__ unsigned short f2bf(float x) {
    unsigned int u = __float_as_uint(x);
    return (unsigned short)((u + 0x7fffu + ((u >> 16) & 1u)) >> 16);
}
__device__ __forceinline__ float bf2f(unsigned short v) {
    return __uint_as_float(((unsigned int)v) << 16);
}
__device__ __forceinline__ void nts(float* p, float x, float y, float z, float w) {
    f32x4 v = {x, y, z, w};
    __builtin_nontemporal_store(v, (f32x4*)p);
}

// Kernel 1 (MFMA core + proven fp32 epilogue; a1/e2 stored bf16).
// XCD swizzle: each XCD gets a contiguous 32-block range = 4 batches.
__global__ __launch_bounds__(256) void s2_mfma_kernel(
    const float* __restrict__ c, const float* __restrict__ q,
    const float* __restrict__ cw, const float* __restrict__ qw,
    const float* __restrict__ cqw,
    unsigned short* __restrict__ e2, unsigned short* __restrict__ a1,
    float* __restrict__ pcm, float* __restrict__ pcs) {
    int lin = blockIdx.x + (int)gridDim.x * blockIdx.y;   // 0..255
    int swz = (lin & 7) * 32 + (lin >> 3);                // XCD-contiguous
    int it = swz & 7, b = swz >> 3;
    int i0 = it * 64;
    int t = threadIdx.x, tx = t & 15, ty = t >> 4;
    int lane = t & 63, w = t >> 6, lo = lane & 15, hi = lane >> 4;
    __shared__ __align__(16) unsigned short cmb[64][72];  // [i][k] bf16
    __shared__ __align__(16) unsigned short qb[64][72];   // [j][k] bf16
    __shared__ float z2s[64][65];                         // fp32 z2 tile
    __shared__ float s0_s[64], s1_s[64], mt_s[64];
    __shared__ float redm[16][65], redp[16][65];
    f32x4 acc[4] = {{0.f,0.f,0.f,0.f},{0.f,0.f,0.f,0.f},{0.f,0.f,0.f,0.f},{0.f,0.f,0.f,0.f}};
    float ps0[4] = {0.f,0.f,0.f,0.f}, ps1[4] = {0.f,0.f,0.f,0.f};

    for (int h0 = 0; h0 < HH; h0 += 64) {
        #pragma unroll
        for (int u = 0; u < 4; ++u) {
            int r = u * 16 + ty;
            int h = tx * 4;
            float4 cv = *(const float4*)(c + ((size_t)(b * LC + i0 + r)) * HH + h0 + h);
            float4 wv = *(const float4*)(cqw + h0 + h);
            cmb[r][h + 0] = f2bf(cv.x * wv.x);
            cmb[r][h + 1] = f2bf(cv.y * wv.y);
            cmb[r][h + 2] = f2bf(cv.z * wv.z);
            cmb[r][h + 3] = f2bf(cv.w * wv.w);
            float4 cwv = *(const float4*)(cw + h0 + h);
            ps0[u] += cv.x * cwv.x + cv.y * cwv.y + cv.z * cwv.z + cv.w * cwv.w;
            float4 qv = *(const float4*)(q + ((size_t)(b * LQ + r)) * HH + h0 + h);
            qb[r][h + 0] = f2bf(qv.x);
            qb[r][h + 1] = f2bf(qv.y);
            qb[r][h + 2] = f2bf(qv.z);
            qb[r][h + 3] = f2bf(qv.w);
            float4 qwv = *(const float4*)(qw + h0 + h);
            ps1[u] += qv.x * qwv.x + qv.y * qwv.y + qv.z * qwv.z + qv.w * qwv.w;
        }
        __syncthreads();
        #pragma unroll
        for (int kk = 0; kk < 64; kk += 32) {
            short8 af = *(const short8*)(&cmb[16 * w + lo][kk + hi * 8]);
            #pragma unroll
            for (int jt = 0; jt < 4; ++jt) {
                short8 bf = *(const short8*)(&qb[16 * jt + lo][kk + hi * 8]);
                acc[jt] = __builtin_amdgcn_mfma_f32_16x16x32_bf16(af, bf, acc[jt], 0, 0, 0);
            }
        }
        __syncthreads();
    }

    #pragma unroll
    for (int jt = 0; jt < 4; ++jt)
        #pragma unroll
        for (int e = 0; e < 4; ++e)
            z2s[16 * w + hi * 4 + e][16 * jt + lo] = acc[jt][e];

    for (int off = 1; off < 16; off <<= 1) {
        #pragma unroll
        for (int u = 0; u < 4; ++u) {
            ps0[u] += __shfl_xor(ps0[u], off, 64);
            ps1[u] += __shfl_xor(ps1[u], off, 64);
        }
    }
    if (tx == 0) {
        #pragma unroll
        for (int u = 0; u < 4; ++u) {
            s0_s[u * 16 + ty] = ps0[u];
            s1_s[u * 16 + ty] = ps1[u];
        }
    }
    __syncthreads();

    float4 zacc[4];
    #pragma unroll
    for (int iy = 0; iy < 4; ++iy) zacc[iy] = *(const float4*)(&z2s[ty * 4 + iy][tx * 4]);

    float4 s1v = make_float4(s1_s[tx * 4 + 0], s1_s[tx * 4 + 1], s1_s[tx * 4 + 2], s1_s[tx * 4 + 3]);
    #pragma unroll
    for (int iy = 0; iy < 4; ++iy) {
        int gi = b * LC + i0 + ty * 4 + iy;
        float z0 = zacc[iy].x + s1v.x, z1 = zacc[iy].y + s1v.y;
        float z2v = zacc[iy].z + s1v.z, z3 = zacc[iy].w + s1v.w;
        float m = fmaxf(fmaxf(z0, z1), fmaxf(z2v, z3));
        for (int off = 1; off < 16; off <<= 1) m = fmaxf(m, __shfl_xor(m, off, 64));
        float e0 = __expf(z0 - m), e1 = __expf(z1 - m), e2v = __expf(z2v - m), e3 = __expf(z3 - m);
        float s = e0 + e1 + e2v + e3;
        for (int off = 1; off < 16; off <<= 1) s += __shfl_xor(s, off, 64);
        float si = 1.f / s;
        ushort4 av;
        av.x = f2bf(e0 * si); av.y = f2bf(e1 * si);
        av.z = f2bf(e2v * si); av.w = f2bf(e3 * si);
        *(ushort4*)(&a1[(size_t)gi * LQ + tx * 4]) = av;
    }

    float s0r[4] = {s0_s[ty * 4 + 0], s0_s[ty * 4 + 1], s0_s[ty * 4 + 2], s0_s[ty * 4 + 3]};
    #pragma unroll
    for (int jx = 0; jx < 4; ++jx) {
        float zc[4] = {(&zacc[0].x)[jx], (&zacc[1].x)[jx], (&zacc[2].x)[jx], (&zacc[3].x)[jx]};
        float m = zc[0] + s0r[0];
        m = fmaxf(m, zc[1] + s0r[1]);
        m = fmaxf(m, zc[2] + s0r[2]);
        m = fmaxf(m, zc[3] + s0r[3]);
        redm[ty][tx * 4 + jx] = m;
    }
    __syncthreads();
    if (t < 64) {
        float M = redm[0][t];
        #pragma unroll
        for (int g = 1; g < 16; ++g) M = fmaxf(M, redm[g][t]);
        mt_s[t] = M;
        pcm[(b * 8 + it) * 64 + t] = M;
    }
    __syncthreads();
    {
        float mj[4] = {mt_s[tx * 4 + 0], mt_s[tx * 4 + 1], mt_s[tx * 4 + 2], mt_s[tx * 4 + 3]};
        float colsum[4] = {0.f, 0.f, 0.f, 0.f};
        #pragma unroll
        for (int iy = 0; iy < 4; ++iy) {
            float e0 = __expf(zacc[iy].x + s0r[iy] - mj[0]);
            float e1 = __expf(zacc[iy].y + s0r[iy] - mj[1]);
            float e2v = __expf(zacc[iy].z + s0r[iy] - mj[2]);
            float e3 = __expf(zacc[iy].w + s0r[iy] - mj[3]);
            colsum[0] += e0; colsum[1] += e1; colsum[2] += e2v; colsum[3] += e3;
            int gi = b * LC + i0 + ty * 4 + iy;
            ushort4 evv;
            evv.x = f2bf(e0); evv.y = f2bf(e1); evv.z = f2bf(e2v); evv.w = f2bf(e3);
            *(ushort4*)(&e2[(size_t)gi * LQ + tx * 4]) = evv;
        }
        #pragma unroll
        for (int jx = 0; jx < 4; ++jx) redp[ty][tx * 4 + jx] = colsum[jx];
    }
    __syncthreads();
    if (t < 64) {
        float S = redp[0][t];
        #pragma unroll
        for (int g = 1; g < 16; ++g) S += redp[g][t];
        pcs[(b * 8 + it) * 64 + t] = S;
    }
}

// Kernel 2 (fused t+f, h-tile 32, 512 blocks, 2/CU).
// XCD swizzle: each XCD gets 64 contiguous blocks = 4 complete batches
// (e2/a1/q for 4 b's ≈ 1 MB -> L2-resident shared reads).
struct TFP1 { unsigned short a2b[64][72]; unsigned short cb[32][72]; };
struct TFP2 { unsigned short a1b[2][64][72]; float spill[64][72]; };
union TFU { TFP1 p1; TFP2 p2; };

__global__ __launch_bounds__(256) void tf_kernel(
    const float* __restrict__ c, const float* __restrict__ q,
    const unsigned short* __restrict__ e2,
    const float* __restrict__ pcm, const float* __restrict__ pcs,
    const unsigned short* __restrict__ a1, float* __restrict__ out) {
    int lin = blockIdx.x + (int)gridDim.x * blockIdx.y;   // 0..511
    int swz = (lin & 7) * 64 + (lin >> 3);                // XCD-contiguous
    int h0 = (swz & 15) * 32, b = swz >> 4;
    int t = threadIdx.x;
    int lane = t & 63, w = t >> 6, lo = lane & 15, hi = lane >> 4;
    __shared__ __align__(16) TFU u_;
    __shared__ __align__(16) unsigned short qTb[32][72];  // [h][k] bf16
    __shared__ __align__(16) unsigned short tTb[32][72];  // [h][k] bf16 (tmat slice)
    __shared__ float sc_s[8][64];

    if (t < 64) {
        float pm[8];
        #pragma unroll
        for (int g = 0; g < 8; ++g) pm[g] = pcm[(b * 8 + g) * 64 + t];
        float M = pm[0];
        #pragma unroll
        for (int g = 1; g < 8; ++g) M = fmaxf(M, pm[g]);
        float S = 0.f, ee[8];
        #pragma unroll
        for (int g = 0; g < 8; ++g) {
            ee[g] = __expf(pm[g] - M);
            S += pcs[(b * 8 + g) * 64 + t] * ee[g];
        }
        float si = 1.f / S;
        #pragma unroll
        for (int g = 0; g < 8; ++g) sc_s[g][t] = ee[g] * si;
    }
    __syncthreads();

    // ---- t-phase: M=64 k, N=32 h, K=i ----
    f32x4 acc[2] = {{0.f,0.f,0.f,0.f},{0.f,0.f,0.f,0.f}};
    for (int ic = 0; ic < LC; ic += 64) {
        #pragma unroll
        for (int u = 0; u < 2; ++u) {
            int idx = u * 256 + t;
            int r = idx >> 3, h4 = (idx & 7) * 4;
            float4 cv = *(const float4*)(c + (size_t)(b * LC + ic + r) * HH + h0 + h4);
            u_.p1.cb[h4 + 0][r] = f2bf(cv.x);
            u_.p1.cb[h4 + 1][r] = f2bf(cv.y);
            u_.p1.cb[h4 + 2][r] = f2bf(cv.z);
            u_.p1.cb[h4 + 3][r] = f2bf(cv.w);
        }
        #pragma unroll
        for (int u = 0; u < 4; ++u) {
            int idx = u * 256 + t;
            int r = idx >> 4, k4 = (idx & 15) * 4;
            ushort4 ev = *(const ushort4*)(e2 + (size_t)(b * LC + ic + r) * LQ + k4);
            float4 scv = *(const float4*)(&sc_s[ic >> 6][k4]);
            u_.p1.a2b[k4 + 0][r] = f2bf(bf2f(ev.x) * scv.x);
            u_.p1.a2b[k4 + 1][r] = f2bf(bf2f(ev.y) * scv.y);
            u_.p1.a2b[k4 + 2][r] = f2bf(bf2f(ev.z) * scv.z);
            u_.p1.a2b[k4 + 3][r] = f2bf(bf2f(ev.w) * scv.w);
        }
        __syncthreads();
        #pragma unroll
        for (int kk = 0; kk < 64; kk += 32) {
            short8 af = *(const short8*)(&u_.p1.a2b[16 * w + lo][kk + hi * 8]);
            #pragma unroll
            for (int jt = 0; jt < 2; ++jt) {
                short8 bf = *(const short8*)(&u_.p1.cb[16 * jt + lo][kk + hi * 8]);
                acc[jt] = __builtin_amdgcn_mfma_f32_16x16x32_bf16(af, bf, acc[jt], 0, 0, 0);
            }
        }
        __syncthreads();
    }
    // spill tmat slice: D (k=16w+hi*4+e, h=16jt+lo) -> tTb[h][k]
    #pragma unroll
    for (int jt = 0; jt < 2; ++jt)
        #pragma unroll
        for (int e = 0; e < 4; ++e)
            tTb[16 * jt + lo][16 * w + hi * 4 + e] = f2bf(acc[jt][e]);
    // stage q slice -> qTb[h][k]
    #pragma unroll
    for (int u = 0; u < 2; ++u) {
        int idx = u * 256 + t;
        int k = idx >> 3, h4 = (idx & 7) * 4;
        float4 qv = *(const float4*)(q + ((size_t)(b * LQ + k)) * HH + h0 + h4);
        qTb[h4 + 0][k] = f2bf(qv.x); qTb[h4 + 1][k] = f2bf(qv.y);
        qTb[h4 + 2][k] = f2bf(qv.z); qTb[h4 + 3][k] = f2bf(qv.w);
    }
    // prologue: stage a1 chunk 0 into buffer 0
    #pragma unroll
    for (int u = 0; u < 2; ++u) {
        int idx = u * 256 + t;
        int r = idx >> 3, seg = idx & 7;
        *(short8*)(&u_.p2.a1b[0][r][seg * 8]) =
            *(const short8*)(a1 + (size_t)(b * LC + r) * LQ + seg * 8);
    }
    __syncthreads();

    // ---- f-phase: 8 i-chunks, double-buffered a1, 2 barriers/chunk ----
    for (int it = 0; it < 8; ++it) {
        int cur = it & 1, nxt = cur ^ 1;
        int i0 = it * 64;
        if (it < 7) {
            #pragma unroll
            for (int u = 0; u < 2; ++u) {
                int idx = u * 256 + t;
                int r = idx >> 3, seg = idx & 7;
                *(short8*)(&u_.p2.a1b[nxt][r][seg * 8]) =
                    *(const short8*)(a1 + (size_t)(b * LC + i0 + 64 + r) * LQ + seg * 8);
            }
        }
        f32x4 fa[2] = {{0.f,0.f,0.f,0.f},{0.f,0.f,0.f,0.f}};
        f32x4 fb[2] = {{0.f,0.f,0.f,0.f},{0.f,0.f,0.f,0.f}};
        #pragma unroll
        for (int kk = 0; kk < 64; kk += 32) {
            short8 af = *(const short8*)(&u_.p2.a1b[cur][16 * w + lo][kk + hi * 8]);
            #pragma unroll
            for (int jt = 0; jt < 2; ++jt) {
                short8 bq = *(const short8*)(&qTb[16 * jt + lo][kk + hi * 8]);
                fa[jt] = __builtin_amdgcn_mfma_f32_16x16x32_bf16(af, bq, fa[jt], 0, 0, 0);
                short8 bt = *(const short8*)(&tTb[16 * jt + lo][kk + hi * 8]);
                fb[jt] = __builtin_amdgcn_mfma_f32_16x16x32_bf16(af, bt, fb[jt], 0, 0, 0);
            }
        }
        // single spill: fa -> cols 0..31, fb -> cols 32..63
        #pragma unroll
        for (int jt = 0; jt < 2; ++jt)
            #pragma unroll
            for (int e = 0; e < 4; ++e) {
                u_.p2.spill[16 * w + hi * 4 + e][16 * jt + lo] = fa[jt][e];
                u_.p2.spill[16 * w + hi * 4 + e][32 + 16 * jt + lo] = fb[jt][e];
            }
        __syncthreads();
        // one store pass: all 4 sections
        #pragma unroll
        for (int u = 0; u < 2; ++u) {
            int idx = u * 256 + t;
            int r = idx >> 3, c4 = (idx & 7) * 4;
            size_t gi = (size_t)(b * LC + i0 + r);
            float4 av = *(const float4*)(&u_.p2.spill[r][c4]);
            float4 bv = *(const float4*)(&u_.p2.spill[r][32 + c4]);
            float4 cv = *(const float4*)(c + gi * HH + h0 + c4);
            float* orow = out + gi * 2048 + h0;
            nts(orow + c4, cv.x, cv.y, cv.z, cv.w);
            nts(orow + 512 + c4, av.x, av.y, av.z, av.w);
            nts(orow + 1024 + c4, cv.x * av.x, cv.y * av.y, cv.z * av.z, cv.w * av.w);
            nts(orow + 1536 + c4, cv.x * bv.x, cv.y * bv.y, cv.z * bv.z, cv.w * bv.w);
        }
        __syncthreads();   // spill + a1b[cur] safe to overwrite next iter
    }
}

extern "C" void kernel_launch(void* const* d_in, const int* in_sizes, int n_in,
                              void* d_out, int out_size, void* d_ws, size_t ws_size,
                              hipStream_t stream) {
    const float* c   = (const float*)d_in[0];
    const float* q   = (const float*)d_in[1];
    const float* cw  = (const float*)d_in[4];
    const float* qw  = (const float*)d_in[5];
    const float* cqw = (const float*)d_in[6];
    float* out = (float*)d_out;

    unsigned short* e2 = (unsigned short*)d_ws;              // 1M bf16
    unsigned short* a1 = e2 + (size_t)BB * LC * LQ;          // 1M bf16
    float* pcm = (float*)(a1 + (size_t)BB * LC * LQ);        // 16384 f32
    float* pcs = pcm + BB * (LC / 64) * LQ;                  // 16384 f32

    s2_mfma_kernel<<<dim3(LC / 64, BB), 256, 0, stream>>>(c, q, cw, qw, cqw, e2, a1, pcm, pcs);
    tf_kernel<<<dim3(HH / 32, BB), 256, 0, stream>>>(c, q, e2, pcm, pcs, a1, out);
}

// Round 21
// 58.335 us; speedup vs baseline: 2.1360x; 1.0016x over previous
//
#include <hip/hip_runtime.h>
#include <math.h>

#define BB 32
#define LC 512
#define LQ 64
#define HH 512

typedef __attribute__((ext_vector_type(8))) short short8;
typedef __attribute__((ext_vector_type(4))) float f32x4;

__device__ __forceinline__ unsigned short f2bf(float x) {
    unsigned int u = __float_as_uint(x);
    return (unsigned short)((u + 0x7fffu + ((u >> 16) & 1u)) >> 16);
}
__device__ __forceinline__ float bf2f(unsigned short v) {
    return __uint_as_float(((unsigned int)v) << 16);
}
__device__ __forceinline__ void nts(float* p, float x, float y, float z, float w) {
    f32x4 v = {x, y, z, w};
    __builtin_nontemporal_store(v, (f32x4*)p);
}

// Kernel 1 (MFMA core + proven fp32 epilogue; a1/e2 stored bf16).
// XCD swizzle: each XCD gets a contiguous 32-block range = 4 batches.
__global__ __launch_bounds__(256) void s2_mfma_kernel(
    const float* __restrict__ c, const float* __restrict__ q,
    const float* __restrict__ cw, const float* __restrict__ qw,
    const float* __restrict__ cqw,
    unsigned short* __restrict__ e2, unsigned short* __restrict__ a1,
    float* __restrict__ pcm, float* __restrict__ pcs) {
    int lin = blockIdx.x + (int)gridDim.x * blockIdx.y;   // 0..255
    int swz = (lin & 7) * 32 + (lin >> 3);                // XCD-contiguous
    int it = swz & 7, b = swz >> 3;
    int i0 = it * 64;
    int t = threadIdx.x, tx = t & 15, ty = t >> 4;
    int lane = t & 63, w = t >> 6, lo = lane & 15, hi = lane >> 4;
    __shared__ __align__(16) unsigned short cmb[64][72];  // [i][k] bf16
    __shared__ __align__(16) unsigned short qb[64][72];   // [j][k] bf16
    __shared__ float z2s[64][65];                         // fp32 z2 tile
    __shared__ float s0_s[64], s1_s[64], mt_s[64];
    __shared__ float redm[16][65], redp[16][65];
    f32x4 acc[4] = {{0.f,0.f,0.f,0.f},{0.f,0.f,0.f,0.f},{0.f,0.f,0.f,0.f},{0.f,0.f,0.f,0.f}};
    float ps0[4] = {0.f,0.f,0.f,0.f}, ps1[4] = {0.f,0.f,0.f,0.f};

    for (int h0 = 0; h0 < HH; h0 += 64) {
        #pragma unroll
        for (int u = 0; u < 4; ++u) {
            int r = u * 16 + ty;
            int h = tx * 4;
            float4 cv = *(const float4*)(c + ((size_t)(b * LC + i0 + r)) * HH + h0 + h);
            float4 wv = *(const float4*)(cqw + h0 + h);
            cmb[r][h + 0] = f2bf(cv.x * wv.x);
            cmb[r][h + 1] = f2bf(cv.y * wv.y);
            cmb[r][h + 2] = f2bf(cv.z * wv.z);
            cmb[r][h + 3] = f2bf(cv.w * wv.w);
            float4 cwv = *(const float4*)(cw + h0 + h);
            ps0[u] += cv.x * cwv.x + cv.y * cwv.y + cv.z * cwv.z + cv.w * cwv.w;
            float4 qv = *(const float4*)(q + ((size_t)(b * LQ + r)) * HH + h0 + h);
            qb[r][h + 0] = f2bf(qv.x);
            qb[r][h + 1] = f2bf(qv.y);
            qb[r][h + 2] = f2bf(qv.z);
            qb[r][h + 3] = f2bf(qv.w);
            float4 qwv = *(const float4*)(qw + h0 + h);
            ps1[u] += qv.x * qwv.x + qv.y * qwv.y + qv.z * qwv.z + qv.w * qwv.w;
        }
        __syncthreads();
        #pragma unroll
        for (int kk = 0; kk < 64; kk += 32) {
            short8 af = *(const short8*)(&cmb[16 * w + lo][kk + hi * 8]);
            #pragma unroll
            for (int jt = 0; jt < 4; ++jt) {
                short8 bf = *(const short8*)(&qb[16 * jt + lo][kk + hi * 8]);
                acc[jt] = __builtin_amdgcn_mfma_f32_16x16x32_bf16(af, bf, acc[jt], 0, 0, 0);
            }
        }
        __syncthreads();
    }

    #pragma unroll
    for (int jt = 0; jt < 4; ++jt)
        #pragma unroll
        for (int e = 0; e < 4; ++e)
            z2s[16 * w + hi * 4 + e][16 * jt + lo] = acc[jt][e];

    for (int off = 1; off < 16; off <<= 1) {
        #pragma unroll
        for (int u = 0; u < 4; ++u) {
            ps0[u] += __shfl_xor(ps0[u], off, 64);
            ps1[u] += __shfl_xor(ps1[u], off, 64);
        }
    }
    if (tx == 0) {
        #pragma unroll
        for (int u = 0; u < 4; ++u) {
            s0_s[u * 16 + ty] = ps0[u];
            s1_s[u * 16 + ty] = ps1[u];
        }
    }
    __syncthreads();

    float4 zacc[4];
    #pragma unroll
    for (int iy = 0; iy < 4; ++iy) zacc[iy] = *(const float4*)(&z2s[ty * 4 + iy][tx * 4]);

    float4 s1v = make_float4(s1_s[tx * 4 + 0], s1_s[tx * 4 + 1], s1_s[tx * 4 + 2], s1_s[tx * 4 + 3]);
    #pragma unroll
    for (int iy = 0; iy < 4; ++iy) {
        int gi = b * LC + i0 + ty * 4 + iy;
        float z0 = zacc[iy].x + s1v.x, z1 = zacc[iy].y + s1v.y;
        float z2v = zacc[iy].z + s1v.z, z3 = zacc[iy].w + s1v.w;
        float m = fmaxf(fmaxf(z0, z1), fmaxf(z2v, z3));
        for (int off = 1; off < 16; off <<= 1) m = fmaxf(m, __shfl_xor(m, off, 64));
        float e0 = __expf(z0 - m), e1 = __expf(z1 - m), e2v = __expf(z2v - m), e3 = __expf(z3 - m);
        float s = e0 + e1 + e2v + e3;
        for (int off = 1; off < 16; off <<= 1) s += __shfl_xor(s, off, 64);
        float si = 1.f / s;
        ushort4 av;
        av.x = f2bf(e0 * si); av.y = f2bf(e1 * si);
        av.z = f2bf(e2v * si); av.w = f2bf(e3 * si);
        *(ushort4*)(&a1[(size_t)gi * LQ + tx * 4]) = av;
    }

    float s0r[4] = {s0_s[ty * 4 + 0], s0_s[ty * 4 + 1], s0_s[ty * 4 + 2], s0_s[ty * 4 + 3]};
    #pragma unroll
    for (int jx = 0; jx < 4; ++jx) {
        float zc[4] = {(&zacc[0].x)[jx], (&zacc[1].x)[jx], (&zacc[2].x)[jx], (&zacc[3].x)[jx]};
        float m = zc[0] + s0r[0];
        m = fmaxf(m, zc[1] + s0r[1]);
        m = fmaxf(m, zc[2] + s0r[2]);
        m = fmaxf(m, zc[3] + s0r[3]);
        redm[ty][tx * 4 + jx] = m;
    }
    __syncthreads();
    if (t < 64) {
        float M = redm[0][t];
        #pragma unroll
        for (int g = 1; g < 16; ++g) M = fmaxf(M, redm[g][t]);
        mt_s[t] = M;
        pcm[(b * 8 + it) * 64 + t] = M;
    }
    __syncthreads();
    {
        float mj[4] = {mt_s[tx * 4 + 0], mt_s[tx * 4 + 1], mt_s[tx * 4 + 2], mt_s[tx * 4 + 3]};
        float colsum[4] = {0.f, 0.f, 0.f, 0.f};
        #pragma unroll
        for (int iy = 0; iy < 4; ++iy) {
            float e0 = __expf(zacc[iy].x + s0r[iy] - mj[0]);
            float e1 = __expf(zacc[iy].y + s0r[iy] - mj[1]);
            float e2v = __expf(zacc[iy].z + s0r[iy] - mj[2]);
            float e3 = __expf(zacc[iy].w + s0r[iy] - mj[3]);
            colsum[0] += e0; colsum[1] += e1; colsum[2] += e2v; colsum[3] += e3;
            int gi = b * LC + i0 + ty * 4 + iy;
            ushort4 evv;
            evv.x = f2bf(e0); evv.y = f2bf(e1); evv.z = f2bf(e2v); evv.w = f2bf(e3);
            *(ushort4*)(&e2[(size_t)gi * LQ + tx * 4]) = evv;
        }
        #pragma unroll
        for (int jx = 0; jx < 4; ++jx) redp[ty][tx * 4 + jx] = colsum[jx];
    }
    __syncthreads();
    if (t < 64) {
        float S = redp[0][t];
        #pragma unroll
        for (int g = 1; g < 16; ++g) S += redp[g][t];
        pcs[(b * 8 + it) * 64 + t] = S;
    }
}

// Kernel 2 (fused t+f, h-tile 32, 512 blocks, 2/CU).
// XCD swizzle: each XCD gets 64 contiguous blocks = 4 complete batches
// (e2/a1/q for 4 b's ≈ 1 MB -> L2-resident shared reads).
struct TFP1 { unsigned short a2b[64][72]; unsigned short cb[32][72]; };
struct TFP2 { unsigned short a1b[2][64][72]; float spill[64][72]; };
union TFU { TFP1 p1; TFP2 p2; };

__global__ __launch_bounds__(256) void tf_kernel(
    const float* __restrict__ c, const float* __restrict__ q,
    const unsigned short* __restrict__ e2,
    const float* __restrict__ pcm, const float* __restrict__ pcs,
    const unsigned short* __restrict__ a1, float* __restrict__ out) {
    int lin = blockIdx.x + (int)gridDim.x * blockIdx.y;   // 0..511
    int swz = (lin & 7) * 64 + (lin >> 3);                // XCD-contiguous
    int h0 = (swz & 15) * 32, b = swz >> 4;
    int t = threadIdx.x;
    int lane = t & 63, w = t >> 6, lo = lane & 15, hi = lane >> 4;
    __shared__ __align__(16) TFU u_;
    __shared__ __align__(16) unsigned short qTb[32][72];  // [h][k] bf16
    __shared__ __align__(16) unsigned short tTb[32][72];  // [h][k] bf16 (tmat slice)
    __shared__ float sc_s[8][64];

    if (t < 64) {
        float pm[8];
        #pragma unroll
        for (int g = 0; g < 8; ++g) pm[g] = pcm[(b * 8 + g) * 64 + t];
        float M = pm[0];
        #pragma unroll
        for (int g = 1; g < 8; ++g) M = fmaxf(M, pm[g]);
        float S = 0.f, ee[8];
        #pragma unroll
        for (int g = 0; g < 8; ++g) {
            ee[g] = __expf(pm[g] - M);
            S += pcs[(b * 8 + g) * 64 + t] * ee[g];
        }
        float si = 1.f / S;
        #pragma unroll
        for (int g = 0; g < 8; ++g) sc_s[g][t] = ee[g] * si;
    }
    __syncthreads();

    // ---- t-phase: M=64 k, N=32 h, K=i ----
    f32x4 acc[2] = {{0.f,0.f,0.f,0.f},{0.f,0.f,0.f,0.f}};
    for (int ic = 0; ic < LC; ic += 64) {
        #pragma unroll
        for (int u = 0; u < 2; ++u) {
            int idx = u * 256 + t;
            int r = idx >> 3, h4 = (idx & 7) * 4;
            float4 cv = *(const float4*)(c + (size_t)(b * LC + ic + r) * HH + h0 + h4);
            u_.p1.cb[h4 + 0][r] = f2bf(cv.x);
            u_.p1.cb[h4 + 1][r] = f2bf(cv.y);
            u_.p1.cb[h4 + 2][r] = f2bf(cv.z);
            u_.p1.cb[h4 + 3][r] = f2bf(cv.w);
        }
        #pragma unroll
        for (int u = 0; u < 4; ++u) {
            int idx = u * 256 + t;
            int r = idx >> 4, k4 = (idx & 15) * 4;
            ushort4 ev = *(const ushort4*)(e2 + (size_t)(b * LC + ic + r) * LQ + k4);
            float4 scv = *(const float4*)(&sc_s[ic >> 6][k4]);
            u_.p1.a2b[k4 + 0][r] = f2bf(bf2f(ev.x) * scv.x);
            u_.p1.a2b[k4 + 1][r] = f2bf(bf2f(ev.y) * scv.y);
            u_.p1.a2b[k4 + 2][r] = f2bf(bf2f(ev.z) * scv.z);
            u_.p1.a2b[k4 + 3][r] = f2bf(bf2f(ev.w) * scv.w);
        }
        __syncthreads();
        #pragma unroll
        for (int kk = 0; kk < 64; kk += 32) {
            short8 af = *(const short8*)(&u_.p1.a2b[16 * w + lo][kk + hi * 8]);
            #pragma unroll
            for (int jt = 0; jt < 2; ++jt) {
                short8 bf = *(const short8*)(&u_.p1.cb[16 * jt + lo][kk + hi * 8]);
                acc[jt] = __builtin_amdgcn_mfma_f32_16x16x32_bf16(af, bf, acc[jt], 0, 0, 0);
            }
        }
        __syncthreads();
    }
    // spill tmat slice: D (k=16w+hi*4+e, h=16jt+lo) -> tTb[h][k]
    #pragma unroll
    for (int jt = 0; jt < 2; ++jt)
        #pragma unroll
        for (int e = 0; e < 4; ++e)
            tTb[16 * jt + lo][16 * w + hi * 4 + e] = f2bf(acc[jt][e]);
    // stage q slice -> qTb[h][k]
    #pragma unroll
    for (int u = 0; u < 2; ++u) {
        int idx = u * 256 + t;
        int k = idx >> 3, h4 = (idx & 7) * 4;
        float4 qv = *(const float4*)(q + ((size_t)(b * LQ + k)) * HH + h0 + h4);
        qTb[h4 + 0][k] = f2bf(qv.x); qTb[h4 + 1][k] = f2bf(qv.y);
        qTb[h4 + 2][k] = f2bf(qv.z); qTb[h4 + 3][k] = f2bf(qv.w);
    }
    // prologue: stage a1 chunk 0 into buffer 0
    #pragma unroll
    for (int u = 0; u < 2; ++u) {
        int idx = u * 256 + t;
        int r = idx >> 3, seg = idx & 7;
        *(short8*)(&u_.p2.a1b[0][r][seg * 8]) =
            *(const short8*)(a1 + (size_t)(b * LC + r) * LQ + seg * 8);
    }
    __syncthreads();

    // ---- f-phase: 8 i-chunks, double-buffered a1, 2 barriers/chunk ----
    for (int it = 0; it < 8; ++it) {
        int cur = it & 1, nxt = cur ^ 1;
        int i0 = it * 64;
        if (it < 7) {
            #pragma unroll
            for (int u = 0; u < 2; ++u) {
                int idx = u * 256 + t;
                int r = idx >> 3, seg = idx & 7;
                *(short8*)(&u_.p2.a1b[nxt][r][seg * 8]) =
                    *(const short8*)(a1 + (size_t)(b * LC + i0 + 64 + r) * LQ + seg * 8);
            }
        }
        f32x4 fa[2] = {{0.f,0.f,0.f,0.f},{0.f,0.f,0.f,0.f}};
        f32x4 fb[2] = {{0.f,0.f,0.f,0.f},{0.f,0.f,0.f,0.f}};
        #pragma unroll
        for (int kk = 0; kk < 64; kk += 32) {
            short8 af = *(const short8*)(&u_.p2.a1b[cur][16 * w + lo][kk + hi * 8]);
            #pragma unroll
            for (int jt = 0; jt < 2; ++jt) {
                short8 bq = *(const short8*)(&qTb[16 * jt + lo][kk + hi * 8]);
                fa[jt] = __builtin_amdgcn_mfma_f32_16x16x32_bf16(af, bq, fa[jt], 0, 0, 0);
                short8 bt = *(const short8*)(&tTb[16 * jt + lo][kk + hi * 8]);
                fb[jt] = __builtin_amdgcn_mfma_f32_16x16x32_bf16(af, bt, fb[jt], 0, 0, 0);
            }
        }
        // single spill: fa -> cols 0..31, fb -> cols 32..63
        #pragma unroll
        for (int jt = 0; jt < 2; ++jt)
            #pragma unroll
            for (int e = 0; e < 4; ++e) {
                u_.p2.spill[16 * w + hi * 4 + e][16 * jt + lo] = fa[jt][e];
                u_.p2.spill[16 * w + hi * 4 + e][32 + 16 * jt + lo] = fb[jt][e];
            }
        __syncthreads();
        // one store pass: all 4 sections
        #pragma unroll
        for (int u = 0; u < 2; ++u) {
            int idx = u * 256 + t;
            int r = idx >> 3, c4 = (idx & 7) * 4;
            size_t gi = (size_t)(b * LC + i0 + r);
            float4 av = *(const float4*)(&u_.p2.spill[r][c4]);
            float4 bv = *(const float4*)(&u_.p2.spill[r][32 + c4]);
            float4 cv = *(const float4*)(c + gi * HH + h0 + c4);
            float* orow = out + gi * 2048 + h0;
            nts(orow + c4, cv.x, cv.y, cv.z, cv.w);
            nts(orow + 512 + c4, av.x, av.y, av.z, av.w);
            nts(orow + 1024 + c4, cv.x * av.x, cv.y * av.y, cv.z * av.z, cv.w * av.w);
            nts(orow + 1536 + c4, cv.x * bv.x, cv.y * bv.y, cv.z * bv.z, cv.w * bv.w);
        }
        __syncthreads();   // spill + a1b[cur] safe to overwrite next iter
    }
}

extern "C" void kernel_launch(void* const* d_in, const int* in_sizes, int n_in,
                              void* d_out, int out_size, void* d_ws, size_t ws_size,
                              hipStream_t stream) {
    const float* c   = (const float*)d_in[0];
    const float* q   = (const float*)d_in[1];
    const float* cw  = (const float*)d_in[4];
    const float* qw  = (const float*)d_in[5];
    const float* cqw = (const float*)d_in[6];
    float* out = (float*)d_out;

    unsigned short* e2 = (unsigned short*)d_ws;              // 1M bf16
    unsigned short* a1 = e2 + (size_t)BB * LC * LQ;          // 1M bf16
    float* pcm = (float*)(a1 + (size_t)BB * LC * LQ);        // 16384 f32
    float* pcs = pcm + BB * (LC / 64) * LQ;                  // 16384 f32

    s2_mfma_kernel<<<dim3(LC / 64, BB), 256, 0, stream>>>(c, q, cw, qw, cqw, e2, a1, pcm, pcs);
    tf_kernel<<<dim3(HH / 32, BB), 256, 0, stream>>>(c, q, e2, pcm, pcs, a1, out);
}

// Round 23
// 56.004 us; speedup vs baseline: 2.2249x; 1.0416x over previous
//
#include <hip/hip_runtime.h>
#include <math.h>

#define BB 32
#define LC 512
#define LQ 64
#define HH 512

typedef __attribute__((ext_vector_type(8))) short short8;
typedef __attribute__((ext_vector_type(4))) float f32x4;

__device__ __forceinline__ unsigned short f2bf(float x) {
    unsigned int u = __float_as_uint(x);
    return (unsigned short)((u + 0x7fffu + ((u >> 16) & 1u)) >> 16);
}
__device__ __forceinline__ float bf2f(unsigned short v) {
    return __uint_as_float(((unsigned int)v) << 16);
}
__device__ __forceinline__ void nts(float* p, float x, float y, float z, float w) {
    f32x4 v = {x, y, z, w};
    __builtin_nontemporal_store(v, (f32x4*)p);
}

// Kernel 1 (MFMA core, T14 async-stage split + 2-deep LDS ping-pong;
// proven fp32 epilogue verbatim; a1/e2 stored bf16; XCD swizzle).
__global__ __launch_bounds__(256) void s2_mfma_kernel(
    const float* __restrict__ c, const float* __restrict__ q,
    const float* __restrict__ cw, const float* __restrict__ qw,
    const float* __restrict__ cqw,
    unsigned short* __restrict__ e2, unsigned short* __restrict__ a1,
    float* __restrict__ pcm, float* __restrict__ pcs) {
    int lin = blockIdx.x + (int)gridDim.x * blockIdx.y;   // 0..255
    int swz = (lin & 7) * 32 + (lin >> 3);                // XCD-contiguous
    int it = swz & 7, b = swz >> 3;
    int i0 = it * 64;
    int t = threadIdx.x, tx = t & 15, ty = t >> 4;
    int lane = t & 63, w = t >> 6, lo = lane & 15, hi = lane >> 4;
    __shared__ __align__(16) unsigned short cmb[2][64][72];  // ping-pong [i][k] bf16
    __shared__ __align__(16) unsigned short qb[2][64][72];   // ping-pong [j][k] bf16
    __shared__ float z2s[64][65];                            // fp32 z2 tile
    __shared__ float s0_s[64], s1_s[64], mt_s[64];
    __shared__ float redm[16][65], redp[16][65];
    f32x4 acc[4] = {{0.f,0.f,0.f,0.f},{0.f,0.f,0.f,0.f},{0.f,0.f,0.f,0.f},{0.f,0.f,0.f,0.f}};
    float ps0[4] = {0.f,0.f,0.f,0.f}, ps1[4] = {0.f,0.f,0.f,0.f};

    float4 Lcv[4], Lwv[4], Lcwv[4], Lqv[4], Lqwv[4];

    // prologue: LOAD chunk 0 -> regs, WRITE -> buffers[0]
    #pragma unroll
    for (int u = 0; u < 4; ++u) {
        int r = u * 16 + ty;
        int h = tx * 4;
        Lcv[u]  = *(const float4*)(c + ((size_t)(b * LC + i0 + r)) * HH + h);
        Lwv[u]  = *(const float4*)(cqw + h);
        Lcwv[u] = *(const float4*)(cw + h);
        Lqv[u]  = *(const float4*)(q + ((size_t)(b * LQ + r)) * HH + h);
        Lqwv[u] = *(const float4*)(qw + h);
    }
    #pragma unroll
    for (int u = 0; u < 4; ++u) {
        int r = u * 16 + ty;
        int h = tx * 4;
        cmb[0][r][h + 0] = f2bf(Lcv[u].x * Lwv[u].x);
        cmb[0][r][h + 1] = f2bf(Lcv[u].y * Lwv[u].y);
        cmb[0][r][h + 2] = f2bf(Lcv[u].z * Lwv[u].z);
        cmb[0][r][h + 3] = f2bf(Lcv[u].w * Lwv[u].w);
        ps0[u] += Lcv[u].x * Lcwv[u].x + Lcv[u].y * Lcwv[u].y + Lcv[u].z * Lcwv[u].z + Lcv[u].w * Lcwv[u].w;
        qb[0][r][h + 0] = f2bf(Lqv[u].x);
        qb[0][r][h + 1] = f2bf(Lqv[u].y);
        qb[0][r][h + 2] = f2bf(Lqv[u].z);
        qb[0][r][h + 3] = f2bf(Lqv[u].w);
        ps1[u] += Lqv[u].x * Lqwv[u].x + Lqv[u].y * Lqwv[u].y + Lqv[u].z * Lqwv[u].z + Lqv[u].w * Lqwv[u].w;
    }

    for (int itc = 0; itc < 8; ++itc) {
        int cur = itc & 1, nxt = cur ^ 1;
        // issue next chunk's loads early (regs only)
        if (itc < 7) {
            int h0 = (itc + 1) * 64;
            #pragma unroll
            for (int u = 0; u < 4; ++u) {
                int r = u * 16 + ty;
                int h = tx * 4;
                Lcv[u]  = *(const float4*)(c + ((size_t)(b * LC + i0 + r)) * HH + h0 + h);
                Lwv[u]  = *(const float4*)(cqw + h0 + h);
                Lcwv[u] = *(const float4*)(cw + h0 + h);
                Lqv[u]  = *(const float4*)(q + ((size_t)(b * LQ + r)) * HH + h0 + h);
                Lqwv[u] = *(const float4*)(qw + h0 + h);
            }
        }
        __syncthreads();   // buffers[cur] writes (prev iter / prologue) visible
        #pragma unroll
        for (int kk = 0; kk < 64; kk += 32) {
            short8 af = *(const short8*)(&cmb[cur][16 * w + lo][kk + hi * 8]);
            #pragma unroll
            for (int jt = 0; jt < 4; ++jt) {
                short8 bf = *(const short8*)(&qb[cur][16 * jt + lo][kk + hi * 8]);
                acc[jt] = __builtin_amdgcn_mfma_f32_16x16x32_bf16(af, bf, acc[jt], 0, 0, 0);
            }
        }
        // write next chunk to the other buffer (no barrier needed until next iter)
        if (itc < 7) {
            #pragma unroll
            for (int u = 0; u < 4; ++u) {
                int r = u * 16 + ty;
                int h = tx * 4;
                cmb[nxt][r][h + 0] = f2bf(Lcv[u].x * Lwv[u].x);
                cmb[nxt][r][h + 1] = f2bf(Lcv[u].y * Lwv[u].y);
                cmb[nxt][r][h + 2] = f2bf(Lcv[u].z * Lwv[u].z);
                cmb[nxt][r][h + 3] = f2bf(Lcv[u].w * Lwv[u].w);
                ps0[u] += Lcv[u].x * Lcwv[u].x + Lcv[u].y * Lcwv[u].y + Lcv[u].z * Lcwv[u].z + Lcv[u].w * Lcwv[u].w;
                qb[nxt][r][h + 0] = f2bf(Lqv[u].x);
                qb[nxt][r][h + 1] = f2bf(Lqv[u].y);
                qb[nxt][r][h + 2] = f2bf(Lqv[u].z);
                qb[nxt][r][h + 3] = f2bf(Lqv[u].w);
                ps1[u] += Lqv[u].x * Lqwv[u].x + Lqv[u].y * Lqwv[u].y + Lqv[u].z * Lqwv[u].z + Lqv[u].w * Lqwv[u].w;
            }
        }
    }

    #pragma unroll
    for (int jt = 0; jt < 4; ++jt)
        #pragma unroll
        for (int e = 0; e < 4; ++e)
            z2s[16 * w + hi * 4 + e][16 * jt + lo] = acc[jt][e];

    for (int off = 1; off < 16; off <<= 1) {
        #pragma unroll
        for (int u = 0; u < 4; ++u) {
            ps0[u] += __shfl_xor(ps0[u], off, 64);
            ps1[u] += __shfl_xor(ps1[u], off, 64);
        }
    }
    if (tx == 0) {
        #pragma unroll
        for (int u = 0; u < 4; ++u) {
            s0_s[u * 16 + ty] = ps0[u];
            s1_s[u * 16 + ty] = ps1[u];
        }
    }
    __syncthreads();

    float4 zacc[4];
    #pragma unroll
    for (int iy = 0; iy < 4; ++iy) zacc[iy] = *(const float4*)(&z2s[ty * 4 + iy][tx * 4]);

    float4 s1v = make_float4(s1_s[tx * 4 + 0], s1_s[tx * 4 + 1], s1_s[tx * 4 + 2], s1_s[tx * 4 + 3]);
    #pragma unroll
    for (int iy = 0; iy < 4; ++iy) {
        int gi = b * LC + i0 + ty * 4 + iy;
        float z0 = zacc[iy].x + s1v.x, z1 = zacc[iy].y + s1v.y;
        float z2v = zacc[iy].z + s1v.z, z3 = zacc[iy].w + s1v.w;
        float m = fmaxf(fmaxf(z0, z1), fmaxf(z2v, z3));
        for (int off = 1; off < 16; off <<= 1) m = fmaxf(m, __shfl_xor(m, off, 64));
        float e0 = __expf(z0 - m), e1 = __expf(z1 - m), e2v = __expf(z2v - m), e3 = __expf(z3 - m);
        float s = e0 + e1 + e2v + e3;
        for (int off = 1; off < 16; off <<= 1) s += __shfl_xor(s, off, 64);
        float si = 1.f / s;
        ushort4 av;
        av.x = f2bf(e0 * si); av.y = f2bf(e1 * si);
        av.z = f2bf(e2v * si); av.w = f2bf(e3 * si);
        *(ushort4*)(&a1[(size_t)gi * LQ + tx * 4]) = av;
    }

    float s0r[4] = {s0_s[ty * 4 + 0], s0_s[ty * 4 + 1], s0_s[ty * 4 + 2], s0_s[ty * 4 + 3]};
    #pragma unroll
    for (int jx = 0; jx < 4; ++jx) {
        float zc[4] = {(&zacc[0].x)[jx], (&zacc[1].x)[jx], (&zacc[2].x)[jx], (&zacc[3].x)[jx]};
        float m = zc[0] + s0r[0];
        m = fmaxf(m, zc[1] + s0r[1]);
        m = fmaxf(m, zc[2] + s0r[2]);
        m = fmaxf(m, zc[3] + s0r[3]);
        redm[ty][tx * 4 + jx] = m;
    }
    __syncthreads();
    if (t < 64) {
        float M = redm[0][t];
        #pragma unroll
        for (int g = 1; g < 16; ++g) M = fmaxf(M, redm[g][t]);
        mt_s[t] = M;
        pcm[(b * 8 + it) * 64 + t] = M;
    }
    __syncthreads();
    {
        float mj[4] = {mt_s[tx * 4 + 0], mt_s[tx * 4 + 1], mt_s[tx * 4 + 2], mt_s[tx * 4 + 3]};
        float colsum[4] = {0.f, 0.f, 0.f, 0.f};
        #pragma unroll
        for (int iy = 0; iy < 4; ++iy) {
            float e0 = __expf(zacc[iy].x + s0r[iy] - mj[0]);
            float e1 = __expf(zacc[iy].y + s0r[iy] - mj[1]);
            float e2v = __expf(zacc[iy].z + s0r[iy] - mj[2]);
            float e3 = __expf(zacc[iy].w + s0r[iy] - mj[3]);
            colsum[0] += e0; colsum[1] += e1; colsum[2] += e2v; colsum[3] += e3;
            int gi = b * LC + i0 + ty * 4 + iy;
            ushort4 evv;
            evv.x = f2bf(e0); evv.y = f2bf(e1); evv.z = f2bf(e2v); evv.w = f2bf(e3);
            *(ushort4*)(&e2[(size_t)gi * LQ + tx * 4]) = evv;
        }
        #pragma unroll
        for (int jx = 0; jx < 4; ++jx) redp[ty][tx * 4 + jx] = colsum[jx];
    }
    __syncthreads();
    if (t < 64) {
        float S = redp[0][t];
        #pragma unroll
        for (int g = 1; g < 16; ++g) S += redp[g][t];
        pcs[(b * 8 + it) * 64 + t] = S;
    }
}

// Kernel 2 (fused t+f, h-tile 32, 512 blocks, 2/CU, XCD-swizzled) — unchanged.
struct TFP1 { unsigned short a2b[64][72]; unsigned short cb[32][72]; };
struct TFP2 { unsigned short a1b[2][64][72]; float spill[64][72]; };
union TFU { TFP1 p1; TFP2 p2; };

__global__ __launch_bounds__(256) void tf_kernel(
    const float* __restrict__ c, const float* __restrict__ q,
    const unsigned short* __restrict__ e2,
    const float* __restrict__ pcm, const float* __restrict__ pcs,
    const unsigned short* __restrict__ a1, float* __restrict__ out) {
    int lin = blockIdx.x + (int)gridDim.x * blockIdx.y;   // 0..511
    int swz = (lin & 7) * 64 + (lin >> 3);                // XCD-contiguous
    int h0 = (swz & 15) * 32, b = swz >> 4;
    int t = threadIdx.x;
    int lane = t & 63, w = t >> 6, lo = lane & 15, hi = lane >> 4;
    __shared__ __align__(16) TFU u_;
    __shared__ __align__(16) unsigned short qTb[32][72];  // [h][k] bf16
    __shared__ __align__(16) unsigned short tTb[32][72];  // [h][k] bf16 (tmat slice)
    __shared__ float sc_s[8][64];

    if (t < 64) {
        float pm[8];
        #pragma unroll
        for (int g = 0; g < 8; ++g) pm[g] = pcm[(b * 8 + g) * 64 + t];
        float M = pm[0];
        #pragma unroll
        for (int g = 1; g < 8; ++g) M = fmaxf(M, pm[g]);
        float S = 0.f, ee[8];
        #pragma unroll
        for (int g = 0; g < 8; ++g) {
            ee[g] = __expf(pm[g] - M);
            S += pcs[(b * 8 + g) * 64 + t] * ee[g];
        }
        float si = 1.f / S;
        #pragma unroll
        for (int g = 0; g < 8; ++g) sc_s[g][t] = ee[g] * si;
    }
    __syncthreads();

    // ---- t-phase: M=64 k, N=32 h, K=i ----
    f32x4 acc[2] = {{0.f,0.f,0.f,0.f},{0.f,0.f,0.f,0.f}};
    for (int ic = 0; ic < LC; ic += 64) {
        #pragma unroll
        for (int u = 0; u < 2; ++u) {
            int idx = u * 256 + t;
            int r = idx >> 3, h4 = (idx & 7) * 4;
            float4 cv = *(const float4*)(c + (size_t)(b * LC + ic + r) * HH + h0 + h4);
            u_.p1.cb[h4 + 0][r] = f2bf(cv.x);
            u_.p1.cb[h4 + 1][r] = f2bf(cv.y);
            u_.p1.cb[h4 + 2][r] = f2bf(cv.z);
            u_.p1.cb[h4 + 3][r] = f2bf(cv.w);
        }
        #pragma unroll
        for (int u = 0; u < 4; ++u) {
            int idx = u * 256 + t;
            int r = idx >> 4, k4 = (idx & 15) * 4;
            ushort4 ev = *(const ushort4*)(e2 + (size_t)(b * LC + ic + r) * LQ + k4);
            float4 scv = *(const float4*)(&sc_s[ic >> 6][k4]);
            u_.p1.a2b[k4 + 0][r] = f2bf(bf2f(ev.x) * scv.x);
            u_.p1.a2b[k4 + 1][r] = f2bf(bf2f(ev.y) * scv.y);
            u_.p1.a2b[k4 + 2][r] = f2bf(bf2f(ev.z) * scv.z);
            u_.p1.a2b[k4 + 3][r] = f2bf(bf2f(ev.w) * scv.w);
        }
        __syncthreads();
        #pragma unroll
        for (int kk = 0; kk < 64; kk += 32) {
            short8 af = *(const short8*)(&u_.p1.a2b[16 * w + lo][kk + hi * 8]);
            #pragma unroll
            for (int jt = 0; jt < 2; ++jt) {
                short8 bf = *(const short8*)(&u_.p1.cb[16 * jt + lo][kk + hi * 8]);
                acc[jt] = __builtin_amdgcn_mfma_f32_16x16x32_bf16(af, bf, acc[jt], 0, 0, 0);
            }
        }
        __syncthreads();
    }
    // spill tmat slice: D (k=16w+hi*4+e, h=16jt+lo) -> tTb[h][k]
    #pragma unroll
    for (int jt = 0; jt < 2; ++jt)
        #pragma unroll
        for (int e = 0; e < 4; ++e)
            tTb[16 * jt + lo][16 * w + hi * 4 + e] = f2bf(acc[jt][e]);
    // stage q slice -> qTb[h][k]
    #pragma unroll
    for (int u = 0; u < 2; ++u) {
        int idx = u * 256 + t;
        int k = idx >> 3, h4 = (idx & 7) * 4;
        float4 qv = *(const float4*)(q + ((size_t)(b * LQ + k)) * HH + h0 + h4);
        qTb[h4 + 0][k] = f2bf(qv.x); qTb[h4 + 1][k] = f2bf(qv.y);
        qTb[h4 + 2][k] = f2bf(qv.z); qTb[h4 + 3][k] = f2bf(qv.w);
    }
    // prologue: stage a1 chunk 0 into buffer 0
    #pragma unroll
    for (int u = 0; u < 2; ++u) {
        int idx = u * 256 + t;
        int r = idx >> 3, seg = idx & 7;
        *(short8*)(&u_.p2.a1b[0][r][seg * 8]) =
            *(const short8*)(a1 + (size_t)(b * LC + r) * LQ + seg * 8);
    }
    __syncthreads();

    // ---- f-phase: 8 i-chunks, double-buffered a1, 2 barriers/chunk ----
    for (int it = 0; it < 8; ++it) {
        int cur = it & 1, nxt = cur ^ 1;
        int i0 = it * 64;
        if (it < 7) {
            #pragma unroll
            for (int u = 0; u < 2; ++u) {
                int idx = u * 256 + t;
                int r = idx >> 3, seg = idx & 7;
                *(short8*)(&u_.p2.a1b[nxt][r][seg * 8]) =
                    *(const short8*)(a1 + (size_t)(b * LC + i0 + 64 + r) * LQ + seg * 8);
            }
        }
        f32x4 fa[2] = {{0.f,0.f,0.f,0.f},{0.f,0.f,0.f,0.f}};
        f32x4 fb[2] = {{0.f,0.f,0.f,0.f},{0.f,0.f,0.f,0.f}};
        #pragma unroll
        for (int kk = 0; kk < 64; kk += 32) {
            short8 af = *(const short8*)(&u_.p2.a1b[cur][16 * w + lo][kk + hi * 8]);
            #pragma unroll
            for (int jt = 0; jt < 2; ++jt) {
                short8 bq = *(const short8*)(&qTb[16 * jt + lo][kk + hi * 8]);
                fa[jt] = __builtin_amdgcn_mfma_f32_16x16x32_bf16(af, bq, fa[jt], 0, 0, 0);
                short8 bt = *(const short8*)(&tTb[16 * jt + lo][kk + hi * 8]);
                fb[jt] = __builtin_amdgcn_mfma_f32_16x16x32_bf16(af, bt, fb[jt], 0, 0, 0);
            }
        }
        // single spill: fa -> cols 0..31, fb -> cols 32..63
        #pragma unroll
        for (int jt = 0; jt < 2; ++jt)
            #pragma unroll
            for (int e = 0; e < 4; ++e) {
                u_.p2.spill[16 * w + hi * 4 + e][16 * jt + lo] = fa[jt][e];
                u_.p2.spill[16 * w + hi * 4 + e][32 + 16 * jt + lo] = fb[jt][e];
            }
        __syncthreads();
        // one store pass: all 4 sections
        #pragma unroll
        for (int u = 0; u < 2; ++u) {
            int idx = u * 256 + t;
            int r = idx >> 3, c4 = (idx & 7) * 4;
            size_t gi = (size_t)(b * LC + i0 + r);
            float4 av = *(const float4*)(&u_.p2.spill[r][c4]);
            float4 bv = *(const float4*)(&u_.p2.spill[r][32 + c4]);
            float4 cv = *(const float4*)(c + gi * HH + h0 + c4);
            float* orow = out + gi * 2048 + h0;
            nts(orow + c4, cv.x, cv.y, cv.z, cv.w);
            nts(orow + 512 + c4, av.x, av.y, av.z, av.w);
            nts(orow + 1024 + c4, cv.x * av.x, cv.y * av.y, cv.z * av.z, cv.w * av.w);
            nts(orow + 1536 + c4, cv.x * bv.x, cv.y * bv.y, cv.z * bv.z, cv.w * bv.w);
        }
        __syncthreads();   // spill + a1b[cur] safe to overwrite next iter
    }
}

extern "C" void kernel_launch(void* const* d_in, const int* in_sizes, int n_in,
                              void* d_out, int out_size, void* d_ws, size_t ws_size,
                              hipStream_t stream) {
    const float* c   = (const float*)d_in[0];
    const float* q   = (const float*)d_in[1];
    const float* cw  = (const float*)d_in[4];
    const float* qw  = (const float*)d_in[5];
    const float* cqw = (const float*)d_in[6];
    float* out = (float*)d_out;

    unsigned short* e2 = (unsigned short*)d_ws;              // 1M bf16
    unsigned short* a1 = e2 + (size_t)BB * LC * LQ;          // 1M bf16
    float* pcm = (float*)(a1 + (size_t)BB * LC * LQ);        // 16384 f32
    float* pcs = pcm + BB * (LC / 64) * LQ;                  // 16384 f32

    s2_mfma_kernel<<<dim3(LC / 64, BB), 256, 0, stream>>>(c, q, cw, qw, cqw, e2, a1, pcm, pcs);
    tf_kernel<<<dim3(HH / 32, BB), 256, 0, stream>>>(c, q, e2, pcm, pcs, a1, out);
}

// Round 24
// 51.816 us; speedup vs baseline: 2.4048x; 1.0808x over previous
//
#include <hip/hip_runtime.h>
#include <math.h>

#define BB 32
#define LC 512
#define LQ 64
#define HH 512

typedef __attribute__((ext_vector_type(8))) short short8;
typedef __attribute__((ext_vector_type(4))) float f32x4;

__device__ __forceinline__ unsigned short f2bf(float x) {
    unsigned int u = __float_as_uint(x);
    return (unsigned short)((u + 0x7fffu + ((u >> 16) & 1u)) >> 16);
}
__device__ __forceinline__ float bf2f(unsigned short v) {
    return __uint_as_float(((unsigned int)v) << 16);
}
__device__ __forceinline__ void nts(float* p, float x, float y, float z, float w) {
    f32x4 v = {x, y, z, w};
    __builtin_nontemporal_store(v, (f32x4*)p);
}

// Kernel 1 (MFMA core, T14 async-stage split + 2-deep LDS ping-pong;
// proven fp32 epilogue verbatim; a1/e2 stored bf16; XCD swizzle) — unchanged.
__global__ __launch_bounds__(256) void s2_mfma_kernel(
    const float* __restrict__ c, const float* __restrict__ q,
    const float* __restrict__ cw, const float* __restrict__ qw,
    const float* __restrict__ cqw,
    unsigned short* __restrict__ e2, unsigned short* __restrict__ a1,
    float* __restrict__ pcm, float* __restrict__ pcs) {
    int lin = blockIdx.x + (int)gridDim.x * blockIdx.y;   // 0..255
    int swz = (lin & 7) * 32 + (lin >> 3);                // XCD-contiguous
    int it = swz & 7, b = swz >> 3;
    int i0 = it * 64;
    int t = threadIdx.x, tx = t & 15, ty = t >> 4;
    int lane = t & 63, w = t >> 6, lo = lane & 15, hi = lane >> 4;
    __shared__ __align__(16) unsigned short cmb[2][64][72];  // ping-pong [i][k] bf16
    __shared__ __align__(16) unsigned short qb[2][64][72];   // ping-pong [j][k] bf16
    __shared__ float z2s[64][65];                            // fp32 z2 tile
    __shared__ float s0_s[64], s1_s[64], mt_s[64];
    __shared__ float redm[16][65], redp[16][65];
    f32x4 acc[4] = {{0.f,0.f,0.f,0.f},{0.f,0.f,0.f,0.f},{0.f,0.f,0.f,0.f},{0.f,0.f,0.f,0.f}};
    float ps0[4] = {0.f,0.f,0.f,0.f}, ps1[4] = {0.f,0.f,0.f,0.f};

    float4 Lcv[4], Lwv[4], Lcwv[4], Lqv[4], Lqwv[4];

    #pragma unroll
    for (int u = 0; u < 4; ++u) {
        int r = u * 16 + ty;
        int h = tx * 4;
        Lcv[u]  = *(const float4*)(c + ((size_t)(b * LC + i0 + r)) * HH + h);
        Lwv[u]  = *(const float4*)(cqw + h);
        Lcwv[u] = *(const float4*)(cw + h);
        Lqv[u]  = *(const float4*)(q + ((size_t)(b * LQ + r)) * HH + h);
        Lqwv[u] = *(const float4*)(qw + h);
    }
    #pragma unroll
    for (int u = 0; u < 4; ++u) {
        int r = u * 16 + ty;
        int h = tx * 4;
        cmb[0][r][h + 0] = f2bf(Lcv[u].x * Lwv[u].x);
        cmb[0][r][h + 1] = f2bf(Lcv[u].y * Lwv[u].y);
        cmb[0][r][h + 2] = f2bf(Lcv[u].z * Lwv[u].z);
        cmb[0][r][h + 3] = f2bf(Lcv[u].w * Lwv[u].w);
        ps0[u] += Lcv[u].x * Lcwv[u].x + Lcv[u].y * Lcwv[u].y + Lcv[u].z * Lcwv[u].z + Lcv[u].w * Lcwv[u].w;
        qb[0][r][h + 0] = f2bf(Lqv[u].x);
        qb[0][r][h + 1] = f2bf(Lqv[u].y);
        qb[0][r][h + 2] = f2bf(Lqv[u].z);
        qb[0][r][h + 3] = f2bf(Lqv[u].w);
        ps1[u] += Lqv[u].x * Lqwv[u].x + Lqv[u].y * Lqwv[u].y + Lqv[u].z * Lqwv[u].z + Lqv[u].w * Lqwv[u].w;
    }

    for (int itc = 0; itc < 8; ++itc) {
        int cur = itc & 1, nxt = cur ^ 1;
        if (itc < 7) {
            int h0 = (itc + 1) * 64;
            #pragma unroll
            for (int u = 0; u < 4; ++u) {
                int r = u * 16 + ty;
                int h = tx * 4;
                Lcv[u]  = *(const float4*)(c + ((size_t)(b * LC + i0 + r)) * HH + h0 + h);
                Lwv[u]  = *(const float4*)(cqw + h0 + h);
                Lcwv[u] = *(const float4*)(cw + h0 + h);
                Lqv[u]  = *(const float4*)(q + ((size_t)(b * LQ + r)) * HH + h0 + h);
                Lqwv[u] = *(const float4*)(qw + h0 + h);
            }
        }
        __syncthreads();
        #pragma unroll
        for (int kk = 0; kk < 64; kk += 32) {
            short8 af = *(const short8*)(&cmb[cur][16 * w + lo][kk + hi * 8]);
            #pragma unroll
            for (int jt = 0; jt < 4; ++jt) {
                short8 bf = *(const short8*)(&qb[cur][16 * jt + lo][kk + hi * 8]);
                acc[jt] = __builtin_amdgcn_mfma_f32_16x16x32_bf16(af, bf, acc[jt], 0, 0, 0);
            }
        }
        if (itc < 7) {
            #pragma unroll
            for (int u = 0; u < 4; ++u) {
                int r = u * 16 + ty;
                int h = tx * 4;
                cmb[nxt][r][h + 0] = f2bf(Lcv[u].x * Lwv[u].x);
                cmb[nxt][r][h + 1] = f2bf(Lcv[u].y * Lwv[u].y);
                cmb[nxt][r][h + 2] = f2bf(Lcv[u].z * Lwv[u].z);
                cmb[nxt][r][h + 3] = f2bf(Lcv[u].w * Lwv[u].w);
                ps0[u] += Lcv[u].x * Lcwv[u].x + Lcv[u].y * Lcwv[u].y + Lcv[u].z * Lcwv[u].z + Lcv[u].w * Lcwv[u].w;
                qb[nxt][r][h + 0] = f2bf(Lqv[u].x);
                qb[nxt][r][h + 1] = f2bf(Lqv[u].y);
                qb[nxt][r][h + 2] = f2bf(Lqv[u].z);
                qb[nxt][r][h + 3] = f2bf(Lqv[u].w);
                ps1[u] += Lqv[u].x * Lqwv[u].x + Lqv[u].y * Lqwv[u].y + Lqv[u].z * Lqwv[u].z + Lqv[u].w * Lqwv[u].w;
            }
        }
    }

    #pragma unroll
    for (int jt = 0; jt < 4; ++jt)
        #pragma unroll
        for (int e = 0; e < 4; ++e)
            z2s[16 * w + hi * 4 + e][16 * jt + lo] = acc[jt][e];

    for (int off = 1; off < 16; off <<= 1) {
        #pragma unroll
        for (int u = 0; u < 4; ++u) {
            ps0[u] += __shfl_xor(ps0[u], off, 64);
            ps1[u] += __shfl_xor(ps1[u], off, 64);
        }
    }
    if (tx == 0) {
        #pragma unroll
        for (int u = 0; u < 4; ++u) {
            s0_s[u * 16 + ty] = ps0[u];
            s1_s[u * 16 + ty] = ps1[u];
        }
    }
    __syncthreads();

    float4 zacc[4];
    #pragma unroll
    for (int iy = 0; iy < 4; ++iy) zacc[iy] = *(const float4*)(&z2s[ty * 4 + iy][tx * 4]);

    float4 s1v = make_float4(s1_s[tx * 4 + 0], s1_s[tx * 4 + 1], s1_s[tx * 4 + 2], s1_s[tx * 4 + 3]);
    #pragma unroll
    for (int iy = 0; iy < 4; ++iy) {
        int gi = b * LC + i0 + ty * 4 + iy;
        float z0 = zacc[iy].x + s1v.x, z1 = zacc[iy].y + s1v.y;
        float z2v = zacc[iy].z + s1v.z, z3 = zacc[iy].w + s1v.w;
        float m = fmaxf(fmaxf(z0, z1), fmaxf(z2v, z3));
        for (int off = 1; off < 16; off <<= 1) m = fmaxf(m, __shfl_xor(m, off, 64));
        float e0 = __expf(z0 - m), e1 = __expf(z1 - m), e2v = __expf(z2v - m), e3 = __expf(z3 - m);
        float s = e0 + e1 + e2v + e3;
        for (int off = 1; off < 16; off <<= 1) s += __shfl_xor(s, off, 64);
        float si = 1.f / s;
        ushort4 av;
        av.x = f2bf(e0 * si); av.y = f2bf(e1 * si);
        av.z = f2bf(e2v * si); av.w = f2bf(e3 * si);
        *(ushort4*)(&a1[(size_t)gi * LQ + tx * 4]) = av;
    }

    float s0r[4] = {s0_s[ty * 4 + 0], s0_s[ty * 4 + 1], s0_s[ty * 4 + 2], s0_s[ty * 4 + 3]};
    #pragma unroll
    for (int jx = 0; jx < 4; ++jx) {
        float zc[4] = {(&zacc[0].x)[jx], (&zacc[1].x)[jx], (&zacc[2].x)[jx], (&zacc[3].x)[jx]};
        float m = zc[0] + s0r[0];
        m = fmaxf(m, zc[1] + s0r[1]);
        m = fmaxf(m, zc[2] + s0r[2]);
        m = fmaxf(m, zc[3] + s0r[3]);
        redm[ty][tx * 4 + jx] = m;
    }
    __syncthreads();
    if (t < 64) {
        float M = redm[0][t];
        #pragma unroll
        for (int g = 1; g < 16; ++g) M = fmaxf(M, redm[g][t]);
        mt_s[t] = M;
        pcm[(b * 8 + it) * 64 + t] = M;
    }
    __syncthreads();
    {
        float mj[4] = {mt_s[tx * 4 + 0], mt_s[tx * 4 + 1], mt_s[tx * 4 + 2], mt_s[tx * 4 + 3]};
        float colsum[4] = {0.f, 0.f, 0.f, 0.f};
        #pragma unroll
        for (int iy = 0; iy < 4; ++iy) {
            float e0 = __expf(zacc[iy].x + s0r[iy] - mj[0]);
            float e1 = __expf(zacc[iy].y + s0r[iy] - mj[1]);
            float e2v = __expf(zacc[iy].z + s0r[iy] - mj[2]);
            float e3 = __expf(zacc[iy].w + s0r[iy] - mj[3]);
            colsum[0] += e0; colsum[1] += e1; colsum[2] += e2v; colsum[3] += e3;
            int gi = b * LC + i0 + ty * 4 + iy;
            ushort4 evv;
            evv.x = f2bf(e0); evv.y = f2bf(e1); evv.z = f2bf(e2v); evv.w = f2bf(e3);
            *(ushort4*)(&e2[(size_t)gi * LQ + tx * 4]) = evv;
        }
        #pragma unroll
        for (int jx = 0; jx < 4; ++jx) redp[ty][tx * 4 + jx] = colsum[jx];
    }
    __syncthreads();
    if (t < 64) {
        float S = redp[0][t];
        #pragma unroll
        for (int g = 1; g < 16; ++g) S += redp[g][t];
        pcs[(b * 8 + it) * 64 + t] = S;
    }
}

// Kernel 2 (fused t+f, h-tile 32, XCD-swizzled; t-phase now T14 ping-pong —
// LDS-free since p2 still dominates the union).
struct TFP1 { unsigned short a2b[2][64][72]; unsigned short cb[2][32][72]; };
struct TFP2 { unsigned short a1b[2][64][72]; float spill[64][72]; };
union TFU { TFP1 p1; TFP2 p2; };

__global__ __launch_bounds__(256) void tf_kernel(
    const float* __restrict__ c, const float* __restrict__ q,
    const unsigned short* __restrict__ e2,
    const float* __restrict__ pcm, const float* __restrict__ pcs,
    const unsigned short* __restrict__ a1, float* __restrict__ out) {
    int lin = blockIdx.x + (int)gridDim.x * blockIdx.y;   // 0..511
    int swz = (lin & 7) * 64 + (lin >> 3);                // XCD-contiguous
    int h0 = (swz & 15) * 32, b = swz >> 4;
    int t = threadIdx.x;
    int lane = t & 63, w = t >> 6, lo = lane & 15, hi = lane >> 4;
    __shared__ __align__(16) TFU u_;
    __shared__ __align__(16) unsigned short qTb[32][72];  // [h][k] bf16
    __shared__ __align__(16) unsigned short tTb[32][72];  // [h][k] bf16 (tmat slice)
    __shared__ float sc_s[8][64];

    if (t < 64) {
        float pm[8];
        #pragma unroll
        for (int g = 0; g < 8; ++g) pm[g] = pcm[(b * 8 + g) * 64 + t];
        float M = pm[0];
        #pragma unroll
        for (int g = 1; g < 8; ++g) M = fmaxf(M, pm[g]);
        float S = 0.f, ee[8];
        #pragma unroll
        for (int g = 0; g < 8; ++g) {
            ee[g] = __expf(pm[g] - M);
            S += pcs[(b * 8 + g) * 64 + t] * ee[g];
        }
        float si = 1.f / S;
        #pragma unroll
        for (int g = 0; g < 8; ++g) sc_s[g][t] = ee[g] * si;
    }
    __syncthreads();   // sc_s visible to all (read-only below)

    // ---- t-phase: M=64 k, N=32 h, K=i; T14 ping-pong (s2-proven pattern) ----
    f32x4 acc[2] = {{0.f,0.f,0.f,0.f},{0.f,0.f,0.f,0.f}};
    float4 Lc[2];
    ushort4 Le[4];
    // prologue: load chunk 0 -> regs, write -> buffers[0]
    #pragma unroll
    for (int u = 0; u < 2; ++u) {
        int idx = u * 256 + t;
        int r = idx >> 3, h4 = (idx & 7) * 4;
        Lc[u] = *(const float4*)(c + (size_t)(b * LC + r) * HH + h0 + h4);
    }
    #pragma unroll
    for (int u = 0; u < 4; ++u) {
        int idx = u * 256 + t;
        int r = idx >> 4, k4 = (idx & 15) * 4;
        Le[u] = *(const ushort4*)(e2 + (size_t)(b * LC + r) * LQ + k4);
    }
    #pragma unroll
    for (int u = 0; u < 2; ++u) {
        int idx = u * 256 + t;
        int r = idx >> 3, h4 = (idx & 7) * 4;
        u_.p1.cb[0][h4 + 0][r] = f2bf(Lc[u].x);
        u_.p1.cb[0][h4 + 1][r] = f2bf(Lc[u].y);
        u_.p1.cb[0][h4 + 2][r] = f2bf(Lc[u].z);
        u_.p1.cb[0][h4 + 3][r] = f2bf(Lc[u].w);
    }
    #pragma unroll
    for (int u = 0; u < 4; ++u) {
        int idx = u * 256 + t;
        int r = idx >> 4, k4 = (idx & 15) * 4;
        float4 scv = *(const float4*)(&sc_s[0][k4]);
        u_.p1.a2b[0][k4 + 0][r] = f2bf(bf2f(Le[u].x) * scv.x);
        u_.p1.a2b[0][k4 + 1][r] = f2bf(bf2f(Le[u].y) * scv.y);
        u_.p1.a2b[0][k4 + 2][r] = f2bf(bf2f(Le[u].z) * scv.z);
        u_.p1.a2b[0][k4 + 3][r] = f2bf(bf2f(Le[u].w) * scv.w);
    }

    for (int icc = 0; icc < 8; ++icc) {
        int cur = icc & 1, nxt = cur ^ 1;
        if (icc < 7) {
            int ic = (icc + 1) * 64;
            #pragma unroll
            for (int u = 0; u < 2; ++u) {
                int idx = u * 256 + t;
                int r = idx >> 3, h4 = (idx & 7) * 4;
                Lc[u] = *(const float4*)(c + (size_t)(b * LC + ic + r) * HH + h0 + h4);
            }
            #pragma unroll
            for (int u = 0; u < 4; ++u) {
                int idx = u * 256 + t;
                int r = idx >> 4, k4 = (idx & 15) * 4;
                Le[u] = *(const ushort4*)(e2 + (size_t)(b * LC + ic + r) * LQ + k4);
            }
        }
        __syncthreads();   // buffers[cur] writes (prev iter / prologue) visible
        #pragma unroll
        for (int kk = 0; kk < 64; kk += 32) {
            short8 af = *(const short8*)(&u_.p1.a2b[cur][16 * w + lo][kk + hi * 8]);
            #pragma unroll
            for (int jt = 0; jt < 2; ++jt) {
                short8 bf = *(const short8*)(&u_.p1.cb[cur][16 * jt + lo][kk + hi * 8]);
                acc[jt] = __builtin_amdgcn_mfma_f32_16x16x32_bf16(af, bf, acc[jt], 0, 0, 0);
            }
        }
        if (icc < 7) {
            #pragma unroll
            for (int u = 0; u < 2; ++u) {
                int idx = u * 256 + t;
                int r = idx >> 3, h4 = (idx & 7) * 4;
                u_.p1.cb[nxt][h4 + 0][r] = f2bf(Lc[u].x);
                u_.p1.cb[nxt][h4 + 1][r] = f2bf(Lc[u].y);
                u_.p1.cb[nxt][h4 + 2][r] = f2bf(Lc[u].z);
                u_.p1.cb[nxt][h4 + 3][r] = f2bf(Lc[u].w);
            }
            #pragma unroll
            for (int u = 0; u < 4; ++u) {
                int idx = u * 256 + t;
                int r = idx >> 4, k4 = (idx & 15) * 4;
                float4 scv = *(const float4*)(&sc_s[icc + 1][k4]);
                u_.p1.a2b[nxt][k4 + 0][r] = f2bf(bf2f(Le[u].x) * scv.x);
                u_.p1.a2b[nxt][k4 + 1][r] = f2bf(bf2f(Le[u].y) * scv.y);
                u_.p1.a2b[nxt][k4 + 2][r] = f2bf(bf2f(Le[u].z) * scv.z);
                u_.p1.a2b[nxt][k4 + 3][r] = f2bf(bf2f(Le[u].w) * scv.w);
            }
        }
    }
    __syncthreads();   // t-phase MFMA reads done before tTb/qTb (overlap p1) writes below

    // spill tmat slice: D (k=16w+hi*4+e, h=16jt+lo) -> tTb[h][k]
    #pragma unroll
    for (int jt = 0; jt < 2; ++jt)
        #pragma unroll
        for (int e = 0; e < 4; ++e)
            tTb[16 * jt + lo][16 * w + hi * 4 + e] = f2bf(acc[jt][e]);
    // stage q slice -> qTb[h][k]
    #pragma unroll
    for (int u = 0; u < 2; ++u) {
        int idx = u * 256 + t;
        int k = idx >> 3, h4 = (idx & 7) * 4;
        float4 qv = *(const float4*)(q + ((size_t)(b * LQ + k)) * HH + h0 + h4);
        qTb[h4 + 0][k] = f2bf(qv.x); qTb[h4 + 1][k] = f2bf(qv.y);
        qTb[h4 + 2][k] = f2bf(qv.z); qTb[h4 + 3][k] = f2bf(qv.w);
    }
    // prologue: stage a1 chunk 0 into buffer 0
    #pragma unroll
    for (int u = 0; u < 2; ++u) {
        int idx = u * 256 + t;
        int r = idx >> 3, seg = idx & 7;
        *(short8*)(&u_.p2.a1b[0][r][seg * 8]) =
            *(const short8*)(a1 + (size_t)(b * LC + r) * LQ + seg * 8);
    }
    __syncthreads();

    // ---- f-phase: 8 i-chunks, double-buffered a1, 2 barriers/chunk ----
    for (int it = 0; it < 8; ++it) {
        int cur = it & 1, nxt = cur ^ 1;
        int i0 = it * 64;
        if (it < 7) {
            #pragma unroll
            for (int u = 0; u < 2; ++u) {
                int idx = u * 256 + t;
                int r = idx >> 3, seg = idx & 7;
                *(short8*)(&u_.p2.a1b[nxt][r][seg * 8]) =
                    *(const short8*)(a1 + (size_t)(b * LC + i0 + 64 + r) * LQ + seg * 8);
            }
        }
        f32x4 fa[2] = {{0.f,0.f,0.f,0.f},{0.f,0.f,0.f,0.f}};
        f32x4 fb[2] = {{0.f,0.f,0.f,0.f},{0.f,0.f,0.f,0.f}};
        #pragma unroll
        for (int kk = 0; kk < 64; kk += 32) {
            short8 af = *(const short8*)(&u_.p2.a1b[cur][16 * w + lo][kk + hi * 8]);
            #pragma unroll
            for (int jt = 0; jt < 2; ++jt) {
                short8 bq = *(const short8*)(&qTb[16 * jt + lo][kk + hi * 8]);
                fa[jt] = __builtin_amdgcn_mfma_f32_16x16x32_bf16(af, bq, fa[jt], 0, 0, 0);
                short8 bt = *(const short8*)(&tTb[16 * jt + lo][kk + hi * 8]);
                fb[jt] = __builtin_amdgcn_mfma_f32_16x16x32_bf16(af, bt, fb[jt], 0, 0, 0);
            }
        }
        // single spill: fa -> cols 0..31, fb -> cols 32..63
        #pragma unroll
        for (int jt = 0; jt < 2; ++jt)
            #pragma unroll
            for (int e = 0; e < 4; ++e) {
                u_.p2.spill[16 * w + hi * 4 + e][16 * jt + lo] = fa[jt][e];
                u_.p2.spill[16 * w + hi * 4 + e][32 + 16 * jt + lo] = fb[jt][e];
            }
        __syncthreads();
        // one store pass: all 4 sections
        #pragma unroll
        for (int u = 0; u < 2; ++u) {
            int idx = u * 256 + t;
            int r = idx >> 3, c4 = (idx & 7) * 4;
            size_t gi = (size_t)(b * LC + i0 + r);
            float4 av = *(const float4*)(&u_.p2.spill[r][c4]);
            float4 bv = *(const float4*)(&u_.p2.spill[r][32 + c4]);
            float4 cv = *(const float4*)(c + gi * HH + h0 + c4);
            float* orow = out + gi * 2048 + h0;
            nts(orow + c4, cv.x, cv.y, cv.z, cv.w);
            nts(orow + 512 + c4, av.x, av.y, av.z, av.w);
            nts(orow + 1024 + c4, cv.x * av.x, cv.y * av.y, cv.z * av.z, cv.w * av.w);
            nts(orow + 1536 + c4, cv.x * bv.x, cv.y * bv.y, cv.z * bv.z, cv.w * bv.w);
        }
        __syncthreads();   // spill + a1b[cur] safe to overwrite next iter
    }
}

extern "C" void kernel_launch(void* const* d_in, const int* in_sizes, int n_in,
                              void* d_out, int out_size, void* d_ws, size_t ws_size,
                              hipStream_t stream) {
    const float* c   = (const float*)d_in[0];
    const float* q   = (const float*)d_in[1];
    const float* cw  = (const float*)d_in[4];
    const float* qw  = (const float*)d_in[5];
    const float* cqw = (const float*)d_in[6];
    float* out = (float*)d_out;

    unsigned short* e2 = (unsigned short*)d_ws;              // 1M bf16
    unsigned short* a1 = e2 + (size_t)BB * LC * LQ;          // 1M bf16
    float* pcm = (float*)(a1 + (size_t)BB * LC * LQ);        // 16384 f32
    float* pcs = pcm + BB * (LC / 64) * LQ;                  // 16384 f32

    s2_mfma_kernel<<<dim3(LC / 64, BB), 256, 0, stream>>>(c, q, cw, qw, cqw, e2, a1, pcm, pcs);
    tf_kernel<<<dim3(HH / 32, BB), 256, 0, stream>>>(c, q, e2, pcm, pcs, a1, out);
}